// Round 1
// baseline (1025.251 us; speedup 1.0000x reference)
//
#include <hip/hip_runtime.h>
#include <math.h>

#define B_    32
#define N_    784
#define D_    512
#define K_    10
#define RES_  28
#define INF_  100000.0f
#define TM    16
#define DK    128
#define TILES (N_ / TM)   // 49
#define BIGF  3.0e38f

// ---------------------------------------------------------------------------
// Kernel A: per-row inv_norm = 1/max(||nf||,1e-12) and sq = ||nf*inv||^2.
// One wave (64 lanes) per row of 512 floats.
// ---------------------------------------------------------------------------
__global__ __launch_bounds__(256) void norm_kernel(const float* __restrict__ nf,
                                                   float* __restrict__ inv_norm,
                                                   float* __restrict__ sq) {
    int wave = threadIdx.x >> 6;
    int lane = threadIdx.x & 63;
    int row  = blockIdx.x * 4 + wave;
    if (row >= B_ * N_) return;
    const float4* p = (const float4*)(nf + (size_t)row * D_);
    float4 a = p[lane * 2];
    float4 b = p[lane * 2 + 1];
    float s = a.x*a.x + a.y*a.y + a.z*a.z + a.w*a.w
            + b.x*b.x + b.y*b.y + b.z*b.z + b.w*b.w;
    #pragma unroll
    for (int off = 32; off >= 1; off >>= 1)
        s += __shfl_xor(s, off, 64);
    if (lane == 0) {
        float nrm = sqrtf(s);
        float iv  = 1.0f / fmaxf(nrm, 1e-12f);
        inv_norm[row] = iv;
        sq[row]       = s * iv * iv;
    }
}

// ---------------------------------------------------------------------------
// Kernel B: one block per (batch b, tile of TM=16 rows). Computes raw dot
// products vs all 784 columns (register-blocked, A tile in LDS), applies the
// distance formula + rel-pos + neighbor mask into an LDS dist tile, then each
// wave does register-resident top-10 (argmin iterations, stable tie-break).
// ---------------------------------------------------------------------------
__global__ __launch_bounds__(256) void dist_topk_kernel(
    const float* __restrict__ nf, const float* __restrict__ rel,
    const float* __restrict__ inv_norm, const float* __restrict__ sqv,
    int* __restrict__ out)
{
    __shared__ float As[TM][DK];       // 8 KB
    __shared__ float distS[TM][N_];    // 50176 B

    const int tid  = threadIdx.x;
    const int b    = blockIdx.x / TILES;
    const int tile = blockIdx.x % TILES;
    const int n0   = tile * TM;
    const size_t baseRow = (size_t)b * N_;

    float acc[TM][4];
    #pragma unroll
    for (int i = 0; i < TM; i++)
        #pragma unroll
        for (int j = 0; j < 4; j++) acc[i][j] = 0.f;

    int  m[4];
    bool mv[4];
    #pragma unroll
    for (int j = 0; j < 4; j++) { m[j] = tid + 256 * j; mv[j] = (m[j] < N_); }

    const float* bbase = nf + baseRow * D_;

    for (int d0 = 0; d0 < D_; d0 += DK) {
        __syncthreads();   // protect As against readers from previous chunk
        #pragma unroll
        for (int t = 0; t < 2; t++) {
            int f4  = tid + t * 256;        // 0..511 float4s (16 rows x 32)
            int row = f4 >> 5;
            int col = (f4 & 31) << 2;
            float4 v = *(const float4*)(nf + (baseRow + n0 + row) * D_ + d0 + col);
            *(float4*)&As[row][col] = v;
        }
        __syncthreads();

        for (int d4 = 0; d4 < DK; d4 += 4) {
            float4 bv[4];
            #pragma unroll
            for (int j = 0; j < 4; j++) {
                if (mv[j]) bv[j] = *(const float4*)(bbase + (size_t)m[j] * D_ + d0 + d4);
                else       bv[j] = make_float4(0.f, 0.f, 0.f, 0.f);
            }
            #pragma unroll
            for (int nl = 0; nl < TM; nl++) {
                float4 av = *(const float4*)&As[nl][d4];
                #pragma unroll
                for (int j = 0; j < 4; j++) {
                    acc[nl][j] = fmaf(av.x, bv[j].x, acc[nl][j]);
                    acc[nl][j] = fmaf(av.y, bv[j].y, acc[nl][j]);
                    acc[nl][j] = fmaf(av.z, bv[j].z, acc[nl][j]);
                    acc[nl][j] = fmaf(av.w, bv[j].w, acc[nl][j]);
                }
            }
        }
    }

    // ---- epilogue: distance formula into LDS dist tile ----
    float invm[4], sqm[4];
    #pragma unroll
    for (int j = 0; j < 4; j++) {
        if (mv[j]) { invm[j] = inv_norm[baseRow + m[j]]; sqm[j] = sqv[baseRow + m[j]]; }
        else       { invm[j] = 0.f; sqm[j] = 0.f; }
    }
    #pragma unroll
    for (int nl = 0; nl < TM; nl++) {
        int ng = n0 + nl;
        float invn = inv_norm[baseRow + ng];
        float sqn  = sqv[baseRow + ng];
        int r1 = ng / RES_, c1 = ng % RES_;
        #pragma unroll
        for (int j = 0; j < 4; j++) {
            if (!mv[j]) continue;
            int mm = m[j];
            float d = sqn + sqm[j] - 2.f * invn * invm[j] * acc[nl][j]
                    + rel[(size_t)ng * N_ + mm];
            int r2 = mm / RES_, c2 = mm % RES_;
            int dr = r1 - r2; if (dr < 0) dr = -dr;
            int dc = c1 - c2; if (dc < 0) dc = -dc;
            if (dr <= 1 && dc <= 1) d += INF_;
            distS[nl][mm] = d;
        }
    }
    __syncthreads();

    // ---- top-K per row: wave w handles rows w*4 .. w*4+3 ----
    const int wv   = tid >> 6;
    const int lane = tid & 63;
    for (int r = 0; r < 4; r++) {
        int nl = wv * 4 + r;
        int ng = n0 + nl;
        float vals[13];
        #pragma unroll
        for (int j = 0; j < 13; j++) {
            int mm = lane + 64 * j;
            vals[j] = (mm < N_) ? distS[nl][mm] : BIGF;
        }
        size_t outbase = (size_t)(baseRow + ng) * K_ * 3;
        for (int k = 0; k < K_; k++) {
            // lane-local argmin (lowest index wins ties: scan ascending)
            float bd = vals[0]; int bi = lane;
            #pragma unroll
            for (int j = 1; j < 13; j++) {
                int mm = lane + 64 * j;
                if (vals[j] < bd || (vals[j] == bd && mm < bi)) { bd = vals[j]; bi = mm; }
            }
            // 64-lane butterfly min with index tie-break
            float cd = bd; int ci = bi;
            #pragma unroll
            for (int off = 32; off >= 1; off >>= 1) {
                float od = __shfl_xor(cd, off, 64);
                int   oi = __shfl_xor(ci, off, 64);
                if (od < cd || (od == cd && oi < ci)) { cd = od; ci = oi; }
            }
            // invalidate winner in its owner's registers (static indexing only)
            #pragma unroll
            for (int j = 0; j < 13; j++) {
                if (ci == lane + 64 * j) vals[j] = BIGF;
            }
            if (lane == 0) {
                out[outbase + (size_t)k * 3 + 0] = (int)baseRow + ci;
                out[outbase + (size_t)k * 3 + 1] = (int)(baseRow + ng);
                out[outbase + (size_t)k * 3 + 2] = 0;
            }
        }
    }
}

extern "C" void kernel_launch(void* const* d_in, const int* in_sizes, int n_in,
                              void* d_out, int out_size, void* d_ws, size_t ws_size,
                              hipStream_t stream) {
    const float* nf  = (const float*)d_in[0];   // [32, 784, 512] f32
    const float* rel = (const float*)d_in[1];   // [1, 784, 784] f32 (already -rel)
    float* inv_norm  = (float*)d_ws;            // [25088]
    float* sq        = inv_norm + B_ * N_;      // [25088]
    int*   out       = (int*)d_out;             // [25088*10*3] int32

    norm_kernel<<<(B_ * N_) / 4, 256, 0, stream>>>(nf, inv_norm, sq);
    dist_topk_kernel<<<B_ * TILES, 256, 0, stream>>>(nf, rel, inv_norm, sq, out);
}

// Round 2
// 657.318 us; speedup vs baseline: 1.5597x; 1.5597x over previous
//
#include <hip/hip_runtime.h>
#include <math.h>

#define B_    32
#define N_    784
#define D_    512
#define K_    10
#define RES_  28
#define INF_  100000.0f
#define TM    16
#define DK    128
#define TILES (N_ / TM)   // 49
#define BIGF  3.0e38f
#define NTPW  13          // max col-tiles per wave in mfma kernel
#define LDSW  785         // padded dist row stride (floats)

typedef __attribute__((ext_vector_type(8))) short short8;
typedef __attribute__((ext_vector_type(4))) float f32x4;

__device__ __forceinline__ unsigned short f2bf(float f) {
    unsigned u = __float_as_uint(f);
    unsigned r = (u + 0x7fffu + ((u >> 16) & 1u)) >> 16;   // RNE
    return (unsigned short)r;
}
__device__ __forceinline__ float bf2f(unsigned short h) {
    return __uint_as_float(((unsigned)h) << 16);
}

// ---------------------------------------------------------------------------
// Kernel A (main path): per-row inv_norm & sq, plus split-bf16 conversion
// x = hi + lo with hi=bf16(x), lo=bf16(x-hi). One wave per row.
// ---------------------------------------------------------------------------
__global__ __launch_bounds__(256) void norm_convert_kernel(
    const float* __restrict__ nf, float* __restrict__ inv_norm,
    float* __restrict__ sq, unsigned short* __restrict__ xhi,
    unsigned short* __restrict__ xlo)
{
    int wave = threadIdx.x >> 6;
    int lane = threadIdx.x & 63;
    int row  = blockIdx.x * 4 + wave;           // grid exactly covers B_*N_
    const float* rp = nf + (size_t)row * D_;
    float4 a = *(const float4*)(rp + lane * 8);
    float4 b = *(const float4*)(rp + lane * 8 + 4);
    float v[8] = {a.x, a.y, a.z, a.w, b.x, b.y, b.z, b.w};

    float s = 0.f;
    #pragma unroll
    for (int i = 0; i < 8; i++) s = fmaf(v[i], v[i], s);
    #pragma unroll
    for (int off = 32; off >= 1; off >>= 1)
        s += __shfl_xor(s, off, 64);
    if (lane == 0) {
        float nrm = sqrtf(s);
        float iv  = 1.0f / fmaxf(nrm, 1e-12f);
        inv_norm[row] = iv;
        sq[row]       = s * iv * iv;
    }

    unsigned short h[8], l[8];
    #pragma unroll
    for (int i = 0; i < 8; i++) {
        h[i] = f2bf(v[i]);
        float hf = bf2f(h[i]);
        l[i] = f2bf(v[i] - hf);
    }
    size_t off16 = (size_t)row * D_ + lane * 8;
    short8 h8, l8;
    #pragma unroll
    for (int i = 0; i < 8; i++) { h8[i] = (short)h[i]; l8[i] = (short)l[i]; }
    *(short8*)(xhi + off16) = h8;
    *(short8*)(xlo + off16) = l8;
}

// ---------------------------------------------------------------------------
// Kernel B (main path): one block = (batch, 32 rows). Split-bf16 MFMA GEMM
// vs all 784 columns, fragments loaded straight from global (L2). Epilogue
// per 16-row tile: distance formula -> LDS -> register-resident top-10.
// ---------------------------------------------------------------------------
__global__ __launch_bounds__(256) void mfma_dist_topk(
    const unsigned short* __restrict__ xhi, const unsigned short* __restrict__ xlo,
    const float* __restrict__ rel, const float* __restrict__ inv_norm,
    const float* __restrict__ sqv, int* __restrict__ out)
{
    __shared__ float distS[16][LDSW];   // 50240 B

    const int tid  = threadIdx.x;
    const int wv   = tid >> 6;
    const int lane = tid & 63;
    const int quad = lane >> 4;
    const int l16  = lane & 15;

    // XCD swizzle: 800 blocks = 8 xcds * (4 batches * 25 row-pairs)
    int gb   = blockIdx.x;
    int xcd  = gb & 7;
    int loc  = gb >> 3;                 // 0..99
    int b    = xcd * 4 + loc / 25;
    int pair = loc % 25;
    const int  n0   = pair * 32;
    const bool two  = (pair < 24);      // pair 24 has only 16 rows (784 = 24*32+16)
    const size_t base = (size_t)b * N_;

    const unsigned short* hbase = xhi + base * D_;
    const unsigned short* lbase = xlo + base * D_;

    f32x4 acc[2][NTPW];
    #pragma unroll
    for (int rt = 0; rt < 2; rt++)
        #pragma unroll
        for (int j = 0; j < NTPW; j++) acc[rt][j] = {0.f, 0.f, 0.f, 0.f};

    int  rb[NTPW];
    bool tvalid[NTPW];
    #pragma unroll
    for (int j = 0; j < NTPW; j++) {
        int t = wv + 4 * j;
        tvalid[j] = (t < TILES);
        rb[j] = tvalid[j] ? t * 16 + l16 : 0;
    }

    int ra0 = n0 + l16;
    int ra1 = two ? (n0 + 16 + l16) : ra0;

    for (int t = 0; t < 16; ++t) {      // K-steps of 32
        int koff = t * 32 + quad * 8;
        short8 a0h = *(const short8*)(hbase + (size_t)ra0 * D_ + koff);
        short8 a0l = *(const short8*)(lbase + (size_t)ra0 * D_ + koff);
        short8 a1h = *(const short8*)(hbase + (size_t)ra1 * D_ + koff);
        short8 a1l = *(const short8*)(lbase + (size_t)ra1 * D_ + koff);
        #pragma unroll
        for (int j = 0; j < NTPW; ++j) {
            if (!tvalid[j]) continue;   // wave-uniform
            short8 bh = *(const short8*)(hbase + (size_t)rb[j] * D_ + koff);
            short8 bl = *(const short8*)(lbase + (size_t)rb[j] * D_ + koff);
            acc[0][j] = __builtin_amdgcn_mfma_f32_16x16x32_bf16(a0l, bh, acc[0][j], 0, 0, 0);
            acc[0][j] = __builtin_amdgcn_mfma_f32_16x16x32_bf16(a0h, bl, acc[0][j], 0, 0, 0);
            acc[0][j] = __builtin_amdgcn_mfma_f32_16x16x32_bf16(a0h, bh, acc[0][j], 0, 0, 0);
            acc[1][j] = __builtin_amdgcn_mfma_f32_16x16x32_bf16(a1l, bh, acc[1][j], 0, 0, 0);
            acc[1][j] = __builtin_amdgcn_mfma_f32_16x16x32_bf16(a1h, bl, acc[1][j], 0, 0, 0);
            acc[1][j] = __builtin_amdgcn_mfma_f32_16x16x32_bf16(a1h, bh, acc[1][j], 0, 0, 0);
        }
    }

    for (int rt = 0; rt < 2; ++rt) {
        if (rt == 1 && !two) break;     // block-uniform
        __syncthreads();                // protect distS from previous iteration's readers
        const int nbase = n0 + rt * 16;

        float invn[4], sqn[4];
        int   rr[4], rc[4];
        #pragma unroll
        for (int reg = 0; reg < 4; ++reg) {
            int n = nbase + quad * 4 + reg;
            invn[reg] = inv_norm[base + n];
            sqn[reg]  = sqv[base + n];
            rr[reg] = n / RES_;
            rc[reg] = n % RES_;
        }
        #pragma unroll
        for (int j = 0; j < NTPW; ++j) {
            if (!tvalid[j]) continue;
            int m = (wv + 4 * j) * 16 + l16;
            float invm = inv_norm[base + m];
            float sqm  = sqv[base + m];
            int mr = m / RES_, mc = m % RES_;
            #pragma unroll
            for (int reg = 0; reg < 4; ++reg) {
                int n = nbase + quad * 4 + reg;
                float d = sqn[reg] + sqm - 2.f * invn[reg] * invm * acc[rt][j][reg]
                        + rel[(size_t)n * N_ + m];
                int dr = rr[reg] - mr; if (dr < 0) dr = -dr;
                int dc = rc[reg] - mc; if (dc < 0) dc = -dc;
                if (dr <= 1 && dc <= 1) d += INF_;
                distS[quad * 4 + reg][m] = d;
            }
        }
        __syncthreads();

        // top-K: wave wv handles rows wv*4 .. wv*4+3 of this 16-row tile
        for (int r = 0; r < 4; ++r) {
            int nl = wv * 4 + r;
            int ng = nbase + nl;
            float vals[13];
            #pragma unroll
            for (int j = 0; j < 13; j++) {
                int mm = lane + 64 * j;
                vals[j] = (mm < N_) ? distS[nl][mm] : BIGF;
            }
            size_t outbase = (size_t)(base + ng) * K_ * 3;
            for (int k = 0; k < K_; k++) {
                float bd = vals[0]; int bi = lane;
                #pragma unroll
                for (int j = 1; j < 13; j++) {
                    int mm = lane + 64 * j;
                    if (vals[j] < bd || (vals[j] == bd && mm < bi)) { bd = vals[j]; bi = mm; }
                }
                float cd = bd; int ci = bi;
                #pragma unroll
                for (int off = 32; off >= 1; off >>= 1) {
                    float od = __shfl_xor(cd, off, 64);
                    int   oi = __shfl_xor(ci, off, 64);
                    if (od < cd || (od == cd && oi < ci)) { cd = od; ci = oi; }
                }
                #pragma unroll
                for (int j = 0; j < 13; j++) {
                    if (ci == lane + 64 * j) vals[j] = BIGF;
                }
                if (lane == 0) {
                    out[outbase + (size_t)k * 3 + 0] = (int)base + ci;
                    out[outbase + (size_t)k * 3 + 1] = (int)(base + ng);
                    out[outbase + (size_t)k * 3 + 2] = 0;
                }
            }
        }
    }
}

// ===========================================================================
// Fallback path (round-1 fp32 kernels) — used only if ws_size can't hold the
// split-bf16 arrays.
// ===========================================================================
__global__ __launch_bounds__(256) void norm_kernel(const float* __restrict__ nf,
                                                   float* __restrict__ inv_norm,
                                                   float* __restrict__ sq) {
    int wave = threadIdx.x >> 6;
    int lane = threadIdx.x & 63;
    int row  = blockIdx.x * 4 + wave;
    if (row >= B_ * N_) return;
    const float4* p = (const float4*)(nf + (size_t)row * D_);
    float4 a = p[lane * 2];
    float4 b = p[lane * 2 + 1];
    float s = a.x*a.x + a.y*a.y + a.z*a.z + a.w*a.w
            + b.x*b.x + b.y*b.y + b.z*b.z + b.w*b.w;
    #pragma unroll
    for (int off = 32; off >= 1; off >>= 1)
        s += __shfl_xor(s, off, 64);
    if (lane == 0) {
        float nrm = sqrtf(s);
        float iv  = 1.0f / fmaxf(nrm, 1e-12f);
        inv_norm[row] = iv;
        sq[row]       = s * iv * iv;
    }
}

__global__ __launch_bounds__(256) void dist_topk_kernel(
    const float* __restrict__ nf, const float* __restrict__ rel,
    const float* __restrict__ inv_norm, const float* __restrict__ sqv,
    int* __restrict__ out)
{
    __shared__ float As[TM][DK];
    __shared__ float distS[TM][N_];

    const int tid  = threadIdx.x;
    const int b    = blockIdx.x / TILES;
    const int tile = blockIdx.x % TILES;
    const int n0   = tile * TM;
    const size_t baseRow = (size_t)b * N_;

    float acc[TM][4];
    #pragma unroll
    for (int i = 0; i < TM; i++)
        #pragma unroll
        for (int j = 0; j < 4; j++) acc[i][j] = 0.f;

    int  m[4];
    bool mv[4];
    #pragma unroll
    for (int j = 0; j < 4; j++) { m[j] = tid + 256 * j; mv[j] = (m[j] < N_); }

    const float* bbase = nf + baseRow * D_;

    for (int d0 = 0; d0 < D_; d0 += DK) {
        __syncthreads();
        #pragma unroll
        for (int t = 0; t < 2; t++) {
            int f4  = tid + t * 256;
            int row = f4 >> 5;
            int col = (f4 & 31) << 2;
            float4 v = *(const float4*)(nf + (baseRow + n0 + row) * D_ + d0 + col);
            *(float4*)&As[row][col] = v;
        }
        __syncthreads();

        for (int d4 = 0; d4 < DK; d4 += 4) {
            float4 bv[4];
            #pragma unroll
            for (int j = 0; j < 4; j++) {
                if (mv[j]) bv[j] = *(const float4*)(bbase + (size_t)m[j] * D_ + d0 + d4);
                else       bv[j] = make_float4(0.f, 0.f, 0.f, 0.f);
            }
            #pragma unroll
            for (int nl = 0; nl < TM; nl++) {
                float4 av = *(const float4*)&As[nl][d4];
                #pragma unroll
                for (int j = 0; j < 4; j++) {
                    acc[nl][j] = fmaf(av.x, bv[j].x, acc[nl][j]);
                    acc[nl][j] = fmaf(av.y, bv[j].y, acc[nl][j]);
                    acc[nl][j] = fmaf(av.z, bv[j].z, acc[nl][j]);
                    acc[nl][j] = fmaf(av.w, bv[j].w, acc[nl][j]);
                }
            }
        }
    }

    float invm[4], sqm[4];
    #pragma unroll
    for (int j = 0; j < 4; j++) {
        if (mv[j]) { invm[j] = inv_norm[baseRow + m[j]]; sqm[j] = sqv[baseRow + m[j]]; }
        else       { invm[j] = 0.f; sqm[j] = 0.f; }
    }
    #pragma unroll
    for (int nl = 0; nl < TM; nl++) {
        int ng = n0 + nl;
        float invn = inv_norm[baseRow + ng];
        float sqn  = sqv[baseRow + ng];
        int r1 = ng / RES_, c1 = ng % RES_;
        #pragma unroll
        for (int j = 0; j < 4; j++) {
            if (!mv[j]) continue;
            int mm = m[j];
            float d = sqn + sqm[j] - 2.f * invn * invm[j] * acc[nl][j]
                    + rel[(size_t)ng * N_ + mm];
            int r2 = mm / RES_, c2 = mm % RES_;
            int dr = r1 - r2; if (dr < 0) dr = -dr;
            int dc = c1 - c2; if (dc < 0) dc = -dc;
            if (dr <= 1 && dc <= 1) d += INF_;
            distS[nl][mm] = d;
        }
    }
    __syncthreads();

    const int wv   = tid >> 6;
    const int lane = tid & 63;
    for (int r = 0; r < 4; r++) {
        int nl = wv * 4 + r;
        int ng = n0 + nl;
        float vals[13];
        #pragma unroll
        for (int j = 0; j < 13; j++) {
            int mm = lane + 64 * j;
            vals[j] = (mm < N_) ? distS[nl][mm] : BIGF;
        }
        size_t outbase = (size_t)(baseRow + ng) * K_ * 3;
        for (int k = 0; k < K_; k++) {
            float bd = vals[0]; int bi = lane;
            #pragma unroll
            for (int j = 1; j < 13; j++) {
                int mm = lane + 64 * j;
                if (vals[j] < bd || (vals[j] == bd && mm < bi)) { bd = vals[j]; bi = mm; }
            }
            float cd = bd; int ci = bi;
            #pragma unroll
            for (int off = 32; off >= 1; off >>= 1) {
                float od = __shfl_xor(cd, off, 64);
                int   oi = __shfl_xor(ci, off, 64);
                if (od < cd || (od == cd && oi < ci)) { cd = od; ci = oi; }
            }
            #pragma unroll
            for (int j = 0; j < 13; j++) {
                if (ci == lane + 64 * j) vals[j] = BIGF;
            }
            if (lane == 0) {
                out[outbase + (size_t)k * 3 + 0] = (int)baseRow + ci;
                out[outbase + (size_t)k * 3 + 1] = (int)(baseRow + ng);
                out[outbase + (size_t)k * 3 + 2] = 0;
            }
        }
    }
}

extern "C" void kernel_launch(void* const* d_in, const int* in_sizes, int n_in,
                              void* d_out, int out_size, void* d_ws, size_t ws_size,
                              hipStream_t stream) {
    const float* nf  = (const float*)d_in[0];   // [32, 784, 512] f32
    const float* rel = (const float*)d_in[1];   // [1, 784, 784] f32 (already -rel)
    float* inv_norm  = (float*)d_ws;            // [25088]
    float* sq        = inv_norm + B_ * N_;      // [25088]
    int*   out       = (int*)d_out;

    size_t need = (size_t)2 * B_ * N_ * sizeof(float)
                + (size_t)2 * B_ * N_ * D_ * sizeof(unsigned short);
    if (ws_size >= need) {
        unsigned short* xhi = (unsigned short*)(sq + B_ * N_);
        unsigned short* xlo = xhi + (size_t)B_ * N_ * D_;
        norm_convert_kernel<<<(B_ * N_) / 4, 256, 0, stream>>>(nf, inv_norm, sq, xhi, xlo);
        mfma_dist_topk<<<800, 256, 0, stream>>>(xhi, xlo, rel, inv_norm, sq, out);
    } else {
        norm_kernel<<<(B_ * N_) / 4, 256, 0, stream>>>(nf, inv_norm, sq);
        dist_topk_kernel<<<B_ * TILES, 256, 0, stream>>>(nf, rel, inv_norm, sq, out);
    }
}

// Round 3
// 570.162 us; speedup vs baseline: 1.7982x; 1.1529x over previous
//
#include <hip/hip_runtime.h>
#include <math.h>

#define B_    32
#define N_    784
#define D_    512
#define K_    10
#define RES_  28
#define INF_  100000.0f
#define TM    16
#define DK    128
#define TILES (N_ / TM)   // 49
#define BIGF  3.0e38f
#define LDSW  788         // padded dist row stride (floats): 2-way bank alias only

typedef __attribute__((ext_vector_type(8))) short short8;
typedef __attribute__((ext_vector_type(4))) float f32x4;

__device__ __forceinline__ unsigned short f2bf(float f) {
    unsigned u = __float_as_uint(f);
    unsigned r = (u + 0x7fffu + ((u >> 16) & 1u)) >> 16;   // RNE
    return (unsigned short)r;
}
__device__ __forceinline__ float bf2f(unsigned short h) {
    return __uint_as_float(((unsigned)h) << 16);
}

// ---------------------------------------------------------------------------
// Kernel A (main path): per-row inv_norm & sq, plus split-bf16 conversion
// x = hi + lo with hi=bf16(x), lo=bf16(x-hi). One wave per row.
// ---------------------------------------------------------------------------
__global__ __launch_bounds__(256) void norm_convert_kernel(
    const float* __restrict__ nf, float* __restrict__ inv_norm,
    float* __restrict__ sq, unsigned short* __restrict__ xhi,
    unsigned short* __restrict__ xlo)
{
    int wave = threadIdx.x >> 6;
    int lane = threadIdx.x & 63;
    int row  = blockIdx.x * 4 + wave;           // grid exactly covers B_*N_
    const float* rp = nf + (size_t)row * D_;
    float4 a = *(const float4*)(rp + lane * 8);
    float4 b = *(const float4*)(rp + lane * 8 + 4);
    float v[8] = {a.x, a.y, a.z, a.w, b.x, b.y, b.z, b.w};

    float s = 0.f;
    #pragma unroll
    for (int i = 0; i < 8; i++) s = fmaf(v[i], v[i], s);
    #pragma unroll
    for (int off = 32; off >= 1; off >>= 1)
        s += __shfl_xor(s, off, 64);
    if (lane == 0) {
        float nrm = sqrtf(s);
        float iv  = 1.0f / fmaxf(nrm, 1e-12f);
        inv_norm[row] = iv;
        sq[row]       = s * iv * iv;
    }

    unsigned short h[8], l[8];
    #pragma unroll
    for (int i = 0; i < 8; i++) {
        h[i] = f2bf(v[i]);
        float hf = bf2f(h[i]);
        l[i] = f2bf(v[i] - hf);
    }
    size_t off16 = (size_t)row * D_ + lane * 8;
    short8 h8, l8;
    #pragma unroll
    for (int i = 0; i < 8; i++) { h8[i] = (short)h[i]; l8[i] = (short)l[i]; }
    *(short8*)(xhi + off16) = h8;
    *(short8*)(xlo + off16) = l8;
}

// ---------------------------------------------------------------------------
// Kernel B (main path): one block = (batch, 16-row tile). A fragments for the
// FULL K=512 held in registers (128 VGPRs, bounded by design); col-tile loop
// outside K loop so only one accumulator pair (8 VGPRs) is live -> no spill.
// Epilogue: distance formula -> padded LDS -> register-resident top-10.
// ---------------------------------------------------------------------------
__global__ __launch_bounds__(256, 2) void dist16_topk(
    const unsigned short* __restrict__ xhi, const unsigned short* __restrict__ xlo,
    const float* __restrict__ rel, const float* __restrict__ inv_norm,
    const float* __restrict__ sqv, int* __restrict__ out)
{
    __shared__ float distS[TM][LDSW];   // 50432 B

    const int tid  = threadIdx.x;
    const int wv   = tid >> 6;
    const int lane = tid & 63;
    const int quad = lane >> 4;
    const int l16  = lane & 15;

    // 1568 blocks = 8 XCDs * (4 batches * 49 row-tiles): keep one batch's
    // split arrays (3.2 MB) resident in one XCD's 4 MB L2.
    int gb   = blockIdx.x;
    int xcd  = gb & 7;
    int loc  = gb >> 3;                  // 0..195
    int b    = xcd * 4 + loc / TILES;
    int tile = loc % TILES;
    const int    n0   = tile * TM;
    const size_t base = (size_t)b * N_;

    const unsigned short* hb = xhi + base * D_;
    const unsigned short* lb = xlo + base * D_;

    // ---- A fragments, full K, in registers ----
    const size_t arow = (size_t)(n0 + l16) * D_;
    short8 ah[16], al[16];
    #pragma unroll
    for (int t = 0; t < 16; ++t) {
        int koff = t * 32 + quad * 8;
        ah[t] = *(const short8*)(hb + arow + koff);
        al[t] = *(const short8*)(lb + arow + koff);
    }

    // ---- per-row epilogue constants (loop-invariant) ----
    float invn[4], sqn[4];
    int   rr[4], rc[4];
    #pragma unroll
    for (int reg = 0; reg < 4; ++reg) {
        int n = n0 + quad * 4 + reg;
        invn[reg] = inv_norm[base + n];
        sqn[reg]  = sqv[base + n];
        rr[reg]   = n / RES_;
        rc[reg]   = n % RES_;
    }

    // ---- col-tile pairs: wave wv owns tiles {wv, wv+4, wv+8, ...} ----
    for (int j0 = 0; j0 < 13; j0 += 2) {
        int  t0 = wv + 4 * j0;
        int  t1 = t0 + 4;
        bool v1 = (t1 < TILES);          // wave-uniform
        if (t0 >= TILES) break;          // wave-uniform

        size_t brow0 = (size_t)(t0 * TM + l16) * D_;
        size_t brow1 = v1 ? (size_t)(t1 * TM + l16) * D_ : brow0;

        f32x4 acc0 = {0.f, 0.f, 0.f, 0.f};
        f32x4 acc1 = {0.f, 0.f, 0.f, 0.f};
        #pragma unroll
        for (int t = 0; t < 16; ++t) {
            int koff = t * 32 + quad * 8;
            short8 b0h = *(const short8*)(hb + brow0 + koff);
            short8 b0l = *(const short8*)(lb + brow0 + koff);
            short8 b1h = *(const short8*)(hb + brow1 + koff);
            short8 b1l = *(const short8*)(lb + brow1 + koff);
            acc0 = __builtin_amdgcn_mfma_f32_16x16x32_bf16(al[t], b0h, acc0, 0, 0, 0);
            acc0 = __builtin_amdgcn_mfma_f32_16x16x32_bf16(ah[t], b0l, acc0, 0, 0, 0);
            acc0 = __builtin_amdgcn_mfma_f32_16x16x32_bf16(ah[t], b0h, acc0, 0, 0, 0);
            acc1 = __builtin_amdgcn_mfma_f32_16x16x32_bf16(al[t], b1h, acc1, 0, 0, 0);
            acc1 = __builtin_amdgcn_mfma_f32_16x16x32_bf16(ah[t], b1l, acc1, 0, 0, 0);
            acc1 = __builtin_amdgcn_mfma_f32_16x16x32_bf16(ah[t], b1h, acc1, 0, 0, 0);
        }

        #pragma unroll
        for (int p = 0; p < 2; ++p) {
            if (p == 1 && !v1) break;    // wave-uniform
            int tt = (p == 0) ? t0 : t1;
            f32x4 av = (p == 0) ? acc0 : acc1;
            int m = tt * TM + l16;
            float invm = inv_norm[base + m];
            float sqm  = sqv[base + m];
            int mr = m / RES_, mc = m % RES_;
            #pragma unroll
            for (int reg = 0; reg < 4; ++reg) {
                int n = n0 + quad * 4 + reg;
                float d = sqn[reg] + sqm - 2.f * invn[reg] * invm * av[reg]
                        + rel[(size_t)n * N_ + m];
                int dr = rr[reg] - mr; if (dr < 0) dr = -dr;
                int dc = rc[reg] - mc; if (dc < 0) dc = -dc;
                if (dr <= 1 && dc <= 1) d += INF_;
                distS[quad * 4 + reg][m] = d;
            }
        }
    }
    __syncthreads();

    // ---- top-K: wave wv handles rows wv*4 .. wv*4+3 ----
    for (int r = 0; r < 4; ++r) {
        int nl = wv * 4 + r;
        int ng = n0 + nl;
        float vals[13];
        #pragma unroll
        for (int j = 0; j < 13; j++) {
            int mm = lane + 64 * j;
            vals[j] = (mm < N_) ? distS[nl][mm] : BIGF;
        }
        size_t outbase = (size_t)(base + ng) * K_ * 3;
        for (int k = 0; k < K_; k++) {
            float bd = vals[0]; int bi = lane;
            #pragma unroll
            for (int j = 1; j < 13; j++) {
                int mm = lane + 64 * j;
                if (vals[j] < bd || (vals[j] == bd && mm < bi)) { bd = vals[j]; bi = mm; }
            }
            float cd = bd; int ci = bi;
            #pragma unroll
            for (int off = 32; off >= 1; off >>= 1) {
                float od = __shfl_xor(cd, off, 64);
                int   oi = __shfl_xor(ci, off, 64);
                if (od < cd || (od == cd && oi < ci)) { cd = od; ci = oi; }
            }
            #pragma unroll
            for (int j = 0; j < 13; j++) {
                if (ci == lane + 64 * j) vals[j] = BIGF;
            }
            if (lane == 0) {
                out[outbase + (size_t)k * 3 + 0] = (int)base + ci;
                out[outbase + (size_t)k * 3 + 1] = (int)(base + ng);
                out[outbase + (size_t)k * 3 + 2] = 0;
            }
        }
    }
}

// ===========================================================================
// Fallback path (round-1 fp32 kernels) — used only if ws_size can't hold the
// split-bf16 arrays.
// ===========================================================================
__global__ __launch_bounds__(256) void norm_kernel(const float* __restrict__ nf,
                                                   float* __restrict__ inv_norm,
                                                   float* __restrict__ sq) {
    int wave = threadIdx.x >> 6;
    int lane = threadIdx.x & 63;
    int row  = blockIdx.x * 4 + wave;
    if (row >= B_ * N_) return;
    const float4* p = (const float4*)(nf + (size_t)row * D_);
    float4 a = p[lane * 2];
    float4 b = p[lane * 2 + 1];
    float s = a.x*a.x + a.y*a.y + a.z*a.z + a.w*a.w
            + b.x*b.x + b.y*b.y + b.z*b.z + b.w*b.w;
    #pragma unroll
    for (int off = 32; off >= 1; off >>= 1)
        s += __shfl_xor(s, off, 64);
    if (lane == 0) {
        float nrm = sqrtf(s);
        float iv  = 1.0f / fmaxf(nrm, 1e-12f);
        inv_norm[row] = iv;
        sq[row]       = s * iv * iv;
    }
}

__global__ __launch_bounds__(256) void dist_topk_kernel(
    const float* __restrict__ nf, const float* __restrict__ rel,
    const float* __restrict__ inv_norm, const float* __restrict__ sqv,
    int* __restrict__ out)
{
    __shared__ float As[TM][DK];
    __shared__ float distS[TM][N_];

    const int tid  = threadIdx.x;
    const int b    = blockIdx.x / TILES;
    const int tile = blockIdx.x % TILES;
    const int n0   = tile * TM;
    const size_t baseRow = (size_t)b * N_;

    float acc[TM][4];
    #pragma unroll
    for (int i = 0; i < TM; i++)
        #pragma unroll
        for (int j = 0; j < 4; j++) acc[i][j] = 0.f;

    int  m[4];
    bool mv[4];
    #pragma unroll
    for (int j = 0; j < 4; j++) { m[j] = tid + 256 * j; mv[j] = (m[j] < N_); }

    const float* bbase = nf + baseRow * D_;

    for (int d0 = 0; d0 < D_; d0 += DK) {
        __syncthreads();
        #pragma unroll
        for (int t = 0; t < 2; t++) {
            int f4  = tid + t * 256;
            int row = f4 >> 5;
            int col = (f4 & 31) << 2;
            float4 v = *(const float4*)(nf + (baseRow + n0 + row) * D_ + d0 + col);
            *(float4*)&As[row][col] = v;
        }
        __syncthreads();

        for (int d4 = 0; d4 < DK; d4 += 4) {
            float4 bv[4];
            #pragma unroll
            for (int j = 0; j < 4; j++) {
                if (mv[j]) bv[j] = *(const float4*)(bbase + (size_t)m[j] * D_ + d0 + d4);
                else       bv[j] = make_float4(0.f, 0.f, 0.f, 0.f);
            }
            #pragma unroll
            for (int nl = 0; nl < TM; nl++) {
                float4 av = *(const float4*)&As[nl][d4];
                #pragma unroll
                for (int j = 0; j < 4; j++) {
                    acc[nl][j] = fmaf(av.x, bv[j].x, acc[nl][j]);
                    acc[nl][j] = fmaf(av.y, bv[j].y, acc[nl][j]);
                    acc[nl][j] = fmaf(av.z, bv[j].z, acc[nl][j]);
                    acc[nl][j] = fmaf(av.w, bv[j].w, acc[nl][j]);
                }
            }
        }
    }

    float invm[4], sqm[4];
    #pragma unroll
    for (int j = 0; j < 4; j++) {
        if (mv[j]) { invm[j] = inv_norm[baseRow + m[j]]; sqm[j] = sqv[baseRow + m[j]]; }
        else       { invm[j] = 0.f; sqm[j] = 0.f; }
    }
    #pragma unroll
    for (int nl = 0; nl < TM; nl++) {
        int ng = n0 + nl;
        float invn = inv_norm[baseRow + ng];
        float sqn  = sqv[baseRow + ng];
        int r1 = ng / RES_, c1 = ng % RES_;
        #pragma unroll
        for (int j = 0; j < 4; j++) {
            if (!mv[j]) continue;
            int mm = m[j];
            float d = sqn + sqm[j] - 2.f * invn * invm[j] * acc[nl][j]
                    + rel[(size_t)ng * N_ + mm];
            int r2 = mm / RES_, c2 = mm % RES_;
            int dr = r1 - r2; if (dr < 0) dr = -dr;
            int dc = c1 - c2; if (dc < 0) dc = -dc;
            if (dr <= 1 && dc <= 1) d += INF_;
            distS[nl][mm] = d;
        }
    }
    __syncthreads();

    const int wv   = tid >> 6;
    const int lane = tid & 63;
    for (int r = 0; r < 4; r++) {
        int nl = wv * 4 + r;
        int ng = n0 + nl;
        float vals[13];
        #pragma unroll
        for (int j = 0; j < 13; j++) {
            int mm = lane + 64 * j;
            vals[j] = (mm < N_) ? distS[nl][mm] : BIGF;
        }
        size_t outbase = (size_t)(baseRow + ng) * K_ * 3;
        for (int k = 0; k < K_; k++) {
            float bd = vals[0]; int bi = lane;
            #pragma unroll
            for (int j = 1; j < 13; j++) {
                int mm = lane + 64 * j;
                if (vals[j] < bd || (vals[j] == bd && mm < bi)) { bd = vals[j]; bi = mm; }
            }
            float cd = bd; int ci = bi;
            #pragma unroll
            for (int off = 32; off >= 1; off >>= 1) {
                float od = __shfl_xor(cd, off, 64);
                int   oi = __shfl_xor(ci, off, 64);
                if (od < cd || (od == cd && oi < ci)) { cd = od; ci = oi; }
            }
            #pragma unroll
            for (int j = 0; j < 13; j++) {
                if (ci == lane + 64 * j) vals[j] = BIGF;
            }
            if (lane == 0) {
                out[outbase + (size_t)k * 3 + 0] = (int)baseRow + ci;
                out[outbase + (size_t)k * 3 + 1] = (int)(baseRow + ng);
                out[outbase + (size_t)k * 3 + 2] = 0;
            }
        }
    }
}

extern "C" void kernel_launch(void* const* d_in, const int* in_sizes, int n_in,
                              void* d_out, int out_size, void* d_ws, size_t ws_size,
                              hipStream_t stream) {
    const float* nf  = (const float*)d_in[0];   // [32, 784, 512] f32
    const float* rel = (const float*)d_in[1];   // [1, 784, 784] f32 (already -rel)
    float* inv_norm  = (float*)d_ws;            // [25088]
    float* sq        = inv_norm + B_ * N_;      // [25088]
    int*   out       = (int*)d_out;

    size_t need = (size_t)2 * B_ * N_ * sizeof(float)
                + (size_t)2 * B_ * N_ * D_ * sizeof(unsigned short);
    if (ws_size >= need) {
        unsigned short* xhi = (unsigned short*)(sq + B_ * N_);
        unsigned short* xlo = xhi + (size_t)B_ * N_ * D_;
        norm_convert_kernel<<<(B_ * N_) / 4, 256, 0, stream>>>(nf, inv_norm, sq, xhi, xlo);
        dist16_topk<<<8 * 4 * TILES, 256, 0, stream>>>(xhi, xlo, rel, inv_norm, sq, out);
    } else {
        norm_kernel<<<(B_ * N_) / 4, 256, 0, stream>>>(nf, inv_norm, sq);
        dist_topk_kernel<<<B_ * TILES, 256, 0, stream>>>(nf, rel, inv_norm, sq, out);
    }
}

// Round 4
// 538.284 us; speedup vs baseline: 1.9047x; 1.0592x over previous
//
#include <hip/hip_runtime.h>
#include <math.h>

#define B_    32
#define N_    784
#define D_    512
#define K_    10
#define RES_  28
#define INF_  100000.0f
#define TM    16
#define DK    128
#define TILES (N_ / TM)   // 49
#define BIGF  3.0e38f
#define LDSW  788         // padded dist row stride (floats): 2-way bank alias only

typedef __attribute__((ext_vector_type(8))) short short8;
typedef __attribute__((ext_vector_type(4))) float f32x4;

__device__ __forceinline__ unsigned short f2bf(float f) {
    unsigned u = __float_as_uint(f);
    unsigned r = (u + 0x7fffu + ((u >> 16) & 1u)) >> 16;   // RNE
    return (unsigned short)r;
}
__device__ __forceinline__ float bf2f(unsigned short h) {
    return __uint_as_float(((unsigned)h) << 16);
}

// ---------------------------------------------------------------------------
// Kernel A (main path): per-row inv_norm & sq, plus split-bf16 conversion
// x = hi + lo with hi=bf16(x), lo=bf16(x-hi). One wave per row.
// ---------------------------------------------------------------------------
__global__ __launch_bounds__(256) void norm_convert_kernel(
    const float* __restrict__ nf, float* __restrict__ inv_norm,
    float* __restrict__ sq, unsigned short* __restrict__ xhi,
    unsigned short* __restrict__ xlo)
{
    int wave = threadIdx.x >> 6;
    int lane = threadIdx.x & 63;
    int row  = blockIdx.x * 4 + wave;           // grid exactly covers B_*N_
    const float* rp = nf + (size_t)row * D_;
    float4 a = *(const float4*)(rp + lane * 8);
    float4 b = *(const float4*)(rp + lane * 8 + 4);
    float v[8] = {a.x, a.y, a.z, a.w, b.x, b.y, b.z, b.w};

    float s = 0.f;
    #pragma unroll
    for (int i = 0; i < 8; i++) s = fmaf(v[i], v[i], s);
    #pragma unroll
    for (int off = 32; off >= 1; off >>= 1)
        s += __shfl_xor(s, off, 64);
    if (lane == 0) {
        float nrm = sqrtf(s);
        float iv  = 1.0f / fmaxf(nrm, 1e-12f);
        inv_norm[row] = iv;
        sq[row]       = s * iv * iv;
    }

    unsigned short h[8], l[8];
    #pragma unroll
    for (int i = 0; i < 8; i++) {
        h[i] = f2bf(v[i]);
        float hf = bf2f(h[i]);
        l[i] = f2bf(v[i] - hf);
    }
    size_t off16 = (size_t)row * D_ + lane * 8;
    short8 h8, l8;
    #pragma unroll
    for (int i = 0; i < 8; i++) { h8[i] = (short)h[i]; l8[i] = (short)l[i]; }
    *(short8*)(xhi + off16) = h8;
    *(short8*)(xlo + off16) = l8;
}

// ---------------------------------------------------------------------------
// Kernel B (main path): one block = (batch, 16-row tile). A fragments for the
// FULL K=512 in registers. Col-tile pairs; per pair SIX independent MFMA
// accumulator chains (3 per tile: al*bh, ah*bl, ah*bh) + explicit 1-K-step
// B-fragment prefetch to keep L2 loads a full step ahead of consumption.
// Epilogue: distance formula -> padded LDS -> register-resident top-10.
// ---------------------------------------------------------------------------
__global__ __launch_bounds__(256, 2) void dist16_topk(
    const unsigned short* __restrict__ xhi, const unsigned short* __restrict__ xlo,
    const float* __restrict__ rel, const float* __restrict__ inv_norm,
    const float* __restrict__ sqv, int* __restrict__ out)
{
    __shared__ float distS[TM][LDSW];   // 50432 B

    const int tid  = threadIdx.x;
    const int wv   = tid >> 6;
    const int lane = tid & 63;
    const int quad = lane >> 4;
    const int l16  = lane & 15;

    // 1568 blocks = 8 XCDs * (4 batches * 49 row-tiles): keep one batch's
    // split arrays (3.2 MB) resident in one XCD's 4 MB L2.
    int gb   = blockIdx.x;
    int xcd  = gb & 7;
    int loc  = gb >> 3;                  // 0..195
    int b    = xcd * 4 + loc / TILES;
    int tile = loc % TILES;
    const int    n0   = tile * TM;
    const size_t base = (size_t)b * N_;

    const unsigned short* hb = xhi + base * D_;
    const unsigned short* lb = xlo + base * D_;

    // ---- A fragments, full K, in registers ----
    const size_t arow = (size_t)(n0 + l16) * D_;
    short8 ah[16], al[16];
    #pragma unroll
    for (int t = 0; t < 16; ++t) {
        int koff = t * 32 + quad * 8;
        ah[t] = *(const short8*)(hb + arow + koff);
        al[t] = *(const short8*)(lb + arow + koff);
    }

    // ---- per-row epilogue constants (loop-invariant) ----
    float invn[4], sqn[4];
    int   rr[4], rc[4];
    #pragma unroll
    for (int reg = 0; reg < 4; ++reg) {
        int n = n0 + quad * 4 + reg;
        invn[reg] = inv_norm[base + n];
        sqn[reg]  = sqv[base + n];
        rr[reg]   = n / RES_;
        rc[reg]   = n % RES_;
    }

    // ---- col-tile pairs: wave wv owns tiles {wv, wv+4, wv+8, ...} ----
    for (int j0 = 0; j0 < 13; j0 += 2) {
        int  t0 = wv + 4 * j0;
        int  t1 = t0 + 4;
        bool v1 = (t1 < TILES);          // wave-uniform
        if (t0 >= TILES) break;          // wave-uniform

        size_t brow0 = (size_t)(t0 * TM + l16) * D_;
        size_t brow1 = v1 ? (size_t)(t1 * TM + l16) * D_ : brow0;

        // 6 independent accumulator chains
        f32x4 a0a = {0.f,0.f,0.f,0.f}, a0b = {0.f,0.f,0.f,0.f}, a0c = {0.f,0.f,0.f,0.f};
        f32x4 a1a = {0.f,0.f,0.f,0.f}, a1b = {0.f,0.f,0.f,0.f}, a1c = {0.f,0.f,0.f,0.f};

        // software pipeline: cur/next rotating B fragments
        int k0 = quad * 8;
        short8 c0h = *(const short8*)(hb + brow0 + k0);
        short8 c0l = *(const short8*)(lb + brow0 + k0);
        short8 c1h = *(const short8*)(hb + brow1 + k0);
        short8 c1l = *(const short8*)(lb + brow1 + k0);

        #pragma unroll
        for (int t = 0; t < 16; ++t) {
            short8 n0h, n0l, n1h, n1l;
            if (t < 15) {
                int kn = (t + 1) * 32 + quad * 8;
                n0h = *(const short8*)(hb + brow0 + kn);
                n0l = *(const short8*)(lb + brow0 + kn);
                n1h = *(const short8*)(hb + brow1 + kn);
                n1l = *(const short8*)(lb + brow1 + kn);
            }
            a0a = __builtin_amdgcn_mfma_f32_16x16x32_bf16(al[t], c0h, a0a, 0, 0, 0);
            a1a = __builtin_amdgcn_mfma_f32_16x16x32_bf16(al[t], c1h, a1a, 0, 0, 0);
            a0b = __builtin_amdgcn_mfma_f32_16x16x32_bf16(ah[t], c0l, a0b, 0, 0, 0);
            a1b = __builtin_amdgcn_mfma_f32_16x16x32_bf16(ah[t], c1l, a1b, 0, 0, 0);
            a0c = __builtin_amdgcn_mfma_f32_16x16x32_bf16(ah[t], c0h, a0c, 0, 0, 0);
            a1c = __builtin_amdgcn_mfma_f32_16x16x32_bf16(ah[t], c1h, a1c, 0, 0, 0);
            if (t < 15) {
                c0h = n0h; c0l = n0l; c1h = n1h; c1l = n1l;
            }
        }

        #pragma unroll
        for (int p = 0; p < 2; ++p) {
            if (p == 1 && !v1) break;    // wave-uniform
            int tt = (p == 0) ? t0 : t1;
            f32x4 av;
            if (p == 0) { av = a0a; av += a0b; av += a0c; }
            else        { av = a1a; av += a1b; av += a1c; }
            int m = tt * TM + l16;
            float invm = inv_norm[base + m];
            float sqm  = sqv[base + m];
            int mr = m / RES_, mc = m % RES_;
            #pragma unroll
            for (int reg = 0; reg < 4; ++reg) {
                int n = n0 + quad * 4 + reg;
                float d = sqn[reg] + sqm - 2.f * invn[reg] * invm * av[reg]
                        + rel[(size_t)n * N_ + m];
                int dr = rr[reg] - mr; if (dr < 0) dr = -dr;
                int dc = rc[reg] - mc; if (dc < 0) dc = -dc;
                if (dr <= 1 && dc <= 1) d += INF_;
                distS[quad * 4 + reg][m] = d;
            }
        }
    }
    __syncthreads();

    // ---- top-K: wave wv handles rows wv*4 .. wv*4+3 ----
    for (int r = 0; r < 4; ++r) {
        int nl = wv * 4 + r;
        int ng = n0 + nl;
        float vals[13];
        #pragma unroll
        for (int j = 0; j < 13; j++) {
            int mm = lane + 64 * j;
            vals[j] = (mm < N_) ? distS[nl][mm] : BIGF;
        }
        size_t outbase = (size_t)(base + ng) * K_ * 3;
        for (int k = 0; k < K_; k++) {
            float bd = vals[0]; int bi = lane;
            #pragma unroll
            for (int j = 1; j < 13; j++) {
                int mm = lane + 64 * j;
                if (vals[j] < bd || (vals[j] == bd && mm < bi)) { bd = vals[j]; bi = mm; }
            }
            float cd = bd; int ci = bi;
            #pragma unroll
            for (int off = 32; off >= 1; off >>= 1) {
                float od = __shfl_xor(cd, off, 64);
                int   oi = __shfl_xor(ci, off, 64);
                if (od < cd || (od == cd && oi < ci)) { cd = od; ci = oi; }
            }
            #pragma unroll
            for (int j = 0; j < 13; j++) {
                if (ci == lane + 64 * j) vals[j] = BIGF;
            }
            if (lane == 0) {
                out[outbase + (size_t)k * 3 + 0] = (int)base + ci;
                out[outbase + (size_t)k * 3 + 1] = (int)(base + ng);
                out[outbase + (size_t)k * 3 + 2] = 0;
            }
        }
    }
}

// ===========================================================================
// Fallback path (round-1 fp32 kernels) — used only if ws_size can't hold the
// split-bf16 arrays.
// ===========================================================================
__global__ __launch_bounds__(256) void norm_kernel(const float* __restrict__ nf,
                                                   float* __restrict__ inv_norm,
                                                   float* __restrict__ sq) {
    int wave = threadIdx.x >> 6;
    int lane = threadIdx.x & 63;
    int row  = blockIdx.x * 4 + wave;
    if (row >= B_ * N_) return;
    const float4* p = (const float4*)(nf + (size_t)row * D_);
    float4 a = p[lane * 2];
    float4 b = p[lane * 2 + 1];
    float s = a.x*a.x + a.y*a.y + a.z*a.z + a.w*a.w
            + b.x*b.x + b.y*b.y + b.z*b.z + b.w*b.w;
    #pragma unroll
    for (int off = 32; off >= 1; off >>= 1)
        s += __shfl_xor(s, off, 64);
    if (lane == 0) {
        float nrm = sqrtf(s);
        float iv  = 1.0f / fmaxf(nrm, 1e-12f);
        inv_norm[row] = iv;
        sq[row]       = s * iv * iv;
    }
}

__global__ __launch_bounds__(256) void dist_topk_kernel(
    const float* __restrict__ nf, const float* __restrict__ rel,
    const float* __restrict__ inv_norm, const float* __restrict__ sqv,
    int* __restrict__ out)
{
    __shared__ float As[TM][DK];
    __shared__ float distS[TM][N_];

    const int tid  = threadIdx.x;
    const int b    = blockIdx.x / TILES;
    const int tile = blockIdx.x % TILES;
    const int n0   = tile * TM;
    const size_t baseRow = (size_t)b * N_;

    float acc[TM][4];
    #pragma unroll
    for (int i = 0; i < TM; i++)
        #pragma unroll
        for (int j = 0; j < 4; j++) acc[i][j] = 0.f;

    int  m[4];
    bool mv[4];
    #pragma unroll
    for (int j = 0; j < 4; j++) { m[j] = tid + 256 * j; mv[j] = (m[j] < N_); }

    const float* bbase = nf + baseRow * D_;

    for (int d0 = 0; d0 < D_; d0 += DK) {
        __syncthreads();
        #pragma unroll
        for (int t = 0; t < 2; t++) {
            int f4  = tid + t * 256;
            int row = f4 >> 5;
            int col = (f4 & 31) << 2;
            float4 v = *(const float4*)(nf + (baseRow + n0 + row) * D_ + d0 + col);
            *(float4*)&As[row][col] = v;
        }
        __syncthreads();

        for (int d4 = 0; d4 < DK; d4 += 4) {
            float4 bv[4];
            #pragma unroll
            for (int j = 0; j < 4; j++) {
                if (mv[j]) bv[j] = *(const float4*)(bbase + (size_t)m[j] * D_ + d0 + d4);
                else       bv[j] = make_float4(0.f, 0.f, 0.f, 0.f);
            }
            #pragma unroll
            for (int nl = 0; nl < TM; nl++) {
                float4 av = *(const float4*)&As[nl][d4];
                #pragma unroll
                for (int j = 0; j < 4; j++) {
                    acc[nl][j] = fmaf(av.x, bv[j].x, acc[nl][j]);
                    acc[nl][j] = fmaf(av.y, bv[j].y, acc[nl][j]);
                    acc[nl][j] = fmaf(av.z, bv[j].z, acc[nl][j]);
                    acc[nl][j] = fmaf(av.w, bv[j].w, acc[nl][j]);
                }
            }
        }
    }

    float invm[4], sqm[4];
    #pragma unroll
    for (int j = 0; j < 4; j++) {
        if (mv[j]) { invm[j] = inv_norm[baseRow + m[j]]; sqm[j] = sqv[baseRow + m[j]]; }
        else       { invm[j] = 0.f; sqm[j] = 0.f; }
    }
    #pragma unroll
    for (int nl = 0; nl < TM; nl++) {
        int ng = n0 + nl;
        float invn = inv_norm[baseRow + ng];
        float sqn  = sqv[baseRow + ng];
        int r1 = ng / RES_, c1 = ng % RES_;
        #pragma unroll
        for (int j = 0; j < 4; j++) {
            if (!mv[j]) continue;
            int mm = m[j];
            float d = sqn + sqm[j] - 2.f * invn * invm[j] * acc[nl][j]
                    + rel[(size_t)ng * N_ + mm];
            int r2 = mm / RES_, c2 = mm % RES_;
            int dr = r1 - r2; if (dr < 0) dr = -dr;
            int dc = c1 - c2; if (dc < 0) dc = -dc;
            if (dr <= 1 && dc <= 1) d += INF_;
            distS[nl][mm] = d;
        }
    }
    __syncthreads();

    const int wv   = tid >> 6;
    const int lane = tid & 63;
    for (int r = 0; r < 4; r++) {
        int nl = wv * 4 + r;
        int ng = n0 + nl;
        float vals[13];
        #pragma unroll
        for (int j = 0; j < 13; j++) {
            int mm = lane + 64 * j;
            vals[j] = (mm < N_) ? distS[nl][mm] : BIGF;
        }
        size_t outbase = (size_t)(baseRow + ng) * K_ * 3;
        for (int k = 0; k < K_; k++) {
            float bd = vals[0]; int bi = lane;
            #pragma unroll
            for (int j = 1; j < 13; j++) {
                int mm = lane + 64 * j;
                if (vals[j] < bd || (vals[j] == bd && mm < bi)) { bd = vals[j]; bi = mm; }
            }
            float cd = bd; int ci = bi;
            #pragma unroll
            for (int off = 32; off >= 1; off >>= 1) {
                float od = __shfl_xor(cd, off, 64);
                int   oi = __shfl_xor(ci, off, 64);
                if (od < cd || (od == cd && oi < ci)) { cd = od; ci = oi; }
            }
            #pragma unroll
            for (int j = 0; j < 13; j++) {
                if (ci == lane + 64 * j) vals[j] = BIGF;
            }
            if (lane == 0) {
                out[outbase + (size_t)k * 3 + 0] = (int)baseRow + ci;
                out[outbase + (size_t)k * 3 + 1] = (int)(baseRow + ng);
                out[outbase + (size_t)k * 3 + 2] = 0;
            }
        }
    }
}

extern "C" void kernel_launch(void* const* d_in, const int* in_sizes, int n_in,
                              void* d_out, int out_size, void* d_ws, size_t ws_size,
                              hipStream_t stream) {
    const float* nf  = (const float*)d_in[0];   // [32, 784, 512] f32
    const float* rel = (const float*)d_in[1];   // [1, 784, 784] f32 (already -rel)
    float* inv_norm  = (float*)d_ws;            // [25088]
    float* sq        = inv_norm + B_ * N_;      // [25088]
    int*   out       = (int*)d_out;

    size_t need = (size_t)2 * B_ * N_ * sizeof(float)
                + (size_t)2 * B_ * N_ * D_ * sizeof(unsigned short);
    if (ws_size >= need) {
        unsigned short* xhi = (unsigned short*)(sq + B_ * N_);
        unsigned short* xlo = xhi + (size_t)B_ * N_ * D_;
        norm_convert_kernel<<<(B_ * N_) / 4, 256, 0, stream>>>(nf, inv_norm, sq, xhi, xlo);
        dist16_topk<<<8 * 4 * TILES, 256, 0, stream>>>(xhi, xlo, rel, inv_norm, sq, out);
    } else {
        norm_kernel<<<(B_ * N_) / 4, 256, 0, stream>>>(nf, inv_norm, sq);
        dist_topk_kernel<<<B_ * TILES, 256, 0, stream>>>(nf, rel, inv_norm, sq, out);
    }
}

// Round 5
// 288.433 us; speedup vs baseline: 3.5546x; 1.8662x over previous
//
#include <hip/hip_runtime.h>
#include <math.h>

#define B_    32
#define N_    784
#define D_    512
#define K_    10
#define RES_  28
#define INF_  100000.0f
#define TM    16
#define DK    128
#define TILES (N_ / TM)   // 49
#define BIGF  3.0e38f
#define LDSW  788         // fallback kernel's padded dist row stride
#define BROW  520         // LDS B-tile row stride in shorts (1040 B: 2-way-free banks)

typedef __attribute__((ext_vector_type(8))) short short8;
typedef __attribute__((ext_vector_type(4))) float f32x4;

__device__ __forceinline__ unsigned short f2bf(float f) {
    unsigned u = __float_as_uint(f);
    unsigned r = (u + 0x7fffu + ((u >> 16) & 1u)) >> 16;   // RNE
    return (unsigned short)r;
}
__device__ __forceinline__ float bf2f(unsigned short h) {
    return __uint_as_float(((unsigned)h) << 16);
}

// async global->LDS, 16 B per lane. HW semantics: LDS dest = uniform base +
// lane*16; global src is the per-lane address.
__device__ __forceinline__ void gl_lds16(const void* g, void* l) {
    __builtin_amdgcn_global_load_lds(
        (const __attribute__((address_space(1))) unsigned int*)g,
        (__attribute__((address_space(3))) unsigned int*)(void*)l, 16, 0, 0);
}

// ---------------------------------------------------------------------------
// Kernel A: per-row inv_norm & sq, plus split-bf16 conversion
// x = hi + lo with hi=bf16(x), lo=bf16(x-hi). One wave per row.
// ---------------------------------------------------------------------------
__global__ __launch_bounds__(256) void norm_convert_kernel(
    const float* __restrict__ nf, float* __restrict__ inv_norm,
    float* __restrict__ sq, unsigned short* __restrict__ xhi,
    unsigned short* __restrict__ xlo)
{
    int wave = threadIdx.x >> 6;
    int lane = threadIdx.x & 63;
    int row  = blockIdx.x * 4 + wave;           // grid exactly covers B_*N_
    const float* rp = nf + (size_t)row * D_;
    float4 a = *(const float4*)(rp + lane * 8);
    float4 b = *(const float4*)(rp + lane * 8 + 4);
    float v[8] = {a.x, a.y, a.z, a.w, b.x, b.y, b.z, b.w};

    float s = 0.f;
    #pragma unroll
    for (int i = 0; i < 8; i++) s = fmaf(v[i], v[i], s);
    #pragma unroll
    for (int off = 32; off >= 1; off >>= 1)
        s += __shfl_xor(s, off, 64);
    if (lane == 0) {
        float nrm = sqrtf(s);
        float iv  = 1.0f / fmaxf(nrm, 1e-12f);
        inv_norm[row] = iv;
        sq[row]       = s * iv * iv;
    }

    unsigned short h[8], l[8];
    #pragma unroll
    for (int i = 0; i < 8; i++) {
        h[i] = f2bf(v[i]);
        float hf = bf2f(h[i]);
        l[i] = f2bf(v[i] - hf);
    }
    size_t off16 = (size_t)row * D_ + lane * 8;
    short8 h8, l8;
    #pragma unroll
    for (int i = 0; i < 8; i++) { h8[i] = (short)h[i]; l8[i] = (short)l[i]; }
    *(short8*)(xhi + off16) = h8;
    *(short8*)(xlo + off16) = l8;
}

// ---------------------------------------------------------------------------
// Kernel B: one block = (batch, 64 rows). Wave wv owns row-tile wv. A frags
// (full K=512, hi+lo) in registers. B tiles staged hi+lo into LDS with
// double-buffered async global_load_lds (one row = one wave-instr of 16B/lane),
// consumed via ds_read_b128. 3 independent MFMA chains per K-step. Epilogue
// applies bias+mask and stores final dist rows to global scratch.
// ---------------------------------------------------------------------------
__global__ __launch_bounds__(256, 2) void gemm64(
    const unsigned short* __restrict__ xhi, const unsigned short* __restrict__ xlo,
    const float* __restrict__ rel, const float* __restrict__ inv_norm,
    const float* __restrict__ sqv, float* __restrict__ dist)
{
    __shared__ unsigned short Bs[2][2][16 * BROW];   // 66560 B

    const int tid  = threadIdx.x;
    const int wv   = tid >> 6;
    const int lane = tid & 63;
    const int quad = lane >> 4;
    const int l16  = lane & 15;

    // 416 blocks = 8 XCDs * (4 batches * 13 row-blocks): one batch's split
    // arrays (3.2 MB) stay resident in one XCD's 4 MB L2.
    int gb  = blockIdx.x;
    int xcd = gb & 7;
    int loc = gb >> 3;                  // 0..51
    int b   = xcd * 4 + loc / 13;
    int blk = loc % 13;
    const int    n0   = blk * 64;
    const int    nw   = n0 + wv * 16;           // this wave's row-tile
    const bool   wval = (nw < N_);              // wave-uniform (ragged last block)
    const int    nrow = wval ? nw : (N_ - TM);  // clamp for loads
    const size_t base = (size_t)b * N_;

    const unsigned short* hb = xhi + base * D_;
    const unsigned short* lb = xlo + base * D_;

    // ---- A fragments, full K, in registers ----
    const size_t arow = (size_t)(nrow + l16) * D_;
    short8 ah[16], al[16];
    #pragma unroll
    for (int t = 0; t < 16; ++t) {
        int koff = t * 32 + quad * 8;
        ah[t] = *(const short8*)(hb + arow + koff);
        al[t] = *(const short8*)(lb + arow + koff);
    }

    // ---- per-row epilogue constants ----
    float invn[4], sqn[4];
    int   rr[4], rc[4];
    #pragma unroll
    for (int reg = 0; reg < 4; ++reg) {
        int n = nrow + quad * 4 + reg;
        invn[reg] = inv_norm[base + n];
        sqn[reg]  = sqv[base + n];
        rr[reg]   = n / RES_;
        rc[reg]   = n % RES_;
    }

    // ---- stage tile 0 ----
    {
        const unsigned short* gh = hb + (size_t)0 * D_;   // tile 0 rows start at col row 0
        const unsigned short* gl = lb;
        #pragma unroll
        for (int j = 0; j < 4; ++j) {
            int r = wv * 4 + j;
            gl_lds16(gh + (size_t)r * D_ + lane * 8, &Bs[0][0][r * BROW]);
            gl_lds16(gl + (size_t)r * D_ + lane * 8, &Bs[0][1][r * BROW]);
        }
    }
    __syncthreads();   // drains vmcnt: tile 0 staged

    for (int t = 0; t < TILES; ++t) {
        const int cur = t & 1;
        if (t + 1 < TILES) {
            const int nxt = (t + 1) & 1;
            const size_t rbase = (size_t)(t + 1) * TM;
            #pragma unroll
            for (int j = 0; j < 4; ++j) {
                int r = wv * 4 + j;
                gl_lds16(hb + (rbase + r) * D_ + lane * 8, &Bs[nxt][0][r * BROW]);
                gl_lds16(lb + (rbase + r) * D_ + lane * 8, &Bs[nxt][1][r * BROW]);
            }
        }

        // epilogue operands for this tile (issued early, used after K-loop)
        int   m    = t * TM + l16;
        float invm = inv_norm[base + m];
        float sqm  = sqv[base + m];
        float relv[4];
        #pragma unroll
        for (int reg = 0; reg < 4; ++reg)
            relv[reg] = rel[(size_t)(nrow + quad * 4 + reg) * N_ + m];

        f32x4 aA = {0.f,0.f,0.f,0.f}, aB = {0.f,0.f,0.f,0.f}, aC = {0.f,0.f,0.f,0.f};
        #pragma unroll
        for (int k = 0; k < 16; ++k) {
            int boff = l16 * BROW + k * 32 + quad * 8;
            short8 bh = *(const short8*)&Bs[cur][0][boff];
            short8 bl = *(const short8*)&Bs[cur][1][boff];
            aA = __builtin_amdgcn_mfma_f32_16x16x32_bf16(al[k], bh, aA, 0, 0, 0);
            aB = __builtin_amdgcn_mfma_f32_16x16x32_bf16(ah[k], bl, aB, 0, 0, 0);
            aC = __builtin_amdgcn_mfma_f32_16x16x32_bf16(ah[k], bh, aC, 0, 0, 0);
        }

        if (wval) {
            int mr = m / RES_, mc = m % RES_;
            #pragma unroll
            for (int reg = 0; reg < 4; ++reg) {
                int n = nrow + quad * 4 + reg;
                float dot = aA[reg] + aB[reg] + aC[reg];
                float d = sqn[reg] + sqm - 2.f * invn[reg] * invm * dot + relv[reg];
                int dr = rr[reg] - mr; if (dr < 0) dr = -dr;
                int dc = rc[reg] - mc; if (dc < 0) dc = -dc;
                if (dr <= 1 && dc <= 1) d += INF_;
                dist[(base + n) * (size_t)N_ + m] = d;
            }
        }
        __syncthreads();   // staged t+1 complete; all waves done with Bs[cur]
    }
}

// ---------------------------------------------------------------------------
// Kernel C: one block = (batch, 16-row tile). Cooperative load of the dist
// slab into LDS, then the proven register-resident butterfly top-10.
// ---------------------------------------------------------------------------
__global__ __launch_bounds__(256) void topk16(
    const float* __restrict__ dist, int* __restrict__ out)
{
    __shared__ float distS[TM][N_];   // 50176 B

    const int tid  = threadIdx.x;
    const int wv   = tid >> 6;
    const int lane = tid & 63;

    // 1568 blocks = 8 XCDs * (4 batches * 49 tiles): match gemm64's writer XCD.
    int gb  = blockIdx.x;
    int xcd = gb & 7;
    int loc = gb >> 3;                  // 0..195
    int b   = xcd * 4 + loc / TILES;
    int tile = loc % TILES;
    const int    n0   = tile * TM;
    const size_t base = (size_t)b * N_;

    const float4* src = (const float4*)(dist + (base + n0) * (size_t)N_);
    float4* dst = (float4*)&distS[0][0];
    for (int i = tid; i < TM * N_ / 4; i += 256) dst[i] = src[i];
    __syncthreads();

    for (int r = 0; r < 4; ++r) {
        int nl = wv * 4 + r;
        int ng = n0 + nl;
        float vals[13];
        #pragma unroll
        for (int j = 0; j < 13; j++) {
            int mm = lane + 64 * j;
            vals[j] = (mm < N_) ? distS[nl][mm] : BIGF;
        }
        size_t outbase = (size_t)(base + ng) * K_ * 3;
        for (int k = 0; k < K_; k++) {
            float bd = vals[0]; int bi = lane;
            #pragma unroll
            for (int j = 1; j < 13; j++) {
                int mm = lane + 64 * j;
                if (vals[j] < bd || (vals[j] == bd && mm < bi)) { bd = vals[j]; bi = mm; }
            }
            float cd = bd; int ci = bi;
            #pragma unroll
            for (int off = 32; off >= 1; off >>= 1) {
                float od = __shfl_xor(cd, off, 64);
                int   oi = __shfl_xor(ci, off, 64);
                if (od < cd || (od == cd && oi < ci)) { cd = od; ci = oi; }
            }
            #pragma unroll
            for (int j = 0; j < 13; j++) {
                if (ci == lane + 64 * j) vals[j] = BIGF;
            }
            if (lane == 0) {
                out[outbase + (size_t)k * 3 + 0] = (int)base + ci;
                out[outbase + (size_t)k * 3 + 1] = (int)(base + ng);
                out[outbase + (size_t)k * 3 + 2] = 0;
            }
        }
    }
}

// ===========================================================================
// Fallback (round-4 proven path) — used only if ws can't hold dist scratch.
// ===========================================================================
__global__ __launch_bounds__(256, 2) void dist16_topk(
    const unsigned short* __restrict__ xhi, const unsigned short* __restrict__ xlo,
    const float* __restrict__ rel, const float* __restrict__ inv_norm,
    const float* __restrict__ sqv, int* __restrict__ out)
{
    __shared__ float distS[TM][LDSW];

    const int tid  = threadIdx.x;
    const int wv   = tid >> 6;
    const int lane = tid & 63;
    const int quad = lane >> 4;
    const int l16  = lane & 15;

    int gb   = blockIdx.x;
    int xcd  = gb & 7;
    int loc  = gb >> 3;
    int b    = xcd * 4 + loc / TILES;
    int tile = loc % TILES;
    const int    n0   = tile * TM;
    const size_t base = (size_t)b * N_;

    const unsigned short* hb = xhi + base * D_;
    const unsigned short* lb = xlo + base * D_;

    const size_t arow = (size_t)(n0 + l16) * D_;
    short8 ah[16], al[16];
    #pragma unroll
    for (int t = 0; t < 16; ++t) {
        int koff = t * 32 + quad * 8;
        ah[t] = *(const short8*)(hb + arow + koff);
        al[t] = *(const short8*)(lb + arow + koff);
    }

    float invn[4], sqn[4];
    int   rr[4], rc[4];
    #pragma unroll
    for (int reg = 0; reg < 4; ++reg) {
        int n = n0 + quad * 4 + reg;
        invn[reg] = inv_norm[base + n];
        sqn[reg]  = sqv[base + n];
        rr[reg]   = n / RES_;
        rc[reg]   = n % RES_;
    }

    for (int j0 = 0; j0 < 13; j0 += 2) {
        int  t0 = wv + 4 * j0;
        int  t1 = t0 + 4;
        bool v1 = (t1 < TILES);
        if (t0 >= TILES) break;

        size_t brow0 = (size_t)(t0 * TM + l16) * D_;
        size_t brow1 = v1 ? (size_t)(t1 * TM + l16) * D_ : brow0;

        f32x4 a0a = {0.f,0.f,0.f,0.f}, a0b = {0.f,0.f,0.f,0.f}, a0c = {0.f,0.f,0.f,0.f};
        f32x4 a1a = {0.f,0.f,0.f,0.f}, a1b = {0.f,0.f,0.f,0.f}, a1c = {0.f,0.f,0.f,0.f};

        int k0 = quad * 8;
        short8 c0h = *(const short8*)(hb + brow0 + k0);
        short8 c0l = *(const short8*)(lb + brow0 + k0);
        short8 c1h = *(const short8*)(hb + brow1 + k0);
        short8 c1l = *(const short8*)(lb + brow1 + k0);

        #pragma unroll
        for (int t = 0; t < 16; ++t) {
            short8 n0h, n0l, n1h, n1l;
            if (t < 15) {
                int kn = (t + 1) * 32 + quad * 8;
                n0h = *(const short8*)(hb + brow0 + kn);
                n0l = *(const short8*)(lb + brow0 + kn);
                n1h = *(const short8*)(hb + brow1 + kn);
                n1l = *(const short8*)(lb + brow1 + kn);
            }
            a0a = __builtin_amdgcn_mfma_f32_16x16x32_bf16(al[t], c0h, a0a, 0, 0, 0);
            a1a = __builtin_amdgcn_mfma_f32_16x16x32_bf16(al[t], c1h, a1a, 0, 0, 0);
            a0b = __builtin_amdgcn_mfma_f32_16x16x32_bf16(ah[t], c0l, a0b, 0, 0, 0);
            a1b = __builtin_amdgcn_mfma_f32_16x16x32_bf16(ah[t], c1l, a1b, 0, 0, 0);
            a0c = __builtin_amdgcn_mfma_f32_16x16x32_bf16(ah[t], c0h, a0c, 0, 0, 0);
            a1c = __builtin_amdgcn_mfma_f32_16x16x32_bf16(ah[t], c1h, a1c, 0, 0, 0);
            if (t < 15) { c0h = n0h; c0l = n0l; c1h = n1h; c1l = n1l; }
        }

        #pragma unroll
        for (int p = 0; p < 2; ++p) {
            if (p == 1 && !v1) break;
            int tt = (p == 0) ? t0 : t1;
            f32x4 av;
            if (p == 0) { av = a0a; av += a0b; av += a0c; }
            else        { av = a1a; av += a1b; av += a1c; }
            int m = tt * TM + l16;
            float invm = inv_norm[base + m];
            float sqm  = sqv[base + m];
            int mr = m / RES_, mc = m % RES_;
            #pragma unroll
            for (int reg = 0; reg < 4; ++reg) {
                int n = n0 + quad * 4 + reg;
                float d = sqn[reg] + sqm - 2.f * invn[reg] * invm * av[reg]
                        + rel[(size_t)n * N_ + m];
                int dr = rr[reg] - mr; if (dr < 0) dr = -dr;
                int dc = rc[reg] - mc; if (dc < 0) dc = -dc;
                if (dr <= 1 && dc <= 1) d += INF_;
                distS[quad * 4 + reg][m] = d;
            }
        }
    }
    __syncthreads();

    for (int r = 0; r < 4; ++r) {
        int nl = wv * 4 + r;
        int ng = n0 + nl;
        float vals[13];
        #pragma unroll
        for (int j = 0; j < 13; j++) {
            int mm = lane + 64 * j;
            vals[j] = (mm < N_) ? distS[nl][mm] : BIGF;
        }
        size_t outbase = (size_t)(base + ng) * K_ * 3;
        for (int k = 0; k < K_; k++) {
            float bd = vals[0]; int bi = lane;
            #pragma unroll
            for (int j = 1; j < 13; j++) {
                int mm = lane + 64 * j;
                if (vals[j] < bd || (vals[j] == bd && mm < bi)) { bd = vals[j]; bi = mm; }
            }
            float cd = bd; int ci = bi;
            #pragma unroll
            for (int off = 32; off >= 1; off >>= 1) {
                float od = __shfl_xor(cd, off, 64);
                int   oi = __shfl_xor(ci, off, 64);
                if (od < cd || (od == cd && oi < ci)) { cd = od; ci = oi; }
            }
            #pragma unroll
            for (int j = 0; j < 13; j++) {
                if (ci == lane + 64 * j) vals[j] = BIGF;
            }
            if (lane == 0) {
                out[outbase + (size_t)k * 3 + 0] = (int)base + ci;
                out[outbase + (size_t)k * 3 + 1] = (int)(base + ng);
                out[outbase + (size_t)k * 3 + 2] = 0;
            }
        }
    }
}

extern "C" void kernel_launch(void* const* d_in, const int* in_sizes, int n_in,
                              void* d_out, int out_size, void* d_ws, size_t ws_size,
                              hipStream_t stream) {
    const float* nf  = (const float*)d_in[0];   // [32, 784, 512] f32
    const float* rel = (const float*)d_in[1];   // [1, 784, 784] f32 (already -rel)
    float* inv_norm  = (float*)d_ws;            // [25088]
    float* sq        = inv_norm + B_ * N_;      // [25088]
    int*   out       = (int*)d_out;

    unsigned short* xhi = (unsigned short*)(sq + B_ * N_);
    unsigned short* xlo = xhi + (size_t)B_ * N_ * D_;
    float* dist = (float*)(xlo + (size_t)B_ * N_ * D_);   // [32*784*784]

    size_t need_full = (size_t)2 * B_ * N_ * sizeof(float)
                     + (size_t)2 * B_ * N_ * D_ * sizeof(unsigned short)
                     + (size_t)B_ * N_ * N_ * sizeof(float);

    norm_convert_kernel<<<(B_ * N_) / 4, 256, 0, stream>>>(nf, inv_norm, sq, xhi, xlo);
    if (ws_size >= need_full) {
        gemm64<<<8 * 4 * 13, 256, 0, stream>>>(xhi, xlo, rel, inv_norm, sq, dist);
        topk16<<<8 * 4 * TILES, 256, 0, stream>>>(dist, out);
    } else {
        dist16_topk<<<8 * 4 * TILES, 256, 0, stream>>>(xhi, xlo, rel, inv_norm, sq, out);
    }
}

// Round 6
// 282.108 us; speedup vs baseline: 3.6342x; 1.0224x over previous
//
#include <hip/hip_runtime.h>
#include <math.h>

#define B_    32
#define N_    784
#define D_    512
#define K_    10
#define RES_  28
#define INF_  100000.0f
#define TM    16
#define TILES (N_ / TM)   // 49
#define BIGF  3.0e38f
#define LDSW  788         // fallback kernel's padded dist row stride
#define BROW  520         // LDS B-tile row stride in shorts (1040 B)

typedef __attribute__((ext_vector_type(8))) short short8;
typedef __attribute__((ext_vector_type(4))) float f32x4;

__device__ __forceinline__ unsigned short f2bf(float f) {
    unsigned u = __float_as_uint(f);
    unsigned r = (u + 0x7fffu + ((u >> 16) & 1u)) >> 16;   // RNE
    return (unsigned short)r;
}
__device__ __forceinline__ float bf2f(unsigned short h) {
    return __uint_as_float(((unsigned)h) << 16);
}

// async global->LDS, 16 B per lane: LDS dest = uniform base + lane*16.
__device__ __forceinline__ void gl_lds16(const void* g, void* l) {
    __builtin_amdgcn_global_load_lds(
        (const __attribute__((address_space(1))) unsigned int*)g,
        (__attribute__((address_space(3))) unsigned int*)(void*)l, 16, 0, 0);
}

// ---------------------------------------------------------------------------
// Kernel A: per-row inv_norm & sq, plus split-bf16 conversion
// x = hi + lo with hi=bf16(x), lo=bf16(x-hi). One wave per row.
// ---------------------------------------------------------------------------
__global__ __launch_bounds__(256) void norm_convert_kernel(
    const float* __restrict__ nf, float* __restrict__ inv_norm,
    float* __restrict__ sq, unsigned short* __restrict__ xhi,
    unsigned short* __restrict__ xlo)
{
    int wave = threadIdx.x >> 6;
    int lane = threadIdx.x & 63;
    int row  = blockIdx.x * 4 + wave;           // grid exactly covers B_*N_
    const float* rp = nf + (size_t)row * D_;
    float4 a = *(const float4*)(rp + lane * 8);
    float4 b = *(const float4*)(rp + lane * 8 + 4);
    float v[8] = {a.x, a.y, a.z, a.w, b.x, b.y, b.z, b.w};

    float s = 0.f;
    #pragma unroll
    for (int i = 0; i < 8; i++) s = fmaf(v[i], v[i], s);
    #pragma unroll
    for (int off = 32; off >= 1; off >>= 1)
        s += __shfl_xor(s, off, 64);
    if (lane == 0) {
        float nrm = sqrtf(s);
        float iv  = 1.0f / fmaxf(nrm, 1e-12f);
        inv_norm[row] = iv;
        sq[row]       = s * iv * iv;
    }

    unsigned short h[8], l[8];
    #pragma unroll
    for (int i = 0; i < 8; i++) {
        h[i] = f2bf(v[i]);
        float hf = bf2f(h[i]);
        l[i] = f2bf(v[i] - hf);
    }
    size_t off16 = (size_t)row * D_ + lane * 8;
    short8 h8, l8;
    #pragma unroll
    for (int i = 0; i < 8; i++) { h8[i] = (short)h[i]; l8[i] = (short)l[i]; }
    *(short8*)(xhi + off16) = h8;
    *(short8*)(xlo + off16) = l8;
}

// ---------------------------------------------------------------------------
// Kernel B: block = 2 waves, 64 rows. Each wave owns TWO 16-row A-tiles
// (full K=512 hi+lo resident: 256 VGPRs, 1 wave/SIMD) so every B fragment
// read from LDS feeds 6 MFMAs (2x the reuse of round 5 -> LDS-BW halves).
// B tiles staged hi+lo via double-buffered async global_load_lds.
// Epilogue applies bias+mask, stores dist rows to global scratch.
// ---------------------------------------------------------------------------
__global__ __launch_bounds__(128, 1) void gemm32(
    const unsigned short* __restrict__ xhi, const unsigned short* __restrict__ xlo,
    const float* __restrict__ rel, const float* __restrict__ inv_norm,
    const float* __restrict__ sqv, float* __restrict__ dist)
{
    __shared__ unsigned short Bs[2][2][16 * BROW];   // 66560 B

    const int tid  = threadIdx.x;
    const int wv   = tid >> 6;          // 0..1
    const int lane = tid & 63;
    const int quad = lane >> 4;
    const int l16  = lane & 15;

    // 416 blocks = 8 XCDs * (4 batches * 13 row-blocks)
    int gb  = blockIdx.x;
    int xcd = gb & 7;
    int loc = gb >> 3;                  // 0..51
    int b   = xcd * 4 + loc / 13;
    int blk = loc % 13;
    const int    n0   = blk * 64;
    const size_t base = (size_t)b * N_;

    // wave's two row-tiles (ragged last block: clamp loads, guard stores)
    const int  rt0   = n0 + wv * 32;
    const int  rt1   = rt0 + 16;
    const bool v0    = (rt0 < N_);      // wave-uniform
    const bool vv1   = (rt1 < N_);
    const int  row0  = v0  ? rt0 : (N_ - TM);
    const int  row1  = vv1 ? rt1 : (N_ - TM);

    const unsigned short* hb = xhi + base * D_;
    const unsigned short* lb = xlo + base * D_;

    // ---- A fragments, full K, both tiles, in registers (256 VGPRs) ----
    const size_t ar0 = (size_t)(row0 + l16) * D_;
    const size_t ar1 = (size_t)(row1 + l16) * D_;
    short8 ah0[16], al0[16], ah1[16], al1[16];
    #pragma unroll
    for (int t = 0; t < 16; ++t) {
        int koff = t * 32 + quad * 8;
        ah0[t] = *(const short8*)(hb + ar0 + koff);
        al0[t] = *(const short8*)(lb + ar0 + koff);
        ah1[t] = *(const short8*)(hb + ar1 + koff);
        al1[t] = *(const short8*)(lb + ar1 + koff);
    }

    // ---- per-row epilogue constants ----
    float invn[2][4], sqn[2][4];
    int   rr[2][4], rc[2][4];
    #pragma unroll
    for (int p = 0; p < 2; ++p) {
        int rbase = p ? row1 : row0;
        #pragma unroll
        for (int reg = 0; reg < 4; ++reg) {
            int n = rbase + quad * 4 + reg;
            invn[p][reg] = inv_norm[base + n];
            sqn[p][reg]  = sqv[base + n];
            rr[p][reg]   = n / RES_;
            rc[p][reg]   = n % RES_;
        }
    }

    // ---- stage tile 0 ----
    #pragma unroll
    for (int j = 0; j < 8; ++j) {
        int r = wv * 8 + j;
        gl_lds16(hb + (size_t)r * D_ + lane * 8, &Bs[0][0][r * BROW]);
        gl_lds16(lb + (size_t)r * D_ + lane * 8, &Bs[0][1][r * BROW]);
    }
    __syncthreads();   // drains vmcnt: tile 0 staged

    for (int t = 0; t < TILES; ++t) {
        const int cur = t & 1;
        if (t + 1 < TILES) {
            const int nxt = (t + 1) & 1;
            const size_t rbase = (size_t)(t + 1) * TM;
            #pragma unroll
            for (int j = 0; j < 8; ++j) {
                int r = wv * 8 + j;
                gl_lds16(hb + (rbase + r) * D_ + lane * 8, &Bs[nxt][0][r * BROW]);
                gl_lds16(lb + (rbase + r) * D_ + lane * 8, &Bs[nxt][1][r * BROW]);
            }
        }

        // epilogue operands for this tile (issued early)
        int   m    = t * TM + l16;
        float invm = inv_norm[base + m];
        float sqm  = sqv[base + m];
        float relv[2][4];
        #pragma unroll
        for (int reg = 0; reg < 4; ++reg) {
            relv[0][reg] = rel[(size_t)(row0 + quad * 4 + reg) * N_ + m];
            relv[1][reg] = rel[(size_t)(row1 + quad * 4 + reg) * N_ + m];
        }

        f32x4 aA0 = {0.f,0.f,0.f,0.f}, aB0 = {0.f,0.f,0.f,0.f}, aC0 = {0.f,0.f,0.f,0.f};
        f32x4 aA1 = {0.f,0.f,0.f,0.f}, aB1 = {0.f,0.f,0.f,0.f}, aC1 = {0.f,0.f,0.f,0.f};
        #pragma unroll
        for (int k = 0; k < 16; ++k) {
            int boff = l16 * BROW + k * 32 + quad * 8;
            short8 bh = *(const short8*)&Bs[cur][0][boff];
            short8 bl = *(const short8*)&Bs[cur][1][boff];
            aA0 = __builtin_amdgcn_mfma_f32_16x16x32_bf16(al0[k], bh, aA0, 0, 0, 0);
            aA1 = __builtin_amdgcn_mfma_f32_16x16x32_bf16(al1[k], bh, aA1, 0, 0, 0);
            aB0 = __builtin_amdgcn_mfma_f32_16x16x32_bf16(ah0[k], bl, aB0, 0, 0, 0);
            aB1 = __builtin_amdgcn_mfma_f32_16x16x32_bf16(ah1[k], bl, aB1, 0, 0, 0);
            aC0 = __builtin_amdgcn_mfma_f32_16x16x32_bf16(ah0[k], bh, aC0, 0, 0, 0);
            aC1 = __builtin_amdgcn_mfma_f32_16x16x32_bf16(ah1[k], bh, aC1, 0, 0, 0);
        }

        int mr = m / RES_, mc = m % RES_;
        #pragma unroll
        for (int p = 0; p < 2; ++p) {
            if (p == 0 && !v0) continue;   // wave-uniform
            if (p == 1 && !vv1) continue;  // wave-uniform
            int rbase = p ? row1 : row0;
            #pragma unroll
            for (int reg = 0; reg < 4; ++reg) {
                int n = rbase + quad * 4 + reg;
                float dot;
                if (p == 0) dot = aA0[reg] + aB0[reg] + aC0[reg];
                else        dot = aA1[reg] + aB1[reg] + aC1[reg];
                float d = sqn[p][reg] + sqm - 2.f * invn[p][reg] * invm * dot
                        + relv[p][reg];
                int dr = rr[p][reg] - mr; if (dr < 0) dr = -dr;
                int dc = rc[p][reg] - mc; if (dc < 0) dc = -dc;
                if (dr <= 1 && dc <= 1) d += INF_;
                dist[(base + n) * (size_t)N_ + m] = d;
            }
        }
        __syncthreads();   // staged t+1 complete; all waves done with Bs[cur]
    }
}

// ---------------------------------------------------------------------------
// Kernel C: one wave per row; reads the dist row DIRECTLY from global
// (13 independent coalesced loads = one latency exposure), then the proven
// register-resident butterfly top-10. No LDS, no syncthreads.
// ---------------------------------------------------------------------------
__global__ __launch_bounds__(256) void topk_direct(
    const float* __restrict__ dist, int* __restrict__ out)
{
    const int row  = blockIdx.x * 4 + (threadIdx.x >> 6);   // 0..25087
    const int lane = threadIdx.x & 63;
    const int b    = row / N_;
    const int ng   = row - b * N_;
    const size_t base = (size_t)b * N_;

    const float* dr = dist + (size_t)row * N_;
    float vals[13];
    #pragma unroll
    for (int j = 0; j < 13; j++) {
        int mm = lane + 64 * j;
        vals[j] = (mm < N_) ? dr[mm] : BIGF;
    }
    size_t outbase = (size_t)row * K_ * 3;
    for (int k = 0; k < K_; k++) {
        float bd = vals[0]; int bi = lane;
        #pragma unroll
        for (int j = 1; j < 13; j++) {
            int mm = lane + 64 * j;
            if (vals[j] < bd || (vals[j] == bd && mm < bi)) { bd = vals[j]; bi = mm; }
        }
        float cd = bd; int ci = bi;
        #pragma unroll
        for (int off = 32; off >= 1; off >>= 1) {
            float od = __shfl_xor(cd, off, 64);
            int   oi = __shfl_xor(ci, off, 64);
            if (od < cd || (od == cd && oi < ci)) { cd = od; ci = oi; }
        }
        #pragma unroll
        for (int j = 0; j < 13; j++) {
            if (ci == lane + 64 * j) vals[j] = BIGF;
        }
        if (lane == 0) {
            out[outbase + (size_t)k * 3 + 0] = (int)base + ci;
            out[outbase + (size_t)k * 3 + 1] = row;
            out[outbase + (size_t)k * 3 + 2] = 0;
        }
    }
}

// ===========================================================================
// Fallback (round-4 proven path) — used only if ws can't hold dist scratch.
// ===========================================================================
__global__ __launch_bounds__(256, 2) void dist16_topk(
    const unsigned short* __restrict__ xhi, const unsigned short* __restrict__ xlo,
    const float* __restrict__ rel, const float* __restrict__ inv_norm,
    const float* __restrict__ sqv, int* __restrict__ out)
{
    __shared__ float distS[TM][LDSW];

    const int tid  = threadIdx.x;
    const int wv   = tid >> 6;
    const int lane = tid & 63;
    const int quad = lane >> 4;
    const int l16  = lane & 15;

    int gb   = blockIdx.x;
    int xcd  = gb & 7;
    int loc  = gb >> 3;
    int b    = xcd * 4 + loc / TILES;
    int tile = loc % TILES;
    const int    n0   = tile * TM;
    const size_t base = (size_t)b * N_;

    const unsigned short* hb = xhi + base * D_;
    const unsigned short* lb = xlo + base * D_;

    const size_t arow = (size_t)(n0 + l16) * D_;
    short8 ah[16], al[16];
    #pragma unroll
    for (int t = 0; t < 16; ++t) {
        int koff = t * 32 + quad * 8;
        ah[t] = *(const short8*)(hb + arow + koff);
        al[t] = *(const short8*)(lb + arow + koff);
    }

    float invn[4], sqn[4];
    int   rr[4], rc[4];
    #pragma unroll
    for (int reg = 0; reg < 4; ++reg) {
        int n = n0 + quad * 4 + reg;
        invn[reg] = inv_norm[base + n];
        sqn[reg]  = sqv[base + n];
        rr[reg]   = n / RES_;
        rc[reg]   = n % RES_;
    }

    for (int j0 = 0; j0 < 13; j0 += 2) {
        int  t0 = wv + 4 * j0;
        int  t1 = t0 + 4;
        bool v1 = (t1 < TILES);
        if (t0 >= TILES) break;

        size_t brow0 = (size_t)(t0 * TM + l16) * D_;
        size_t brow1 = v1 ? (size_t)(t1 * TM + l16) * D_ : brow0;

        f32x4 a0a = {0.f,0.f,0.f,0.f}, a0b = {0.f,0.f,0.f,0.f}, a0c = {0.f,0.f,0.f,0.f};
        f32x4 a1a = {0.f,0.f,0.f,0.f}, a1b = {0.f,0.f,0.f,0.f}, a1c = {0.f,0.f,0.f,0.f};

        int k0 = quad * 8;
        short8 c0h = *(const short8*)(hb + brow0 + k0);
        short8 c0l = *(const short8*)(lb + brow0 + k0);
        short8 c1h = *(const short8*)(hb + brow1 + k0);
        short8 c1l = *(const short8*)(lb + brow1 + k0);

        #pragma unroll
        for (int t = 0; t < 16; ++t) {
            short8 n0h, n0l, n1h, n1l;
            if (t < 15) {
                int kn = (t + 1) * 32 + quad * 8;
                n0h = *(const short8*)(hb + brow0 + kn);
                n0l = *(const short8*)(lb + brow0 + kn);
                n1h = *(const short8*)(hb + brow1 + kn);
                n1l = *(const short8*)(lb + brow1 + kn);
            }
            a0a = __builtin_amdgcn_mfma_f32_16x16x32_bf16(al[t], c0h, a0a, 0, 0, 0);
            a1a = __builtin_amdgcn_mfma_f32_16x16x32_bf16(al[t], c1h, a1a, 0, 0, 0);
            a0b = __builtin_amdgcn_mfma_f32_16x16x32_bf16(ah[t], c0l, a0b, 0, 0, 0);
            a1b = __builtin_amdgcn_mfma_f32_16x16x32_bf16(ah[t], c1l, a1b, 0, 0, 0);
            a0c = __builtin_amdgcn_mfma_f32_16x16x32_bf16(ah[t], c0h, a0c, 0, 0, 0);
            a1c = __builtin_amdgcn_mfma_f32_16x16x32_bf16(ah[t], c1h, a1c, 0, 0, 0);
            if (t < 15) { c0h = n0h; c0l = n0l; c1h = n1h; c1l = n1l; }
        }

        #pragma unroll
        for (int p = 0; p < 2; ++p) {
            if (p == 1 && !v1) break;
            int tt = (p == 0) ? t0 : t1;
            f32x4 av;
            if (p == 0) { av = a0a; av += a0b; av += a0c; }
            else        { av = a1a; av += a1b; av += a1c; }
            int m = tt * TM + l16;
            float invm = inv_norm[base + m];
            float sqm  = sqv[base + m];
            int mr = m / RES_, mc = m % RES_;
            #pragma unroll
            for (int reg = 0; reg < 4; ++reg) {
                int n = n0 + quad * 4 + reg;
                float d = sqn[reg] + sqm - 2.f * invn[reg] * invm * av[reg]
                        + rel[(size_t)n * N_ + m];
                int dr = rr[reg] - mr; if (dr < 0) dr = -dr;
                int dc = rc[reg] - mc; if (dc < 0) dc = -dc;
                if (dr <= 1 && dc <= 1) d += INF_;
                distS[quad * 4 + reg][m] = d;
            }
        }
    }
    __syncthreads();

    for (int r = 0; r < 4; ++r) {
        int nl = wv * 4 + r;
        int ng = n0 + nl;
        float vals[13];
        #pragma unroll
        for (int j = 0; j < 13; j++) {
            int mm = lane + 64 * j;
            vals[j] = (mm < N_) ? distS[nl][mm] : BIGF;
        }
        size_t outbase = (size_t)(base + ng) * K_ * 3;
        for (int k = 0; k < K_; k++) {
            float bd = vals[0]; int bi = lane;
            #pragma unroll
            for (int j = 1; j < 13; j++) {
                int mm = lane + 64 * j;
                if (vals[j] < bd || (vals[j] == bd && mm < bi)) { bd = vals[j]; bi = mm; }
            }
            float cd = bd; int ci = bi;
            #pragma unroll
            for (int off = 32; off >= 1; off >>= 1) {
                float od = __shfl_xor(cd, off, 64);
                int   oi = __shfl_xor(ci, off, 64);
                if (od < cd || (od == cd && oi < ci)) { cd = od; ci = oi; }
            }
            #pragma unroll
            for (int j = 0; j < 13; j++) {
                if (ci == lane + 64 * j) vals[j] = BIGF;
            }
            if (lane == 0) {
                out[outbase + (size_t)k * 3 + 0] = (int)base + ci;
                out[outbase + (size_t)k * 3 + 1] = (int)(base + ng);
                out[outbase + (size_t)k * 3 + 2] = 0;
            }
        }
    }
}

extern "C" void kernel_launch(void* const* d_in, const int* in_sizes, int n_in,
                              void* d_out, int out_size, void* d_ws, size_t ws_size,
                              hipStream_t stream) {
    const float* nf  = (const float*)d_in[0];   // [32, 784, 512] f32
    const float* rel = (const float*)d_in[1];   // [1, 784, 784] f32 (already -rel)
    float* inv_norm  = (float*)d_ws;            // [25088]
    float* sq        = inv_norm + B_ * N_;      // [25088]
    int*   out       = (int*)d_out;

    unsigned short* xhi = (unsigned short*)(sq + B_ * N_);
    unsigned short* xlo = xhi + (size_t)B_ * N_ * D_;
    float* dist = (float*)(xlo + (size_t)B_ * N_ * D_);   // [32*784*784]

    size_t need_full = (size_t)2 * B_ * N_ * sizeof(float)
                     + (size_t)2 * B_ * N_ * D_ * sizeof(unsigned short)
                     + (size_t)B_ * N_ * N_ * sizeof(float);

    norm_convert_kernel<<<(B_ * N_) / 4, 256, 0, stream>>>(nf, inv_norm, sq, xhi, xlo);
    if (ws_size >= need_full) {
        gemm32<<<8 * 4 * 13, 128, 0, stream>>>(xhi, xlo, rel, inv_norm, sq, dist);
        topk_direct<<<(B_ * N_) / 4, 256, 0, stream>>>(dist, out);
    } else {
        dist16_topk<<<8 * 4 * TILES, 256, 0, stream>>>(xhi, xlo, rel, inv_norm, sq, out);
    }
}

// Round 7
// 260.761 us; speedup vs baseline: 3.9318x; 1.0819x over previous
//
#include <hip/hip_runtime.h>
#include <math.h>

#define B_    32
#define N_    784
#define D_    512
#define K_    10
#define RES_  28
#define INF_  100000.0f
#define TM    16
#define TILES (N_ / TM)   // 49
#define BIGF  3.0e38f
#define LDSW  788         // fallback kernel's padded dist row stride
#define BROW  520         // LDS B-tile row stride in shorts (1040 B)

typedef __attribute__((ext_vector_type(8))) short short8;
typedef __attribute__((ext_vector_type(4))) float f32x4;

__device__ __forceinline__ unsigned short f2bf(float f) {
    unsigned u = __float_as_uint(f);
    unsigned r = (u + 0x7fffu + ((u >> 16) & 1u)) >> 16;   // RNE
    return (unsigned short)r;
}
__device__ __forceinline__ float bf2f(unsigned short h) {
    return __uint_as_float(((unsigned)h) << 16);
}

// async global->LDS, 16 B per lane: LDS dest = uniform base + lane*16.
__device__ __forceinline__ void gl_lds16(const void* g, void* l) {
    __builtin_amdgcn_global_load_lds(
        (const __attribute__((address_space(1))) unsigned int*)g,
        (__attribute__((address_space(3))) unsigned int*)(void*)l, 16, 0, 0);
}

// ---------------------------------------------------------------------------
// Kernel A: per-row inv_norm & sq, plus split-bf16 conversion
// x = hi + lo with hi=bf16(x), lo=bf16(x-hi). One wave per row.
// ---------------------------------------------------------------------------
__global__ __launch_bounds__(256) void norm_convert_kernel(
    const float* __restrict__ nf, float* __restrict__ inv_norm,
    float* __restrict__ sq, unsigned short* __restrict__ xhi,
    unsigned short* __restrict__ xlo)
{
    int wave = threadIdx.x >> 6;
    int lane = threadIdx.x & 63;
    int row  = blockIdx.x * 4 + wave;           // grid exactly covers B_*N_
    const float* rp = nf + (size_t)row * D_;
    float4 a = *(const float4*)(rp + lane * 8);
    float4 b = *(const float4*)(rp + lane * 8 + 4);
    float v[8] = {a.x, a.y, a.z, a.w, b.x, b.y, b.z, b.w};

    float s = 0.f;
    #pragma unroll
    for (int i = 0; i < 8; i++) s = fmaf(v[i], v[i], s);
    #pragma unroll
    for (int off = 32; off >= 1; off >>= 1)
        s += __shfl_xor(s, off, 64);
    if (lane == 0) {
        float nrm = sqrtf(s);
        float iv  = 1.0f / fmaxf(nrm, 1e-12f);
        inv_norm[row] = iv;
        sq[row]       = s * iv * iv;
    }

    unsigned short h[8], l[8];
    #pragma unroll
    for (int i = 0; i < 8; i++) {
        h[i] = f2bf(v[i]);
        float hf = bf2f(h[i]);
        l[i] = f2bf(v[i] - hf);
    }
    size_t off16 = (size_t)row * D_ + lane * 8;
    short8 h8, l8;
    #pragma unroll
    for (int i = 0; i < 8; i++) { h8[i] = (short)h[i]; l8[i] = (short)l[i]; }
    *(short8*)(xhi + off16) = h8;
    *(short8*)(xlo + off16) = l8;
}

// ---------------------------------------------------------------------------
// Kernel B: one block = (batch, 64 rows), 4 waves, wave wv owns row-tile wv.
// A fragments (full K=512, hi+lo = 128 VGPRs) loaded ONCE and pinned into
// registers with an empty asm barrier -- round-6 counters proved the
// compiler otherwise re-loads them from L2 every tile (VGPR_Count 100, the
// dominant 2.6 GB L2 stream). B tiles staged hi+lo via double-buffered
// async global_load_lds, consumed with ds_read_b128. 3 independent MFMA
// chains. Epilogue applies bias+mask, stores dist rows to global scratch.
// ---------------------------------------------------------------------------
__global__ __launch_bounds__(256, 2) void gemm64(
    const unsigned short* __restrict__ xhi, const unsigned short* __restrict__ xlo,
    const float* __restrict__ rel, const float* __restrict__ inv_norm,
    const float* __restrict__ sqv, float* __restrict__ dist)
{
    __shared__ unsigned short Bs[2][2][16 * BROW];   // 66560 B

    const int tid  = threadIdx.x;
    const int wv   = tid >> 6;
    const int lane = tid & 63;
    const int quad = lane >> 4;
    const int l16  = lane & 15;

    // 416 blocks = 8 XCDs * (4 batches * 13 row-blocks)
    int gb  = blockIdx.x;
    int xcd = gb & 7;
    int loc = gb >> 3;                  // 0..51
    int b   = xcd * 4 + loc / 13;
    int blk = loc % 13;
    const int    n0   = blk * 64;
    const int    nw   = n0 + wv * 16;           // this wave's row-tile
    const bool   wval = (nw < N_);              // wave-uniform (ragged last block)
    const int    nrow = wval ? nw : (N_ - TM);  // clamp for loads
    const size_t base = (size_t)b * N_;

    const unsigned short* hb = xhi + base * D_;
    const unsigned short* lb = xlo + base * D_;

    // ---- A fragments, full K, in registers -- loaded once, PINNED ----
    const size_t arow = (size_t)(nrow + l16) * D_;
    short8 ah[16], al[16];
    #pragma unroll
    for (int t = 0; t < 16; ++t) {
        int koff = t * 32 + quad * 8;
        ah[t] = *(const short8*)(hb + arow + koff);
        al[t] = *(const short8*)(lb + arow + koff);
    }
    #pragma unroll
    for (int t = 0; t < 16; ++t) {
        asm volatile("" : "+v"(ah[t]));   // force VGPR residency; forbid
        asm volatile("" : "+v"(al[t]));   // rematerialized L2 reloads
    }

    // ---- per-row epilogue constants ----
    float invn[4], sqn[4];
    int   rr[4], rc[4];
    #pragma unroll
    for (int reg = 0; reg < 4; ++reg) {
        int n = nrow + quad * 4 + reg;
        invn[reg] = inv_norm[base + n];
        sqn[reg]  = sqv[base + n];
        rr[reg]   = n / RES_;
        rc[reg]   = n % RES_;
    }

    // ---- stage tile 0 ----
    #pragma unroll
    for (int j = 0; j < 4; ++j) {
        int r = wv * 4 + j;
        gl_lds16(hb + (size_t)r * D_ + lane * 8, &Bs[0][0][r * BROW]);
        gl_lds16(lb + (size_t)r * D_ + lane * 8, &Bs[0][1][r * BROW]);
    }
    __syncthreads();   // drains vmcnt: tile 0 staged

    for (int t = 0; t < TILES; ++t) {
        const int cur = t & 1;
        if (t + 1 < TILES) {
            const int nxt = (t + 1) & 1;
            const size_t rbase = (size_t)(t + 1) * TM;
            #pragma unroll
            for (int j = 0; j < 4; ++j) {
                int r = wv * 4 + j;
                gl_lds16(hb + (rbase + r) * D_ + lane * 8, &Bs[nxt][0][r * BROW]);
                gl_lds16(lb + (rbase + r) * D_ + lane * 8, &Bs[nxt][1][r * BROW]);
            }
        }

        // epilogue operands for this tile (issued early)
        int   m    = t * TM + l16;
        float invm = inv_norm[base + m];
        float sqm  = sqv[base + m];
        float relv[4];
        #pragma unroll
        for (int reg = 0; reg < 4; ++reg)
            relv[reg] = rel[(size_t)(nrow + quad * 4 + reg) * N_ + m];

        f32x4 aA = {0.f,0.f,0.f,0.f}, aB = {0.f,0.f,0.f,0.f}, aC = {0.f,0.f,0.f,0.f};
        #pragma unroll
        for (int k = 0; k < 16; ++k) {
            int boff = l16 * BROW + k * 32 + quad * 8;
            short8 bh = *(const short8*)&Bs[cur][0][boff];
            short8 bl = *(const short8*)&Bs[cur][1][boff];
            aA = __builtin_amdgcn_mfma_f32_16x16x32_bf16(al[k], bh, aA, 0, 0, 0);
            aB = __builtin_amdgcn_mfma_f32_16x16x32_bf16(ah[k], bl, aB, 0, 0, 0);
            aC = __builtin_amdgcn_mfma_f32_16x16x32_bf16(ah[k], bh, aC, 0, 0, 0);
        }

        if (wval) {
            int mr = m / RES_, mc = m % RES_;
            #pragma unroll
            for (int reg = 0; reg < 4; ++reg) {
                int n = nrow + quad * 4 + reg;
                float dot = aA[reg] + aB[reg] + aC[reg];
                float d = sqn[reg] + sqm - 2.f * invn[reg] * invm * dot + relv[reg];
                int dr = rr[reg] - mr; if (dr < 0) dr = -dr;
                int dc = rc[reg] - mc; if (dc < 0) dc = -dc;
                if (dr <= 1 && dc <= 1) d += INF_;
                dist[(base + n) * (size_t)N_ + m] = d;
            }
        }
        __syncthreads();   // staged t+1 complete; all waves done with Bs[cur]
    }
}

// ---------------------------------------------------------------------------
// Kernel C: one wave per row; vectorized direct-global read of the dist row
// (3 x float4 + masked tail), then the proven register butterfly top-10.
// ---------------------------------------------------------------------------
__global__ __launch_bounds__(256) void topk_direct(
    const float* __restrict__ dist, int* __restrict__ out)
{
    const int row  = blockIdx.x * 4 + (threadIdx.x >> 6);   // 0..25087
    const int lane = threadIdx.x & 63;
    const int b    = row / N_;
    const size_t base = (size_t)b * N_;

    const float* dr = dist + (size_t)row * N_;
    // slots 0..11: float4 chunks, mm = j*256 + lane*4 + e; slot 12: tail
    float vals[13];
    #pragma unroll
    for (int j = 0; j < 3; j++) {
        float4 q = *(const float4*)(dr + j * 256 + lane * 4);
        vals[j * 4 + 0] = q.x; vals[j * 4 + 1] = q.y;
        vals[j * 4 + 2] = q.z; vals[j * 4 + 3] = q.w;
    }
    vals[12] = (lane < 16) ? dr[768 + lane] : BIGF;

    size_t outbase = (size_t)row * K_ * 3;
    for (int k = 0; k < K_; k++) {
        // lane-local argmin, lexicographic (value, index): scan ascending mm
        float bd = BIGF; int bi = 0x7fffffff;
        #pragma unroll
        for (int s = 0; s < 12; s++) {
            int mm = (s >> 2) * 256 + lane * 4 + (s & 3);
            if (vals[s] < bd || (vals[s] == bd && mm < bi)) { bd = vals[s]; bi = mm; }
        }
        {
            int mm = 768 + lane;
            if (vals[12] < bd || (vals[12] == bd && mm < bi)) { bd = vals[12]; bi = mm; }
        }
        float cd = bd; int ci = bi;
        #pragma unroll
        for (int off = 32; off >= 1; off >>= 1) {
            float od = __shfl_xor(cd, off, 64);
            int   oi = __shfl_xor(ci, off, 64);
            if (od < cd || (od == cd && oi < ci)) { cd = od; ci = oi; }
        }
        #pragma unroll
        for (int s = 0; s < 12; s++) {
            if (ci == (s >> 2) * 256 + lane * 4 + (s & 3)) vals[s] = BIGF;
        }
        if (ci == 768 + lane) vals[12] = BIGF;
        if (lane == 0) {
            out[outbase + (size_t)k * 3 + 0] = (int)base + ci;
            out[outbase + (size_t)k * 3 + 1] = row;
            out[outbase + (size_t)k * 3 + 2] = 0;
        }
    }
}

// ===========================================================================
// Fallback (round-4 proven path) — used only if ws can't hold dist scratch.
// ===========================================================================
__global__ __launch_bounds__(256, 2) void dist16_topk(
    const unsigned short* __restrict__ xhi, const unsigned short* __restrict__ xlo,
    const float* __restrict__ rel, const float* __restrict__ inv_norm,
    const float* __restrict__ sqv, int* __restrict__ out)
{
    __shared__ float distS[TM][LDSW];

    const int tid  = threadIdx.x;
    const int wv   = tid >> 6;
    const int lane = tid & 63;
    const int quad = lane >> 4;
    const int l16  = lane & 15;

    int gb   = blockIdx.x;
    int xcd  = gb & 7;
    int loc  = gb >> 3;
    int b    = xcd * 4 + loc / TILES;
    int tile = loc % TILES;
    const int    n0   = tile * TM;
    const size_t base = (size_t)b * N_;

    const unsigned short* hb = xhi + base * D_;
    const unsigned short* lb = xlo + base * D_;

    const size_t arow = (size_t)(n0 + l16) * D_;
    short8 ah[16], al[16];
    #pragma unroll
    for (int t = 0; t < 16; ++t) {
        int koff = t * 32 + quad * 8;
        ah[t] = *(const short8*)(hb + arow + koff);
        al[t] = *(const short8*)(lb + arow + koff);
    }

    float invn[4], sqn[4];
    int   rr[4], rc[4];
    #pragma unroll
    for (int reg = 0; reg < 4; ++reg) {
        int n = n0 + quad * 4 + reg;
        invn[reg] = inv_norm[base + n];
        sqn[reg]  = sqv[base + n];
        rr[reg]   = n / RES_;
        rc[reg]   = n % RES_;
    }

    for (int j0 = 0; j0 < 13; j0 += 2) {
        int  t0 = wv + 4 * j0;
        int  t1 = t0 + 4;
        bool v1 = (t1 < TILES);
        if (t0 >= TILES) break;

        size_t brow0 = (size_t)(t0 * TM + l16) * D_;
        size_t brow1 = v1 ? (size_t)(t1 * TM + l16) * D_ : brow0;

        f32x4 a0a = {0.f,0.f,0.f,0.f}, a0b = {0.f,0.f,0.f,0.f}, a0c = {0.f,0.f,0.f,0.f};
        f32x4 a1a = {0.f,0.f,0.f,0.f}, a1b = {0.f,0.f,0.f,0.f}, a1c = {0.f,0.f,0.f,0.f};

        int k0 = quad * 8;
        short8 c0h = *(const short8*)(hb + brow0 + k0);
        short8 c0l = *(const short8*)(lb + brow0 + k0);
        short8 c1h = *(const short8*)(hb + brow1 + k0);
        short8 c1l = *(const short8*)(lb + brow1 + k0);

        #pragma unroll
        for (int t = 0; t < 16; ++t) {
            short8 n0h, n0l, n1h, n1l;
            if (t < 15) {
                int kn = (t + 1) * 32 + quad * 8;
                n0h = *(const short8*)(hb + brow0 + kn);
                n0l = *(const short8*)(lb + brow0 + kn);
                n1h = *(const short8*)(hb + brow1 + kn);
                n1l = *(const short8*)(lb + brow1 + kn);
            }
            a0a = __builtin_amdgcn_mfma_f32_16x16x32_bf16(al[t], c0h, a0a, 0, 0, 0);
            a1a = __builtin_amdgcn_mfma_f32_16x16x32_bf16(al[t], c1h, a1a, 0, 0, 0);
            a0b = __builtin_amdgcn_mfma_f32_16x16x32_bf16(ah[t], c0l, a0b, 0, 0, 0);
            a1b = __builtin_amdgcn_mfma_f32_16x16x32_bf16(ah[t], c1l, a1b, 0, 0, 0);
            a0c = __builtin_amdgcn_mfma_f32_16x16x32_bf16(ah[t], c0h, a0c, 0, 0, 0);
            a1c = __builtin_amdgcn_mfma_f32_16x16x32_bf16(ah[t], c1h, a1c, 0, 0, 0);
            if (t < 15) { c0h = n0h; c0l = n0l; c1h = n1h; c1l = n1l; }
        }

        #pragma unroll
        for (int p = 0; p < 2; ++p) {
            if (p == 1 && !v1) break;
            int tt = (p == 0) ? t0 : t1;
            f32x4 av;
            if (p == 0) { av = a0a; av += a0b; av += a0c; }
            else        { av = a1a; av += a1b; av += a1c; }
            int m = tt * TM + l16;
            float invm = inv_norm[base + m];
            float sqm  = sqv[base + m];
            int mr = m / RES_, mc = m % RES_;
            #pragma unroll
            for (int reg = 0; reg < 4; ++reg) {
                int n = n0 + quad * 4 + reg;
                float d = sqn[reg] + sqm - 2.f * invn[reg] * invm * av[reg]
                        + rel[(size_t)n * N_ + m];
                int dr = rr[reg] - mr; if (dr < 0) dr = -dr;
                int dc = rc[reg] - mc; if (dc < 0) dc = -dc;
                if (dr <= 1 && dc <= 1) d += INF_;
                distS[quad * 4 + reg][m] = d;
            }
        }
    }
    __syncthreads();

    for (int r = 0; r < 4; ++r) {
        int nl = wv * 4 + r;
        int ng = n0 + nl;
        float vals[13];
        #pragma unroll
        for (int j = 0; j < 13; j++) {
            int mm = lane + 64 * j;
            vals[j] = (mm < N_) ? distS[nl][mm] : BIGF;
        }
        size_t outbase = (size_t)(base + ng) * K_ * 3;
        for (int k = 0; k < K_; k++) {
            float bd = vals[0]; int bi = lane;
            #pragma unroll
            for (int j = 1; j < 13; j++) {
                int mm = lane + 64 * j;
                if (vals[j] < bd || (vals[j] == bd && mm < bi)) { bd = vals[j]; bi = mm; }
            }
            float cd = bd; int ci = bi;
            #pragma unroll
            for (int off = 32; off >= 1; off >>= 1) {
                float od = __shfl_xor(cd, off, 64);
                int   oi = __shfl_xor(ci, off, 64);
                if (od < cd || (od == cd && oi < ci)) { cd = od; ci = oi; }
            }
            #pragma unroll
            for (int j = 0; j < 13; j++) {
                if (ci == lane + 64 * j) vals[j] = BIGF;
            }
            if (lane == 0) {
                out[outbase + (size_t)k * 3 + 0] = (int)base + ci;
                out[outbase + (size_t)k * 3 + 1] = (int)(base + ng);
                out[outbase + (size_t)k * 3 + 2] = 0;
            }
        }
    }
}

extern "C" void kernel_launch(void* const* d_in, const int* in_sizes, int n_in,
                              void* d_out, int out_size, void* d_ws, size_t ws_size,
                              hipStream_t stream) {
    const float* nf  = (const float*)d_in[0];   // [32, 784, 512] f32
    const float* rel = (const float*)d_in[1];   // [1, 784, 784] f32 (already -rel)
    float* inv_norm  = (float*)d_ws;            // [25088]
    float* sq        = inv_norm + B_ * N_;      // [25088]
    int*   out       = (int*)d_out;

    unsigned short* xhi = (unsigned short*)(sq + B_ * N_);
    unsigned short* xlo = xhi + (size_t)B_ * N_ * D_;
    float* dist = (float*)(xlo + (size_t)B_ * N_ * D_);   // [32*784*784]

    size_t need_full = (size_t)2 * B_ * N_ * sizeof(float)
                     + (size_t)2 * B_ * N_ * D_ * sizeof(unsigned short)
                     + (size_t)B_ * N_ * N_ * sizeof(float);

    norm_convert_kernel<<<(B_ * N_) / 4, 256, 0, stream>>>(nf, inv_norm, sq, xhi, xlo);
    if (ws_size >= need_full) {
        gemm64<<<8 * 4 * 13, 256, 0, stream>>>(xhi, xlo, rel, inv_norm, sq, dist);
        topk_direct<<<(B_ * N_) / 4, 256, 0, stream>>>(dist, out);
    } else {
        dist16_topk<<<8 * 4 * TILES, 256, 0, stream>>>(xhi, xlo, rel, inv_norm, sq, out);
    }
}

// Round 8
// 260.195 us; speedup vs baseline: 3.9403x; 1.0022x over previous
//
#include <hip/hip_runtime.h>
#include <math.h>

#define B_    32
#define N_    784
#define D_    512
#define K_    10
#define RES_  28
#define INF_  100000.0f
#define TM    16
#define TILES (N_ / TM)   // 49
#define BIGF  3.0e38f
#define LDSW  788         // fallback kernel's padded dist row stride
#define BROW  520         // LDS B-tile row stride in shorts (1040 B)

typedef __attribute__((ext_vector_type(8))) short short8;
typedef __attribute__((ext_vector_type(4))) float f32x4;

__device__ __forceinline__ unsigned short f2bf(float f) {
    unsigned u = __float_as_uint(f);
    unsigned r = (u + 0x7fffu + ((u >> 16) & 1u)) >> 16;   // RNE
    return (unsigned short)r;
}
__device__ __forceinline__ float bf2f(unsigned short h) {
    return __uint_as_float(((unsigned)h) << 16);
}

// async global->LDS, 16 B per lane: LDS dest = uniform base + lane*16.
__device__ __forceinline__ void gl_lds16(const void* g, void* l) {
    __builtin_amdgcn_global_load_lds(
        (const __attribute__((address_space(1))) unsigned int*)g,
        (__attribute__((address_space(3))) unsigned int*)(void*)l, 16, 0, 0);
}

// ---------------------------------------------------------------------------
// Kernel A: per-row inv_norm & sq, plus split-bf16 conversion
// x = hi + lo with hi=bf16(x), lo=bf16(x-hi). One wave per row.
// ---------------------------------------------------------------------------
__global__ __launch_bounds__(256) void norm_convert_kernel(
    const float* __restrict__ nf, float* __restrict__ inv_norm,
    float* __restrict__ sq, unsigned short* __restrict__ xhi,
    unsigned short* __restrict__ xlo)
{
    int wave = threadIdx.x >> 6;
    int lane = threadIdx.x & 63;
    int row  = blockIdx.x * 4 + wave;           // grid exactly covers B_*N_
    const float* rp = nf + (size_t)row * D_;
    float4 a = *(const float4*)(rp + lane * 8);
    float4 b = *(const float4*)(rp + lane * 8 + 4);
    float v[8] = {a.x, a.y, a.z, a.w, b.x, b.y, b.z, b.w};

    float s = 0.f;
    #pragma unroll
    for (int i = 0; i < 8; i++) s = fmaf(v[i], v[i], s);
    #pragma unroll
    for (int off = 32; off >= 1; off >>= 1)
        s += __shfl_xor(s, off, 64);
    if (lane == 0) {
        float nrm = sqrtf(s);
        float iv  = 1.0f / fmaxf(nrm, 1e-12f);
        inv_norm[row] = iv;
        sq[row]       = s * iv * iv;
    }

    unsigned short h[8], l[8];
    #pragma unroll
    for (int i = 0; i < 8; i++) {
        h[i] = f2bf(v[i]);
        float hf = bf2f(h[i]);
        l[i] = f2bf(v[i] - hf);
    }
    size_t off16 = (size_t)row * D_ + lane * 8;
    short8 h8, l8;
    #pragma unroll
    for (int i = 0; i < 8; i++) { h8[i] = (short)h[i]; l8[i] = (short)l[i]; }
    *(short8*)(xhi + off16) = h8;
    *(short8*)(xlo + off16) = l8;
}

// ---------------------------------------------------------------------------
// Kernel B: SYMMETRIC distance GEMM. dist is symmetric (x.x^T, rel, mask all
// symmetric), so block (batch, row-block i of 64 rows) sweeps only col-tiles
// t in [4i, 49). For t >= 4i+4 it also mirror-writes dist[m][n] (a perfect
// per-lane float4: 4 consecutive cols of row m). Diagonal 64-block covers
// both orientations directly. ~51% of the round-7 LDS/MFMA work.
// Heavy blocks (i=0) launch first for load balance.
// ---------------------------------------------------------------------------
__global__ __launch_bounds__(256, 2) void gemm64(
    const unsigned short* __restrict__ xhi, const unsigned short* __restrict__ xlo,
    const float* __restrict__ rel, const float* __restrict__ inv_norm,
    const float* __restrict__ sqv, float* __restrict__ dist)
{
    __shared__ unsigned short Bs[2][2][16 * BROW];   // 66560 B

    const int tid  = threadIdx.x;
    const int wv   = tid >> 6;
    const int lane = tid & 63;
    const int quad = lane >> 4;
    const int l16  = lane & 15;

    // 416 blocks = 8 XCDs * (13 row-blocks * 4 batches); blk ascending in
    // launch order => heaviest (blk 0, 49 col-tiles) dispatched first.
    int gb  = blockIdx.x;
    int xcd = gb & 7;
    int loc = gb >> 3;                  // 0..51
    int blk = loc >> 2;                 // 0..12  (row-block, heavy first)
    int b   = xcd * 4 + (loc & 3);      // 4 batches per XCD (L2 residency)
    const int    n0   = blk * 64;
    const int    t0   = blk * 4;        // first col-tile (upper triangle)
    const int    nw   = n0 + wv * 16;           // this wave's row-tile
    const bool   wval = (nw < N_);              // wave-uniform (ragged last block)
    const int    nrow = wval ? nw : (N_ - TM);  // clamp for loads
    const size_t base = (size_t)b * N_;

    const unsigned short* hb = xhi + base * D_;
    const unsigned short* lb = xlo + base * D_;

    // ---- A fragments, full K, in registers/AGPRs (loaded once) ----
    const size_t arow = (size_t)(nrow + l16) * D_;
    short8 ah[16], al[16];
    #pragma unroll
    for (int t = 0; t < 16; ++t) {
        int koff = t * 32 + quad * 8;
        ah[t] = *(const short8*)(hb + arow + koff);
        al[t] = *(const short8*)(lb + arow + koff);
    }

    // ---- per-row epilogue constants ----
    float invn[4], sqn[4];
    int   rr[4], rc[4];
    #pragma unroll
    for (int reg = 0; reg < 4; ++reg) {
        int n = nrow + quad * 4 + reg;
        invn[reg] = inv_norm[base + n];
        sqn[reg]  = sqv[base + n];
        rr[reg]   = n / RES_;
        rc[reg]   = n % RES_;
    }

    // ---- stage first tile (t0) ----
    #pragma unroll
    for (int j = 0; j < 4; ++j) {
        int r = wv * 4 + j;
        gl_lds16(hb + (size_t)(t0 * TM + r) * D_ + lane * 8, &Bs[0][0][r * BROW]);
        gl_lds16(lb + (size_t)(t0 * TM + r) * D_ + lane * 8, &Bs[0][1][r * BROW]);
    }
    __syncthreads();   // drains vmcnt: first tile staged

    for (int t = t0; t < TILES; ++t) {
        const int cur = t & 1;          // t0 is even, so buffer 0 first
        if (t + 1 < TILES) {
            const int nxt = (t + 1) & 1;
            const size_t rbase = (size_t)(t + 1) * TM;
            #pragma unroll
            for (int j = 0; j < 4; ++j) {
                int r = wv * 4 + j;
                gl_lds16(hb + (rbase + r) * D_ + lane * 8, &Bs[nxt][0][r * BROW]);
                gl_lds16(lb + (rbase + r) * D_ + lane * 8, &Bs[nxt][1][r * BROW]);
            }
        }

        // epilogue operands for this tile (issued early)
        int   m    = t * TM + l16;
        float invm = inv_norm[base + m];
        float sqm  = sqv[base + m];
        float relv[4];
        #pragma unroll
        for (int reg = 0; reg < 4; ++reg)
            relv[reg] = rel[(size_t)(nrow + quad * 4 + reg) * N_ + m];

        f32x4 aA = {0.f,0.f,0.f,0.f}, aB = {0.f,0.f,0.f,0.f}, aC = {0.f,0.f,0.f,0.f};
        #pragma unroll
        for (int k = 0; k < 16; ++k) {
            int boff = l16 * BROW + k * 32 + quad * 8;
            short8 bh = *(const short8*)&Bs[cur][0][boff];
            short8 bl = *(const short8*)&Bs[cur][1][boff];
            aA = __builtin_amdgcn_mfma_f32_16x16x32_bf16(al[k], bh, aA, 0, 0, 0);
            aB = __builtin_amdgcn_mfma_f32_16x16x32_bf16(ah[k], bl, aB, 0, 0, 0);
            aC = __builtin_amdgcn_mfma_f32_16x16x32_bf16(ah[k], bh, aC, 0, 0, 0);
        }

        if (wval) {
            int mr = m / RES_, mc = m % RES_;
            float dv[4];
            #pragma unroll
            for (int reg = 0; reg < 4; ++reg) {
                int n = nrow + quad * 4 + reg;
                float dot = aA[reg] + aB[reg] + aC[reg];
                float d = sqn[reg] + sqm - 2.f * invn[reg] * invm * dot + relv[reg];
                int dr = rr[reg] - mr; if (dr < 0) dr = -dr;
                int dc = rc[reg] - mc; if (dc < 0) dc = -dc;
                if (dr <= 1 && dc <= 1) d += INF_;
                dv[reg] = d;
                dist[(base + n) * (size_t)N_ + m] = d;
            }
            if (t >= t0 + 4) {
                // mirror: dist[m][nrow+quad*4 .. +3] -- one float4 per lane
                float4 q = make_float4(dv[0], dv[1], dv[2], dv[3]);
                *(float4*)(dist + (base + m) * (size_t)N_ + nrow + quad * 4) = q;
            }
        }
        __syncthreads();   // staged t+1 complete; all waves done with Bs[cur]
    }
}

// ---------------------------------------------------------------------------
// Kernel C: one wave per row; vectorized direct-global read of the dist row
// (3 x float4 + masked tail), then the proven register butterfly top-10.
// ---------------------------------------------------------------------------
__global__ __launch_bounds__(256) void topk_direct(
    const float* __restrict__ dist, int* __restrict__ out)
{
    const int row  = blockIdx.x * 4 + (threadIdx.x >> 6);   // 0..25087
    const int lane = threadIdx.x & 63;
    const int b    = row / N_;
    const size_t base = (size_t)b * N_;

    const float* dr = dist + (size_t)row * N_;
    // slots 0..11: float4 chunks, mm = j*256 + lane*4 + e; slot 12: tail
    float vals[13];
    #pragma unroll
    for (int j = 0; j < 3; j++) {
        float4 q = *(const float4*)(dr + j * 256 + lane * 4);
        vals[j * 4 + 0] = q.x; vals[j * 4 + 1] = q.y;
        vals[j * 4 + 2] = q.z; vals[j * 4 + 3] = q.w;
    }
    vals[12] = (lane < 16) ? dr[768 + lane] : BIGF;

    size_t outbase = (size_t)row * K_ * 3;
    for (int k = 0; k < K_; k++) {
        // lane-local argmin, lexicographic (value, index): scan ascending mm
        float bd = BIGF; int bi = 0x7fffffff;
        #pragma unroll
        for (int s = 0; s < 12; s++) {
            int mm = (s >> 2) * 256 + lane * 4 + (s & 3);
            if (vals[s] < bd || (vals[s] == bd && mm < bi)) { bd = vals[s]; bi = mm; }
        }
        {
            int mm = 768 + lane;
            if (vals[12] < bd || (vals[12] == bd && mm < bi)) { bd = vals[12]; bi = mm; }
        }
        float cd = bd; int ci = bi;
        #pragma unroll
        for (int off = 32; off >= 1; off >>= 1) {
            float od = __shfl_xor(cd, off, 64);
            int   oi = __shfl_xor(ci, off, 64);
            if (od < cd || (od == cd && oi < ci)) { cd = od; ci = oi; }
        }
        #pragma unroll
        for (int s = 0; s < 12; s++) {
            if (ci == (s >> 2) * 256 + lane * 4 + (s & 3)) vals[s] = BIGF;
        }
        if (ci == 768 + lane) vals[12] = BIGF;
        if (lane == 0) {
            out[outbase + (size_t)k * 3 + 0] = (int)base + ci;
            out[outbase + (size_t)k * 3 + 1] = row;
            out[outbase + (size_t)k * 3 + 2] = 0;
        }
    }
}

// ===========================================================================
// Fallback (round-4 proven path) — used only if ws can't hold dist scratch.
// ===========================================================================
__global__ __launch_bounds__(256, 2) void dist16_topk(
    const unsigned short* __restrict__ xhi, const unsigned short* __restrict__ xlo,
    const float* __restrict__ rel, const float* __restrict__ inv_norm,
    const float* __restrict__ sqv, int* __restrict__ out)
{
    __shared__ float distS[TM][LDSW];

    const int tid  = threadIdx.x;
    const int wv   = tid >> 6;
    const int lane = tid & 63;
    const int quad = lane >> 4;
    const int l16  = lane & 15;

    int gb   = blockIdx.x;
    int xcd  = gb & 7;
    int loc  = gb >> 3;
    int b    = xcd * 4 + loc / TILES;
    int tile = loc % TILES;
    const int    n0   = tile * TM;
    const size_t base = (size_t)b * N_;

    const unsigned short* hb = xhi + base * D_;
    const unsigned short* lb = xlo + base * D_;

    const size_t arow = (size_t)(n0 + l16) * D_;
    short8 ah[16], al[16];
    #pragma unroll
    for (int t = 0; t < 16; ++t) {
        int koff = t * 32 + quad * 8;
        ah[t] = *(const short8*)(hb + arow + koff);
        al[t] = *(const short8*)(lb + arow + koff);
    }

    float invn[4], sqn[4];
    int   rr[4], rc[4];
    #pragma unroll
    for (int reg = 0; reg < 4; ++reg) {
        int n = n0 + quad * 4 + reg;
        invn[reg] = inv_norm[base + n];
        sqn[reg]  = sqv[base + n];
        rr[reg]   = n / RES_;
        rc[reg]   = n % RES_;
    }

    for (int j0 = 0; j0 < 13; j0 += 2) {
        int  t0 = wv + 4 * j0;
        int  t1 = t0 + 4;
        bool v1 = (t1 < TILES);
        if (t0 >= TILES) break;

        size_t brow0 = (size_t)(t0 * TM + l16) * D_;
        size_t brow1 = v1 ? (size_t)(t1 * TM + l16) * D_ : brow0;

        f32x4 a0a = {0.f,0.f,0.f,0.f}, a0b = {0.f,0.f,0.f,0.f}, a0c = {0.f,0.f,0.f,0.f};
        f32x4 a1a = {0.f,0.f,0.f,0.f}, a1b = {0.f,0.f,0.f,0.f}, a1c = {0.f,0.f,0.f,0.f};

        int k0 = quad * 8;
        short8 c0h = *(const short8*)(hb + brow0 + k0);
        short8 c0l = *(const short8*)(lb + brow0 + k0);
        short8 c1h = *(const short8*)(hb + brow1 + k0);
        short8 c1l = *(const short8*)(lb + brow1 + k0);

        #pragma unroll
        for (int t = 0; t < 16; ++t) {
            short8 n0h, n0l, n1h, n1l;
            if (t < 15) {
                int kn = (t + 1) * 32 + quad * 8;
                n0h = *(const short8*)(hb + brow0 + kn);
                n0l = *(const short8*)(lb + brow0 + kn);
                n1h = *(const short8*)(hb + brow1 + kn);
                n1l = *(const short8*)(lb + brow1 + kn);
            }
            a0a = __builtin_amdgcn_mfma_f32_16x16x32_bf16(al[t], c0h, a0a, 0, 0, 0);
            a1a = __builtin_amdgcn_mfma_f32_16x16x32_bf16(al[t], c1h, a1a, 0, 0, 0);
            a0b = __builtin_amdgcn_mfma_f32_16x16x32_bf16(ah[t], c0l, a0b, 0, 0, 0);
            a1b = __builtin_amdgcn_mfma_f32_16x16x32_bf16(ah[t], c1l, a1b, 0, 0, 0);
            a0c = __builtin_amdgcn_mfma_f32_16x16x32_bf16(ah[t], c0h, a0c, 0, 0, 0);
            a1c = __builtin_amdgcn_mfma_f32_16x16x32_bf16(ah[t], c1h, a1c, 0, 0, 0);
            if (t < 15) { c0h = n0h; c0l = n0l; c1h = n1h; c1l = n1l; }
        }

        #pragma unroll
        for (int p = 0; p < 2; ++p) {
            if (p == 1 && !v1) break;
            int tt = (p == 0) ? t0 : t1;
            f32x4 av;
            if (p == 0) { av = a0a; av += a0b; av += a0c; }
            else        { av = a1a; av += a1b; av += a1c; }
            int m = tt * TM + l16;
            float invm = inv_norm[base + m];
            float sqm  = sqv[base + m];
            int mr = m / RES_, mc = m % RES_;
            #pragma unroll
            for (int reg = 0; reg < 4; ++reg) {
                int n = n0 + quad * 4 + reg;
                float d = sqn[reg] + sqm - 2.f * invn[reg] * invm * av[reg]
                        + rel[(size_t)n * N_ + m];
                int dr = rr[reg] - mr; if (dr < 0) dr = -dr;
                int dc = rc[reg] - mc; if (dc < 0) dc = -dc;
                if (dr <= 1 && dc <= 1) d += INF_;
                distS[quad * 4 + reg][m] = d;
            }
        }
    }
    __syncthreads();

    for (int r = 0; r < 4; ++r) {
        int nl = wv * 4 + r;
        int ng = n0 + nl;
        float vals[13];
        #pragma unroll
        for (int j = 0; j < 13; j++) {
            int mm = lane + 64 * j;
            vals[j] = (mm < N_) ? distS[nl][mm] : BIGF;
        }
        size_t outbase = (size_t)(base + ng) * K_ * 3;
        for (int k = 0; k < K_; k++) {
            float bd = vals[0]; int bi = lane;
            #pragma unroll
            for (int j = 1; j < 13; j++) {
                int mm = lane + 64 * j;
                if (vals[j] < bd || (vals[j] == bd && mm < bi)) { bd = vals[j]; bi = mm; }
            }
            float cd = bd; int ci = bi;
            #pragma unroll
            for (int off = 32; off >= 1; off >>= 1) {
                float od = __shfl_xor(cd, off, 64);
                int   oi = __shfl_xor(ci, off, 64);
                if (od < cd || (od == cd && oi < ci)) { cd = od; ci = oi; }
            }
            #pragma unroll
            for (int j = 0; j < 13; j++) {
                if (ci == lane + 64 * j) vals[j] = BIGF;
            }
            if (lane == 0) {
                out[outbase + (size_t)k * 3 + 0] = (int)base + ci;
                out[outbase + (size_t)k * 3 + 1] = (int)(base + ng);
                out[outbase + (size_t)k * 3 + 2] = 0;
            }
        }
    }
}

extern "C" void kernel_launch(void* const* d_in, const int* in_sizes, int n_in,
                              void* d_out, int out_size, void* d_ws, size_t ws_size,
                              hipStream_t stream) {
    const float* nf  = (const float*)d_in[0];   // [32, 784, 512] f32
    const float* rel = (const float*)d_in[1];   // [1, 784, 784] f32 (already -rel)
    float* inv_norm  = (float*)d_ws;            // [25088]
    float* sq        = inv_norm + B_ * N_;      // [25088]
    int*   out       = (int*)d_out;

    unsigned short* xhi = (unsigned short*)(sq + B_ * N_);
    unsigned short* xlo = xhi + (size_t)B_ * N_ * D_;
    float* dist = (float*)(xlo + (size_t)B_ * N_ * D_);   // [32*784*784]

    size_t need_full = (size_t)2 * B_ * N_ * sizeof(float)
                     + (size_t)2 * B_ * N_ * D_ * sizeof(unsigned short)
                     + (size_t)B_ * N_ * N_ * sizeof(float);

    norm_convert_kernel<<<(B_ * N_) / 4, 256, 0, stream>>>(nf, inv_norm, sq, xhi, xlo);
    if (ws_size >= need_full) {
        gemm64<<<8 * 4 * 13, 256, 0, stream>>>(xhi, xlo, rel, inv_norm, sq, dist);
        topk_direct<<<(B_ * N_) / 4, 256, 0, stream>>>(dist, out);
    } else {
        dist16_topk<<<8 * 4 * TILES, 256, 0, stream>>>(xhi, xlo, rel, inv_norm, sq, out);
    }
}

// Round 9
// 229.776 us; speedup vs baseline: 4.4620x; 1.1324x over previous
//
#include <hip/hip_runtime.h>
#include <math.h>

#define B_    32
#define N_    784
#define D_    512
#define K_    10
#define RES_  28
#define INF_  100000.0f
#define TM    16
#define TILES (N_ / TM)   // 49
#define BIGF  3.0e38f
#define LDSW  788         // fallback kernel's padded dist row stride
#define BROW  520         // LDS B-tile row stride in shorts (1040 B)
#define NCH   34          // symmetric chunks per batch (<=13 tiles each)

typedef __attribute__((ext_vector_type(8))) short short8;
typedef __attribute__((ext_vector_type(4))) float f32x4;

// chunk tables: row-block i, col-tile range [ts, te). Ordered by DESCENDING
// tile count so the HW block queue packs heavy chunks first (load balance).
__device__ __constant__ unsigned char CH_I[NCH] =
    {0,0,0,1,1,2,2,3,3,4,5,6, 7, 0,1,2,3,4,4,5,6,7,8,9, 1,10, 8, 5, 2,11, 9, 6, 3,12};
__device__ __constant__ unsigned char CH_TS[NCH] =
    {0,13,26,13,26,13,26,13,26,26,26,26, 28, 39,39,39,39,16,39,39,39,39,39,39, 4,40, 32, 20, 8,44, 36, 24, 12,48};
__device__ __constant__ unsigned char CH_TE[NCH] =
    {13,26,39,26,39,26,39,26,39,39,39,39, 39, 49,49,49,49,26,49,49,49,49,49,49, 13,49, 39, 26, 13,49, 39, 26, 13,49};

__device__ __forceinline__ unsigned short f2bf(float f) {
    unsigned u = __float_as_uint(f);
    unsigned r = (u + 0x7fffu + ((u >> 16) & 1u)) >> 16;   // RNE
    return (unsigned short)r;
}
__device__ __forceinline__ float bf2f(unsigned short h) {
    return __uint_as_float(((unsigned)h) << 16);
}

// async global->LDS, 16 B per lane: LDS dest = uniform base + lane*16.
__device__ __forceinline__ void gl_lds16(const void* g, void* l) {
    __builtin_amdgcn_global_load_lds(
        (const __attribute__((address_space(1))) unsigned int*)g,
        (__attribute__((address_space(3))) unsigned int*)(void*)l, 16, 0, 0);
}

// ---------------------------------------------------------------------------
// Kernel A: per-row inv_norm & sq, plus split-bf16 conversion
// x = hi + lo with hi=bf16(x), lo=bf16(x-hi). One wave per row.
// ---------------------------------------------------------------------------
__global__ __launch_bounds__(256) void norm_convert_kernel(
    const float* __restrict__ nf, float* __restrict__ inv_norm,
    float* __restrict__ sq, unsigned short* __restrict__ xhi,
    unsigned short* __restrict__ xlo)
{
    int wave = threadIdx.x >> 6;
    int lane = threadIdx.x & 63;
    int row  = blockIdx.x * 4 + wave;           // grid exactly covers B_*N_
    const float* rp = nf + (size_t)row * D_;
    float4 a = *(const float4*)(rp + lane * 8);
    float4 b = *(const float4*)(rp + lane * 8 + 4);
    float v[8] = {a.x, a.y, a.z, a.w, b.x, b.y, b.z, b.w};

    float s = 0.f;
    #pragma unroll
    for (int i = 0; i < 8; i++) s = fmaf(v[i], v[i], s);
    #pragma unroll
    for (int off = 32; off >= 1; off >>= 1)
        s += __shfl_xor(s, off, 64);
    if (lane == 0) {
        float nrm = sqrtf(s);
        float iv  = 1.0f / fmaxf(nrm, 1e-12f);
        inv_norm[row] = iv;
        sq[row]       = s * iv * iv;
    }

    unsigned short h[8], l[8];
    #pragma unroll
    for (int i = 0; i < 8; i++) {
        h[i] = f2bf(v[i]);
        float hf = bf2f(h[i]);
        l[i] = f2bf(v[i] - hf);
    }
    size_t off16 = (size_t)row * D_ + lane * 8;
    short8 h8, l8;
    #pragma unroll
    for (int i = 0; i < 8; i++) { h8[i] = (short)h[i]; l8[i] = (short)l[i]; }
    *(short8*)(xhi + off16) = h8;
    *(short8*)(xlo + off16) = l8;
}

// ---------------------------------------------------------------------------
// Kernel B: SYMMETRIC distance GEMM, chunk-scheduled. Block = (batch,
// chunk idx): row-block i (64 rows), col-tiles [ts, te) (<=13, from the
// heavy-first constant tables -- round-8 counters showed the monolithic
// triangle blocks left MfmaUtil at 12% from pure load imbalance).
// For t >= 4i+4 the mirrored cell dist[m][n] is written too (per-lane
// float4). Staging/MFMA/epilogue identical to the proven round-8 kernel.
// ---------------------------------------------------------------------------
__global__ __launch_bounds__(256, 2) void gemm64(
    const unsigned short* __restrict__ xhi, const unsigned short* __restrict__ xlo,
    const float* __restrict__ rel, const float* __restrict__ inv_norm,
    const float* __restrict__ sqv, float* __restrict__ dist)
{
    __shared__ unsigned short Bs[2][2][16 * BROW];   // 66560 B

    const int tid  = threadIdx.x;
    const int wv   = tid >> 6;
    const int lane = tid & 63;
    const int quad = lane >> 4;
    const int l16  = lane & 15;

    // 1088 blocks = 8 XCDs * (34 chunks * 4 batches); low blockIdx = heavy
    // chunks. 4 batches per XCD for L2 residency of the split arrays.
    int gb   = blockIdx.x;
    int xcd  = gb & 7;
    int loc  = gb >> 3;                 // 0..135
    int bsel = loc & 3;
    int idx  = loc >> 2;                // 0..33 (ascending = heavy first)
    int b    = xcd * 4 + bsel;
    const int i      = CH_I[idx];
    const int tstart = CH_TS[idx];
    const int tend   = CH_TE[idx];
    const int    n0   = i * 64;
    const int    nw   = n0 + wv * 16;           // this wave's row-tile
    const bool   wval = (nw < N_);              // wave-uniform (ragged i=12)
    const int    nrow = wval ? nw : (N_ - TM);  // clamp for loads
    const size_t base = (size_t)b * N_;

    const unsigned short* hb = xhi + base * D_;
    const unsigned short* lb = xlo + base * D_;

    // ---- A fragments, full K, in registers/AGPRs (loaded once per chunk) ----
    const size_t arow = (size_t)(nrow + l16) * D_;
    short8 ah[16], al[16];
    #pragma unroll
    for (int t = 0; t < 16; ++t) {
        int koff = t * 32 + quad * 8;
        ah[t] = *(const short8*)(hb + arow + koff);
        al[t] = *(const short8*)(lb + arow + koff);
    }

    // ---- per-row epilogue constants ----
    float invn[4], sqn[4];
    int   rr[4], rc[4];
    #pragma unroll
    for (int reg = 0; reg < 4; ++reg) {
        int n = nrow + quad * 4 + reg;
        invn[reg] = inv_norm[base + n];
        sqn[reg]  = sqv[base + n];
        rr[reg]   = n / RES_;
        rc[reg]   = n % RES_;
    }

    // ---- stage first tile (tstart) ----
    const int sb0 = tstart & 1;
    #pragma unroll
    for (int j = 0; j < 4; ++j) {
        int r = wv * 4 + j;
        gl_lds16(hb + (size_t)(tstart * TM + r) * D_ + lane * 8, &Bs[sb0][0][r * BROW]);
        gl_lds16(lb + (size_t)(tstart * TM + r) * D_ + lane * 8, &Bs[sb0][1][r * BROW]);
    }
    __syncthreads();   // drains vmcnt: first tile staged

    for (int t = tstart; t < tend; ++t) {
        const int cur = t & 1;
        if (t + 1 < tend) {
            const int nxt = (t + 1) & 1;
            const size_t rbase = (size_t)(t + 1) * TM;
            #pragma unroll
            for (int j = 0; j < 4; ++j) {
                int r = wv * 4 + j;
                gl_lds16(hb + (rbase + r) * D_ + lane * 8, &Bs[nxt][0][r * BROW]);
                gl_lds16(lb + (rbase + r) * D_ + lane * 8, &Bs[nxt][1][r * BROW]);
            }
        }

        // epilogue operands for this tile (issued early)
        int   m    = t * TM + l16;
        float invm = inv_norm[base + m];
        float sqm  = sqv[base + m];
        float relv[4];
        #pragma unroll
        for (int reg = 0; reg < 4; ++reg)
            relv[reg] = rel[(size_t)(nrow + quad * 4 + reg) * N_ + m];

        f32x4 aA = {0.f,0.f,0.f,0.f}, aB = {0.f,0.f,0.f,0.f}, aC = {0.f,0.f,0.f,0.f};
        #pragma unroll
        for (int k = 0; k < 16; ++k) {
            int boff = l16 * BROW + k * 32 + quad * 8;
            short8 bh = *(const short8*)&Bs[cur][0][boff];
            short8 bl = *(const short8*)&Bs[cur][1][boff];
            aA = __builtin_amdgcn_mfma_f32_16x16x32_bf16(al[k], bh, aA, 0, 0, 0);
            aB = __builtin_amdgcn_mfma_f32_16x16x32_bf16(ah[k], bl, aB, 0, 0, 0);
            aC = __builtin_amdgcn_mfma_f32_16x16x32_bf16(ah[k], bh, aC, 0, 0, 0);
        }

        if (wval) {
            int mr = m / RES_, mc = m % RES_;
            float dv[4];
            #pragma unroll
            for (int reg = 0; reg < 4; ++reg) {
                int n = nrow + quad * 4 + reg;
                float dot = aA[reg] + aB[reg] + aC[reg];
                float d = sqn[reg] + sqm - 2.f * invn[reg] * invm * dot + relv[reg];
                int dr = rr[reg] - mr; if (dr < 0) dr = -dr;
                int dc = rc[reg] - mc; if (dc < 0) dc = -dc;
                if (dr <= 1 && dc <= 1) d += INF_;
                dv[reg] = d;
                dist[(base + n) * (size_t)N_ + m] = d;
            }
            if (t >= 4 * i + 4) {
                // mirror: dist[m][nrow+quad*4 .. +3] -- one float4 per lane
                float4 q = make_float4(dv[0], dv[1], dv[2], dv[3]);
                *(float4*)(dist + (base + m) * (size_t)N_ + nrow + quad * 4) = q;
            }
        }
        __syncthreads();   // staged t+1 complete; all waves done with Bs[cur]
    }
}

// ---------------------------------------------------------------------------
// Kernel C: one wave per row; vectorized direct-global read of the dist row
// (3 x float4 + masked tail), then the proven register butterfly top-10.
// ---------------------------------------------------------------------------
__global__ __launch_bounds__(256) void topk_direct(
    const float* __restrict__ dist, int* __restrict__ out)
{
    const int row  = blockIdx.x * 4 + (threadIdx.x >> 6);   // 0..25087
    const int lane = threadIdx.x & 63;
    const int b    = row / N_;
    const size_t base = (size_t)b * N_;

    const float* dr = dist + (size_t)row * N_;
    // slots 0..11: float4 chunks, mm = j*256 + lane*4 + e; slot 12: tail
    float vals[13];
    #pragma unroll
    for (int j = 0; j < 3; j++) {
        float4 q = *(const float4*)(dr + j * 256 + lane * 4);
        vals[j * 4 + 0] = q.x; vals[j * 4 + 1] = q.y;
        vals[j * 4 + 2] = q.z; vals[j * 4 + 3] = q.w;
    }
    vals[12] = (lane < 16) ? dr[768 + lane] : BIGF;

    size_t outbase = (size_t)row * K_ * 3;
    for (int k = 0; k < K_; k++) {
        // lane-local argmin, lexicographic (value, index): scan ascending mm
        float bd = BIGF; int bi = 0x7fffffff;
        #pragma unroll
        for (int s = 0; s < 12; s++) {
            int mm = (s >> 2) * 256 + lane * 4 + (s & 3);
            if (vals[s] < bd || (vals[s] == bd && mm < bi)) { bd = vals[s]; bi = mm; }
        }
        {
            int mm = 768 + lane;
            if (vals[12] < bd || (vals[12] == bd && mm < bi)) { bd = vals[12]; bi = mm; }
        }
        float cd = bd; int ci = bi;
        #pragma unroll
        for (int off = 32; off >= 1; off >>= 1) {
            float od = __shfl_xor(cd, off, 64);
            int   oi = __shfl_xor(ci, off, 64);
            if (od < cd || (od == cd && oi < ci)) { cd = od; ci = oi; }
        }
        #pragma unroll
        for (int s = 0; s < 12; s++) {
            if (ci == (s >> 2) * 256 + lane * 4 + (s & 3)) vals[s] = BIGF;
        }
        if (ci == 768 + lane) vals[12] = BIGF;
        if (lane == 0) {
            out[outbase + (size_t)k * 3 + 0] = (int)base + ci;
            out[outbase + (size_t)k * 3 + 1] = row;
            out[outbase + (size_t)k * 3 + 2] = 0;
        }
    }
}

// ===========================================================================
// Fallback (round-4 proven path) — used only if ws can't hold dist scratch.
// ===========================================================================
__global__ __launch_bounds__(256, 2) void dist16_topk(
    const unsigned short* __restrict__ xhi, const unsigned short* __restrict__ xlo,
    const float* __restrict__ rel, const float* __restrict__ inv_norm,
    const float* __restrict__ sqv, int* __restrict__ out)
{
    __shared__ float distS[TM][LDSW];

    const int tid  = threadIdx.x;
    const int wv   = tid >> 6;
    const int lane = tid & 63;
    const int quad = lane >> 4;
    const int l16  = lane & 15;

    int gb   = blockIdx.x;
    int xcd  = gb & 7;
    int loc  = gb >> 3;
    int b    = xcd * 4 + loc / TILES;
    int tile = loc % TILES;
    const int    n0   = tile * TM;
    const size_t base = (size_t)b * N_;

    const unsigned short* hb = xhi + base * D_;
    const unsigned short* lb = xlo + base * D_;

    const size_t arow = (size_t)(n0 + l16) * D_;
    short8 ah[16], al[16];
    #pragma unroll
    for (int t = 0; t < 16; ++t) {
        int koff = t * 32 + quad * 8;
        ah[t] = *(const short8*)(hb + arow + koff);
        al[t] = *(const short8*)(lb + arow + koff);
    }

    float invn[4], sqn[4];
    int   rr[4], rc[4];
    #pragma unroll
    for (int reg = 0; reg < 4; ++reg) {
        int n = n0 + quad * 4 + reg;
        invn[reg] = inv_norm[base + n];
        sqn[reg]  = sqv[base + n];
        rr[reg]   = n / RES_;
        rc[reg]   = n % RES_;
    }

    for (int j0 = 0; j0 < 13; j0 += 2) {
        int  t0 = wv + 4 * j0;
        int  t1 = t0 + 4;
        bool v1 = (t1 < TILES);
        if (t0 >= TILES) break;

        size_t brow0 = (size_t)(t0 * TM + l16) * D_;
        size_t brow1 = v1 ? (size_t)(t1 * TM + l16) * D_ : brow0;

        f32x4 a0a = {0.f,0.f,0.f,0.f}, a0b = {0.f,0.f,0.f,0.f}, a0c = {0.f,0.f,0.f,0.f};
        f32x4 a1a = {0.f,0.f,0.f,0.f}, a1b = {0.f,0.f,0.f,0.f}, a1c = {0.f,0.f,0.f,0.f};

        int k0 = quad * 8;
        short8 c0h = *(const short8*)(hb + brow0 + k0);
        short8 c0l = *(const short8*)(lb + brow0 + k0);
        short8 c1h = *(const short8*)(hb + brow1 + k0);
        short8 c1l = *(const short8*)(lb + brow1 + k0);

        #pragma unroll
        for (int t = 0; t < 16; ++t) {
            short8 n0h, n0l, n1h, n1l;
            if (t < 15) {
                int kn = (t + 1) * 32 + quad * 8;
                n0h = *(const short8*)(hb + brow0 + kn);
                n0l = *(const short8*)(lb + brow0 + kn);
                n1h = *(const short8*)(hb + brow1 + kn);
                n1l = *(const short8*)(lb + brow1 + kn);
            }
            a0a = __builtin_amdgcn_mfma_f32_16x16x32_bf16(al[t], c0h, a0a, 0, 0, 0);
            a1a = __builtin_amdgcn_mfma_f32_16x16x32_bf16(al[t], c1h, a1a, 0, 0, 0);
            a0b = __builtin_amdgcn_mfma_f32_16x16x32_bf16(ah[t], c0l, a0b, 0, 0, 0);
            a1b = __builtin_amdgcn_mfma_f32_16x16x32_bf16(ah[t], c1l, a1b, 0, 0, 0);
            a0c = __builtin_amdgcn_mfma_f32_16x16x32_bf16(ah[t], c0h, a0c, 0, 0, 0);
            a1c = __builtin_amdgcn_mfma_f32_16x16x32_bf16(ah[t], c1h, a1c, 0, 0, 0);
            if (t < 15) { c0h = n0h; c0l = n0l; c1h = n1h; c1l = n1l; }
        }

        #pragma unroll
        for (int p = 0; p < 2; ++p) {
            if (p == 1 && !v1) break;
            int tt = (p == 0) ? t0 : t1;
            f32x4 av;
            if (p == 0) { av = a0a; av += a0b; av += a0c; }
            else        { av = a1a; av += a1b; av += a1c; }
            int m = tt * TM + l16;
            float invm = inv_norm[base + m];
            float sqm  = sqv[base + m];
            int mr = m / RES_, mc = m % RES_;
            #pragma unroll
            for (int reg = 0; reg < 4; ++reg) {
                int n = n0 + quad * 4 + reg;
                float d = sqn[reg] + sqm - 2.f * invn[reg] * invm * av[reg]
                        + rel[(size_t)n * N_ + m];
                int dr = rr[reg] - mr; if (dr < 0) dr = -dr;
                int dc = rc[reg] - mc; if (dc < 0) dc = -dc;
                if (dr <= 1 && dc <= 1) d += INF_;
                distS[quad * 4 + reg][m] = d;
            }
        }
    }
    __syncthreads();

    for (int r = 0; r < 4; ++r) {
        int nl = wv * 4 + r;
        int ng = n0 + nl;
        float vals[13];
        #pragma unroll
        for (int j = 0; j < 13; j++) {
            int mm = lane + 64 * j;
            vals[j] = (mm < N_) ? distS[nl][mm] : BIGF;
        }
        size_t outbase = (size_t)(base + ng) * K_ * 3;
        for (int k = 0; k < K_; k++) {
            float bd = vals[0]; int bi = lane;
            #pragma unroll
            for (int j = 1; j < 13; j++) {
                int mm = lane + 64 * j;
                if (vals[j] < bd || (vals[j] == bd && mm < bi)) { bd = vals[j]; bi = mm; }
            }
            float cd = bd; int ci = bi;
            #pragma unroll
            for (int off = 32; off >= 1; off >>= 1) {
                float od = __shfl_xor(cd, off, 64);
                int   oi = __shfl_xor(ci, off, 64);
                if (od < cd || (od == cd && oi < ci)) { cd = od; ci = oi; }
            }
            #pragma unroll
            for (int j = 0; j < 13; j++) {
                if (ci == lane + 64 * j) vals[j] = BIGF;
            }
            if (lane == 0) {
                out[outbase + (size_t)k * 3 + 0] = (int)base + ci;
                out[outbase + (size_t)k * 3 + 1] = (int)(base + ng);
                out[outbase + (size_t)k * 3 + 2] = 0;
            }
        }
    }
}

extern "C" void kernel_launch(void* const* d_in, const int* in_sizes, int n_in,
                              void* d_out, int out_size, void* d_ws, size_t ws_size,
                              hipStream_t stream) {
    const float* nf  = (const float*)d_in[0];   // [32, 784, 512] f32
    const float* rel = (const float*)d_in[1];   // [1, 784, 784] f32 (already -rel)
    float* inv_norm  = (float*)d_ws;            // [25088]
    float* sq        = inv_norm + B_ * N_;      // [25088]
    int*   out       = (int*)d_out;

    unsigned short* xhi = (unsigned short*)(sq + B_ * N_);
    unsigned short* xlo = xhi + (size_t)B_ * N_ * D_;
    float* dist = (float*)(xlo + (size_t)B_ * N_ * D_);   // [32*784*784]

    size_t need_full = (size_t)2 * B_ * N_ * sizeof(float)
                     + (size_t)2 * B_ * N_ * D_ * sizeof(unsigned short)
                     + (size_t)B_ * N_ * N_ * sizeof(float);

    norm_convert_kernel<<<(B_ * N_) / 4, 256, 0, stream>>>(nf, inv_norm, sq, xhi, xlo);
    if (ws_size >= need_full) {
        gemm64<<<8 * 4 * NCH, 256, 0, stream>>>(xhi, xlo, rel, inv_norm, sq, dist);
        topk_direct<<<(B_ * N_) / 4, 256, 0, stream>>>(dist, out);
    } else {
        dist16_topk<<<8 * 4 * TILES, 256, 0, stream>>>(xhi, xlo, rel, inv_norm, sq, out);
    }
}

// Round 10
// 196.794 us; speedup vs baseline: 5.2098x; 1.1676x over previous
//
#include <hip/hip_runtime.h>
#include <math.h>

#define B_    32
#define N_    784
#define D_    512
#define K_    10
#define RES_  28
#define INF_  100000.0f
#define TM    16
#define TILES (N_ / TM)   // 49
#define BIGF  3.0e38f
#define LDSW  788         // fallback kernel's padded dist row stride
#define BROW  520         // LDS B-tile row stride in shorts (1040 B)
#define NCH   34          // symmetric chunks per batch (<=13 tiles each)

typedef __attribute__((ext_vector_type(8))) short short8;
typedef __attribute__((ext_vector_type(4))) float f32x4;

// chunk tables: row-block i, col-tile range [ts, te). Ordered by DESCENDING
// tile count so the HW block queue packs heavy chunks first (load balance).
__device__ __constant__ unsigned char CH_I[NCH] =
    {0,0,0,1,1,2,2,3,3,4,5,6, 7, 0,1,2,3,4,4,5,6,7,8,9, 1,10, 8, 5, 2,11, 9, 6, 3,12};
__device__ __constant__ unsigned char CH_TS[NCH] =
    {0,13,26,13,26,13,26,13,26,26,26,26, 28, 39,39,39,39,16,39,39,39,39,39,39, 4,40, 32, 20, 8,44, 36, 24, 12,48};
__device__ __constant__ unsigned char CH_TE[NCH] =
    {13,26,39,26,39,26,39,26,39,39,39,39, 39, 49,49,49,49,26,49,49,49,49,49,49, 13,49, 39, 26, 13,49, 39, 26, 13,49};

__device__ __forceinline__ unsigned short f2bf(float f) {
    unsigned u = __float_as_uint(f);
    unsigned r = (u + 0x7fffu + ((u >> 16) & 1u)) >> 16;   // RNE
    return (unsigned short)r;
}
__device__ __forceinline__ float bf2f(unsigned short h) {
    return __uint_as_float(((unsigned)h) << 16);
}

// async global->LDS, 16 B per lane: LDS dest = uniform base + lane*16.
__device__ __forceinline__ void gl_lds16(const void* g, void* l) {
    __builtin_amdgcn_global_load_lds(
        (const __attribute__((address_space(1))) unsigned int*)g,
        (__attribute__((address_space(3))) unsigned int*)(void*)l, 16, 0, 0);
}

// ---------------------------------------------------------------------------
// Kernel A: per-row inv_norm & sq, plus split-bf16 conversion
// x = hi + lo with hi=bf16(x), lo=bf16(x-hi). One wave per row.
// ---------------------------------------------------------------------------
__global__ __launch_bounds__(256) void norm_convert_kernel(
    const float* __restrict__ nf, float* __restrict__ inv_norm,
    float* __restrict__ sq, unsigned short* __restrict__ xhi,
    unsigned short* __restrict__ xlo)
{
    int wave = threadIdx.x >> 6;
    int lane = threadIdx.x & 63;
    int row  = blockIdx.x * 4 + wave;           // grid exactly covers B_*N_
    const float* rp = nf + (size_t)row * D_;
    float4 a = *(const float4*)(rp + lane * 8);
    float4 b = *(const float4*)(rp + lane * 8 + 4);
    float v[8] = {a.x, a.y, a.z, a.w, b.x, b.y, b.z, b.w};

    float s = 0.f;
    #pragma unroll
    for (int i = 0; i < 8; i++) s = fmaf(v[i], v[i], s);
    #pragma unroll
    for (int off = 32; off >= 1; off >>= 1)
        s += __shfl_xor(s, off, 64);
    if (lane == 0) {
        float nrm = sqrtf(s);
        float iv  = 1.0f / fmaxf(nrm, 1e-12f);
        inv_norm[row] = iv;
        sq[row]       = s * iv * iv;
    }

    unsigned short h[8], l[8];
    #pragma unroll
    for (int i = 0; i < 8; i++) {
        h[i] = f2bf(v[i]);
        float hf = bf2f(h[i]);
        l[i] = f2bf(v[i] - hf);
    }
    size_t off16 = (size_t)row * D_ + lane * 8;
    short8 h8, l8;
    #pragma unroll
    for (int i = 0; i < 8; i++) { h8[i] = (short)h[i]; l8[i] = (short)l[i]; }
    *(short8*)(xhi + off16) = h8;
    *(short8*)(xlo + off16) = l8;
}

// ---------------------------------------------------------------------------
// Kernel B: SYMMETRIC distance GEMM, chunk-scheduled (proven round 9).
// ---------------------------------------------------------------------------
__global__ __launch_bounds__(256, 2) void gemm64(
    const unsigned short* __restrict__ xhi, const unsigned short* __restrict__ xlo,
    const float* __restrict__ rel, const float* __restrict__ inv_norm,
    const float* __restrict__ sqv, float* __restrict__ dist)
{
    __shared__ unsigned short Bs[2][2][16 * BROW];   // 66560 B

    const int tid  = threadIdx.x;
    const int wv   = tid >> 6;
    const int lane = tid & 63;
    const int quad = lane >> 4;
    const int l16  = lane & 15;

    // 1088 blocks = 8 XCDs * (34 chunks * 4 batches); low blockIdx = heavy
    // chunks. 4 batches per XCD for L2 residency of the split arrays.
    int gb   = blockIdx.x;
    int xcd  = gb & 7;
    int loc  = gb >> 3;                 // 0..135
    int bsel = loc & 3;
    int idx  = loc >> 2;                // 0..33 (ascending = heavy first)
    int b    = xcd * 4 + bsel;
    const int i      = CH_I[idx];
    const int tstart = CH_TS[idx];
    const int tend   = CH_TE[idx];
    const int    n0   = i * 64;
    const int    nw   = n0 + wv * 16;           // this wave's row-tile
    const bool   wval = (nw < N_);              // wave-uniform (ragged i=12)
    const int    nrow = wval ? nw : (N_ - TM);  // clamp for loads
    const size_t base = (size_t)b * N_;

    const unsigned short* hb = xhi + base * D_;
    const unsigned short* lb = xlo + base * D_;

    // ---- A fragments, full K, in registers/AGPRs (loaded once per chunk) ----
    const size_t arow = (size_t)(nrow + l16) * D_;
    short8 ah[16], al[16];
    #pragma unroll
    for (int t = 0; t < 16; ++t) {
        int koff = t * 32 + quad * 8;
        ah[t] = *(const short8*)(hb + arow + koff);
        al[t] = *(const short8*)(lb + arow + koff);
    }

    // ---- per-row epilogue constants ----
    float invn[4], sqn[4];
    int   rr[4], rc[4];
    #pragma unroll
    for (int reg = 0; reg < 4; ++reg) {
        int n = nrow + quad * 4 + reg;
        invn[reg] = inv_norm[base + n];
        sqn[reg]  = sqv[base + n];
        rr[reg]   = n / RES_;
        rc[reg]   = n % RES_;
    }

    // ---- stage first tile (tstart) ----
    const int sb0 = tstart & 1;
    #pragma unroll
    for (int j = 0; j < 4; ++j) {
        int r = wv * 4 + j;
        gl_lds16(hb + (size_t)(tstart * TM + r) * D_ + lane * 8, &Bs[sb0][0][r * BROW]);
        gl_lds16(lb + (size_t)(tstart * TM + r) * D_ + lane * 8, &Bs[sb0][1][r * BROW]);
    }
    __syncthreads();   // drains vmcnt: first tile staged

    for (int t = tstart; t < tend; ++t) {
        const int cur = t & 1;
        if (t + 1 < tend) {
            const int nxt = (t + 1) & 1;
            const size_t rbase = (size_t)(t + 1) * TM;
            #pragma unroll
            for (int j = 0; j < 4; ++j) {
                int r = wv * 4 + j;
                gl_lds16(hb + (rbase + r) * D_ + lane * 8, &Bs[nxt][0][r * BROW]);
                gl_lds16(lb + (rbase + r) * D_ + lane * 8, &Bs[nxt][1][r * BROW]);
            }
        }

        // epilogue operands for this tile (issued early)
        int   m    = t * TM + l16;
        float invm = inv_norm[base + m];
        float sqm  = sqv[base + m];
        float relv[4];
        #pragma unroll
        for (int reg = 0; reg < 4; ++reg)
            relv[reg] = rel[(size_t)(nrow + quad * 4 + reg) * N_ + m];

        f32x4 aA = {0.f,0.f,0.f,0.f}, aB = {0.f,0.f,0.f,0.f}, aC = {0.f,0.f,0.f,0.f};
        #pragma unroll
        for (int k = 0; k < 16; ++k) {
            int boff = l16 * BROW + k * 32 + quad * 8;
            short8 bh = *(const short8*)&Bs[cur][0][boff];
            short8 bl = *(const short8*)&Bs[cur][1][boff];
            aA = __builtin_amdgcn_mfma_f32_16x16x32_bf16(al[k], bh, aA, 0, 0, 0);
            aB = __builtin_amdgcn_mfma_f32_16x16x32_bf16(ah[k], bl, aB, 0, 0, 0);
            aC = __builtin_amdgcn_mfma_f32_16x16x32_bf16(ah[k], bh, aC, 0, 0, 0);
        }

        if (wval) {
            int mr = m / RES_, mc = m % RES_;
            float dv[4];
            #pragma unroll
            for (int reg = 0; reg < 4; ++reg) {
                int n = nrow + quad * 4 + reg;
                float dot = aA[reg] + aB[reg] + aC[reg];
                float d = sqn[reg] + sqm - 2.f * invn[reg] * invm * dot + relv[reg];
                int dr = rr[reg] - mr; if (dr < 0) dr = -dr;
                int dc = rc[reg] - mc; if (dc < 0) dc = -dc;
                if (dr <= 1 && dc <= 1) d += INF_;
                dv[reg] = d;
                dist[(base + n) * (size_t)N_ + m] = d;
            }
            if (t >= 4 * i + 4) {
                // mirror: dist[m][nrow+quad*4 .. +3] -- one float4 per lane
                float4 q = make_float4(dv[0], dv[1], dv[2], dv[3]);
                *(float4*)(dist + (base + m) * (size_t)N_ + nrow + quad * 4) = q;
            }
        }
        __syncthreads();   // staged t+1 complete; all waves done with Bs[cur]
    }
}

// ---------------------------------------------------------------------------
// Kernel C: one wave per row. Cached per-lane top-2 + lazy repair: the per-k
// full 13-slot rescan (round-9 counters: topk 69% VALU-issue-bound) is
// replaced by a one-time top-2 scan; per k only the 64-lane butterfly runs.
// The unique winner lane promotes s2->s1 (cheap); a second pop while dirty
// triggers the rare full rescan (expected ~0.7 per row, execz-skipped else).
// Selection order identical (lexicographic (value, index)).
// ---------------------------------------------------------------------------
__global__ __launch_bounds__(256) void topk_direct(
    const float* __restrict__ dist, int* __restrict__ out)
{
    const int row  = blockIdx.x * 4 + (threadIdx.x >> 6);   // 0..25087
    const int lane = threadIdx.x & 63;
    const int b    = row / N_;
    const size_t base = (size_t)b * N_;

    const float* dr = dist + (size_t)row * N_;
    // slots 0..11: float4 chunks, mm = (s>>2)*256 + lane*4 + (s&3); slot 12: tail
    float vals[13];
    #pragma unroll
    for (int j = 0; j < 3; j++) {
        float4 q = *(const float4*)(dr + j * 256 + lane * 4);
        vals[j * 4 + 0] = q.x; vals[j * 4 + 1] = q.y;
        vals[j * 4 + 2] = q.z; vals[j * 4 + 3] = q.w;
    }
    vals[12] = (lane < 16) ? dr[768 + lane] : BIGF;

    // ---- per-lane top-2 (strict <, ascending-mm scan order => stable) ----
    float s1 = BIGF, s2 = BIGF;
    int   i1 = 0x7fffffff, i2 = 0x7fffffff;
    #pragma unroll
    for (int s = 0; s < 13; ++s) {
        int   m = (s < 12) ? ((s >> 2) * 256 + lane * 4 + (s & 3)) : (768 + lane);
        float v = vals[s];
        bool lt1 = v < s1;
        bool lt2 = v < s2;
        float ns2 = lt1 ? s1 : (lt2 ? v : s2);
        int   ni2 = lt1 ? i1 : (lt2 ? m : i2);
        s1 = lt1 ? v : s1;  i1 = lt1 ? m : i1;
        s2 = ns2;           i2 = ni2;
    }

    bool dirty = false;
    size_t outbase = (size_t)row * K_ * 3;
    for (int k = 0; k < K_; k++) {
        // 64-lane butterfly on cached lane minima, lexicographic (val, idx)
        float cd = s1; int ci = i1;
        #pragma unroll
        for (int off = 32; off >= 1; off >>= 1) {
            float od = __shfl_xor(cd, off, 64);
            int   oi = __shfl_xor(ci, off, 64);
            if (od < cd || (od == cd && oi < ci)) { cd = od; ci = oi; }
        }
        if (lane == 0) {
            out[outbase + (size_t)k * 3 + 0] = (int)base + ci;
            out[outbase + (size_t)k * 3 + 1] = row;
            out[outbase + (size_t)k * 3 + 2] = 0;
        }
        if (ci == i1) {   // unique winner lane (mm sets disjoint across lanes)
            // remove the winning element from this lane's slots
            #pragma unroll
            for (int s = 0; s < 13; ++s) {
                int m = (s < 12) ? ((s >> 2) * 256 + lane * 4 + (s & 3)) : (768 + lane);
                if (m == ci) vals[s] = BIGF;
            }
            if (!dirty) {
                s1 = s2; i1 = i2; dirty = true;   // cheap path: promote cached 2nd
            } else {
                // rare path: rebuild exact top-2 from remaining slots
                float a1 = BIGF, a2 = BIGF;
                int   b1 = 0x7fffffff, b2 = 0x7fffffff;
                #pragma unroll
                for (int s = 0; s < 13; ++s) {
                    int   m = (s < 12) ? ((s >> 2) * 256 + lane * 4 + (s & 3)) : (768 + lane);
                    float v = vals[s];
                    bool lt1 = v < a1;
                    bool lt2 = v < a2;
                    float ns2 = lt1 ? a1 : (lt2 ? v : a2);
                    int   ni2 = lt1 ? b1 : (lt2 ? m : b2);
                    a1 = lt1 ? v : a1;  b1 = lt1 ? m : b1;
                    a2 = ns2;           b2 = ni2;
                }
                s1 = a1; i1 = b1; s2 = a2; i2 = b2; dirty = false;
            }
        }
    }
}

// ===========================================================================
// Fallback (round-4 proven path) — used only if ws can't hold dist scratch.
// ===========================================================================
__global__ __launch_bounds__(256, 2) void dist16_topk(
    const unsigned short* __restrict__ xhi, const unsigned short* __restrict__ xlo,
    const float* __restrict__ rel, const float* __restrict__ inv_norm,
    const float* __restrict__ sqv, int* __restrict__ out)
{
    __shared__ float distS[TM][LDSW];

    const int tid  = threadIdx.x;
    const int wv   = tid >> 6;
    const int lane = tid & 63;
    const int quad = lane >> 4;
    const int l16  = lane & 15;

    int gb   = blockIdx.x;
    int xcd  = gb & 7;
    int loc  = gb >> 3;
    int b    = xcd * 4 + loc / TILES;
    int tile = loc % TILES;
    const int    n0   = tile * TM;
    const size_t base = (size_t)b * N_;

    const unsigned short* hb = xhi + base * D_;
    const unsigned short* lb = xlo + base * D_;

    const size_t arow = (size_t)(n0 + l16) * D_;
    short8 ah[16], al[16];
    #pragma unroll
    for (int t = 0; t < 16; ++t) {
        int koff = t * 32 + quad * 8;
        ah[t] = *(const short8*)(hb + arow + koff);
        al[t] = *(const short8*)(lb + arow + koff);
    }

    float invn[4], sqn[4];
    int   rr[4], rc[4];
    #pragma unroll
    for (int reg = 0; reg < 4; ++reg) {
        int n = n0 + quad * 4 + reg;
        invn[reg] = inv_norm[base + n];
        sqn[reg]  = sqv[base + n];
        rr[reg]   = n / RES_;
        rc[reg]   = n % RES_;
    }

    for (int j0 = 0; j0 < 13; j0 += 2) {
        int  t0 = wv + 4 * j0;
        int  t1 = t0 + 4;
        bool v1 = (t1 < TILES);
        if (t0 >= TILES) break;

        size_t brow0 = (size_t)(t0 * TM + l16) * D_;
        size_t brow1 = v1 ? (size_t)(t1 * TM + l16) * D_ : brow0;

        f32x4 a0a = {0.f,0.f,0.f,0.f}, a0b = {0.f,0.f,0.f,0.f}, a0c = {0.f,0.f,0.f,0.f};
        f32x4 a1a = {0.f,0.f,0.f,0.f}, a1b = {0.f,0.f,0.f,0.f}, a1c = {0.f,0.f,0.f,0.f};

        int k0 = quad * 8;
        short8 c0h = *(const short8*)(hb + brow0 + k0);
        short8 c0l = *(const short8*)(lb + brow0 + k0);
        short8 c1h = *(const short8*)(hb + brow1 + k0);
        short8 c1l = *(const short8*)(lb + brow1 + k0);

        #pragma unroll
        for (int t = 0; t < 16; ++t) {
            short8 n0h, n0l, n1h, n1l;
            if (t < 15) {
                int kn = (t + 1) * 32 + quad * 8;
                n0h = *(const short8*)(hb + brow0 + kn);
                n0l = *(const short8*)(lb + brow0 + kn);
                n1h = *(const short8*)(hb + brow1 + kn);
                n1l = *(const short8*)(lb + brow1 + kn);
            }
            a0a = __builtin_amdgcn_mfma_f32_16x16x32_bf16(al[t], c0h, a0a, 0, 0, 0);
            a1a = __builtin_amdgcn_mfma_f32_16x16x32_bf16(al[t], c1h, a1a, 0, 0, 0);
            a0b = __builtin_amdgcn_mfma_f32_16x16x32_bf16(ah[t], c0l, a0b, 0, 0, 0);
            a1b = __builtin_amdgcn_mfma_f32_16x16x32_bf16(ah[t], c1l, a1b, 0, 0, 0);
            a0c = __builtin_amdgcn_mfma_f32_16x16x32_bf16(ah[t], c0h, a0c, 0, 0, 0);
            a1c = __builtin_amdgcn_mfma_f32_16x16x32_bf16(ah[t], c1h, a1c, 0, 0, 0);
            if (t < 15) { c0h = n0h; c0l = n0l; c1h = n1h; c1l = n1l; }
        }

        #pragma unroll
        for (int p = 0; p < 2; ++p) {
            if (p == 1 && !v1) break;
            int tt = (p == 0) ? t0 : t1;
            f32x4 av;
            if (p == 0) { av = a0a; av += a0b; av += a0c; }
            else        { av = a1a; av += a1b; av += a1c; }
            int m = tt * TM + l16;
            float invm = inv_norm[base + m];
            float sqm  = sqv[base + m];
            int mr = m / RES_, mc = m % RES_;
            #pragma unroll
            for (int reg = 0; reg < 4; ++reg) {
                int n = n0 + quad * 4 + reg;
                float d = sqn[reg] + sqm - 2.f * invn[reg] * invm * av[reg]
                        + rel[(size_t)n * N_ + m];
                int dr = rr[reg] - mr; if (dr < 0) dr = -dr;
                int dc = rc[reg] - mc; if (dc < 0) dc = -dc;
                if (dr <= 1 && dc <= 1) d += INF_;
                distS[quad * 4 + reg][m] = d;
            }
        }
    }
    __syncthreads();

    for (int r = 0; r < 4; ++r) {
        int nl = wv * 4 + r;
        int ng = n0 + nl;
        float vals[13];
        #pragma unroll
        for (int j = 0; j < 13; j++) {
            int mm = lane + 64 * j;
            vals[j] = (mm < N_) ? distS[nl][mm] : BIGF;
        }
        size_t outbase = (size_t)(base + ng) * K_ * 3;
        for (int k = 0; k < K_; k++) {
            float bd = vals[0]; int bi = lane;
            #pragma unroll
            for (int j = 1; j < 13; j++) {
                int mm = lane + 64 * j;
                if (vals[j] < bd || (vals[j] == bd && mm < bi)) { bd = vals[j]; bi = mm; }
            }
            float cd = bd; int ci = bi;
            #pragma unroll
            for (int off = 32; off >= 1; off >>= 1) {
                float od = __shfl_xor(cd, off, 64);
                int   oi = __shfl_xor(ci, off, 64);
                if (od < cd || (od == cd && oi < ci)) { cd = od; ci = oi; }
            }
            #pragma unroll
            for (int j = 0; j < 13; j++) {
                if (ci == lane + 64 * j) vals[j] = BIGF;
            }
            if (lane == 0) {
                out[outbase + (size_t)k * 3 + 0] = (int)base + ci;
                out[outbase + (size_t)k * 3 + 1] = (int)(base + ng);
                out[outbase + (size_t)k * 3 + 2] = 0;
            }
        }
    }
}

extern "C" void kernel_launch(void* const* d_in, const int* in_sizes, int n_in,
                              void* d_out, int out_size, void* d_ws, size_t ws_size,
                              hipStream_t stream) {
    const float* nf  = (const float*)d_in[0];   // [32, 784, 512] f32
    const float* rel = (const float*)d_in[1];   // [1, 784, 784] f32 (already -rel)
    float* inv_norm  = (float*)d_ws;            // [25088]
    float* sq        = inv_norm + B_ * N_;      // [25088]
    int*   out       = (int*)d_out;

    unsigned short* xhi = (unsigned short*)(sq + B_ * N_);
    unsigned short* xlo = xhi + (size_t)B_ * N_ * D_;
    float* dist = (float*)(xlo + (size_t)B_ * N_ * D_);   // [32*784*784]

    size_t need_full = (size_t)2 * B_ * N_ * sizeof(float)
                     + (size_t)2 * B_ * N_ * D_ * sizeof(unsigned short)
                     + (size_t)B_ * N_ * N_ * sizeof(float);

    norm_convert_kernel<<<(B_ * N_) / 4, 256, 0, stream>>>(nf, inv_norm, sq, xhi, xlo);
    if (ws_size >= need_full) {
        gemm64<<<8 * 4 * NCH, 256, 0, stream>>>(xhi, xlo, rel, inv_norm, sq, dist);
        topk_direct<<<(B_ * N_) / 4, 256, 0, stream>>>(dist, out);
    } else {
        dist16_topk<<<8 * 4 * TILES, 256, 0, stream>>>(xhi, xlo, rel, inv_norm, sq, out);
    }
}

// Round 11
// 194.916 us; speedup vs baseline: 5.2600x; 1.0096x over previous
//
#include <hip/hip_runtime.h>
#include <math.h>

#define B_    32
#define N_    784
#define D_    512
#define K_    10
#define RES_  28
#define INF_  100000.0f
#define TM    16
#define TILES (N_ / TM)   // 49
#define BIGF  3.0e38f
#define LDSW  788         // fallback kernel's padded dist row stride
#define BROW  520         // LDS B-tile row stride in shorts (1040 B)
#define NCH   34          // symmetric chunks per batch (<=13 tiles each)

typedef __attribute__((ext_vector_type(8))) short short8;
typedef __attribute__((ext_vector_type(4))) float f32x4;

// chunk tables: row-block i, col-tile range [ts, te). Ordered by DESCENDING
// tile count so the HW block queue packs heavy chunks first (load balance).
__device__ __constant__ unsigned char CH_I[NCH] =
    {0,0,0,1,1,2,2,3,3,4,5,6, 7, 0,1,2,3,4,4,5,6,7,8,9, 1,10, 8, 5, 2,11, 9, 6, 3,12};
__device__ __constant__ unsigned char CH_TS[NCH] =
    {0,13,26,13,26,13,26,13,26,26,26,26, 28, 39,39,39,39,16,39,39,39,39,39,39, 4,40, 32, 20, 8,44, 36, 24, 12,48};
__device__ __constant__ unsigned char CH_TE[NCH] =
    {13,26,39,26,39,26,39,26,39,39,39,39, 39, 49,49,49,49,26,49,49,49,49,49,49, 13,49, 39, 26, 13,49, 39, 26, 13,49};

__device__ __forceinline__ unsigned short f2bf(float f) {
    unsigned u = __float_as_uint(f);
    unsigned r = (u + 0x7fffu + ((u >> 16) & 1u)) >> 16;   // RNE
    return (unsigned short)r;
}
__device__ __forceinline__ float bf2f(unsigned short h) {
    return __uint_as_float(((unsigned)h) << 16);
}

// async global->LDS, 16 B per lane: LDS dest = uniform base + lane*16.
__device__ __forceinline__ void gl_lds16(const void* g, void* l) {
    __builtin_amdgcn_global_load_lds(
        (const __attribute__((address_space(1))) unsigned int*)g,
        (__attribute__((address_space(3))) unsigned int*)(void*)l, 16, 0, 0);
}

// ---------------------------------------------------------------------------
// Kernel A: per-row inv_norm & sq, plus split-bf16 conversion
// x = hi + lo with hi=bf16(x), lo=bf16(x-hi). One wave per row.
// ---------------------------------------------------------------------------
__global__ __launch_bounds__(256) void norm_convert_kernel(
    const float* __restrict__ nf, float* __restrict__ inv_norm,
    float* __restrict__ sq, unsigned short* __restrict__ xhi,
    unsigned short* __restrict__ xlo)
{
    int wave = threadIdx.x >> 6;
    int lane = threadIdx.x & 63;
    int row  = blockIdx.x * 4 + wave;           // grid exactly covers B_*N_
    const float* rp = nf + (size_t)row * D_;
    float4 a = *(const float4*)(rp + lane * 8);
    float4 b = *(const float4*)(rp + lane * 8 + 4);
    float v[8] = {a.x, a.y, a.z, a.w, b.x, b.y, b.z, b.w};

    float s = 0.f;
    #pragma unroll
    for (int i = 0; i < 8; i++) s = fmaf(v[i], v[i], s);
    #pragma unroll
    for (int off = 32; off >= 1; off >>= 1)
        s += __shfl_xor(s, off, 64);
    if (lane == 0) {
        float nrm = sqrtf(s);
        float iv  = 1.0f / fmaxf(nrm, 1e-12f);
        inv_norm[row] = iv;
        sq[row]       = s * iv * iv;
    }

    unsigned short h[8], l[8];
    #pragma unroll
    for (int i = 0; i < 8; i++) {
        h[i] = f2bf(v[i]);
        float hf = bf2f(h[i]);
        l[i] = f2bf(v[i] - hf);
    }
    size_t off16 = (size_t)row * D_ + lane * 8;
    short8 h8, l8;
    #pragma unroll
    for (int i = 0; i < 8; i++) { h8[i] = (short)h[i]; l8[i] = (short)l[i]; }
    *(short8*)(xhi + off16) = h8;
    *(short8*)(xlo + off16) = l8;
}

// ---------------------------------------------------------------------------
// Kernel B: SYMMETRIC distance GEMM, chunk-scheduled, K-SPLIT pairing.
// Round-10 counters: LDS read pipe is the gate (each wave re-read the full
// 32 KB B-tile for 48 MFMAs). Now waves pair up: wave (pair p, half h) holds
// A fragments for BOTH 16-row tiles of its pair but only K-half h (128
// VGPRs), reads only its K-half of B (16 ds_read_b128 instead of 32), and
// exchanges one f32x4 partial via LDS. LDS ops/wave/tile: 32 -> 18.
// Single mid-iteration barrier covers staging drain + Bs reuse + PS
// visibility (epilogue touches neither Bs nor the next PS buffer).
// ---------------------------------------------------------------------------
__global__ __launch_bounds__(256, 2) void gemm64(
    const unsigned short* __restrict__ xhi, const unsigned short* __restrict__ xlo,
    const float* __restrict__ rel, const float* __restrict__ inv_norm,
    const float* __restrict__ sqv, float* __restrict__ dist)
{
    __shared__ unsigned short Bs[2][2][16 * BROW];   // 66560 B
    __shared__ f32x4 PS[2][2][2][64];                // [buf][pair][half][lane] 8 KB

    const int tid  = threadIdx.x;
    const int wv   = tid >> 6;
    const int lane = tid & 63;
    const int quad = lane >> 4;
    const int l16  = lane & 15;
    const int pr   = wv >> 1;           // pair 0..1 (rows)
    const int hf   = wv & 1;            // K-half 0..1

    // 1088 blocks = 8 XCDs * (34 chunks * 4 batches); low blockIdx = heavy
    // chunks. 4 batches per XCD for L2 residency of the split arrays.
    int gb   = blockIdx.x;
    int xcd  = gb & 7;
    int loc  = gb >> 3;                 // 0..135
    int bsel = loc & 3;
    int idx  = loc >> 2;                // 0..33 (ascending = heavy first)
    int b    = xcd * 4 + bsel;
    const int i      = CH_I[idx];
    const int tstart = CH_TS[idx];
    const int tend   = CH_TE[idx];
    const int    n0   = i * 64;
    const size_t base = (size_t)b * N_;

    // pair's two row-tiles (clamped separately for the ragged i=12 block)
    const int rt0 = n0 + pr * 32;
    const int rt1 = rt0 + 16;
    const int r0c = (rt0 < N_) ? rt0 : (N_ - TM);
    const int r1c = (rt1 < N_) ? rt1 : (N_ - TM);
    // this wave finalizes tile h of its pair
    const int  nw   = rt0 + hf * TM;
    const bool wval = (nw < N_);                 // wave-uniform
    const int  nrow = wval ? nw : (N_ - TM);

    const unsigned short* hb = xhi + base * D_;
    const unsigned short* lb = xlo + base * D_;

    // ---- A fragments: both row-tiles, K-half hf only (128 VGPRs) ----
    const size_t ar0 = (size_t)(r0c + l16) * D_;
    const size_t ar1 = (size_t)(r1c + l16) * D_;
    short8 ah0[8], al0[8], ah1[8], al1[8];
    #pragma unroll
    for (int t = 0; t < 8; ++t) {
        int koff = (hf * 8 + t) * 32 + quad * 8;
        ah0[t] = *(const short8*)(hb + ar0 + koff);
        al0[t] = *(const short8*)(lb + ar0 + koff);
        ah1[t] = *(const short8*)(hb + ar1 + koff);
        al1[t] = *(const short8*)(lb + ar1 + koff);
    }

    // ---- per-row epilogue constants (for the finalized tile) ----
    float invn[4], sqn[4];
    int   rr[4], rc[4];
    #pragma unroll
    for (int reg = 0; reg < 4; ++reg) {
        int n = nrow + quad * 4 + reg;
        invn[reg] = inv_norm[base + n];
        sqn[reg]  = sqv[base + n];
        rr[reg]   = n / RES_;
        rc[reg]   = n % RES_;
    }

    // ---- stage first tile (tstart) ----
    const int sb0 = tstart & 1;
    #pragma unroll
    for (int j = 0; j < 4; ++j) {
        int r = wv * 4 + j;
        gl_lds16(hb + (size_t)(tstart * TM + r) * D_ + lane * 8, &Bs[sb0][0][r * BROW]);
        gl_lds16(lb + (size_t)(tstart * TM + r) * D_ + lane * 8, &Bs[sb0][1][r * BROW]);
    }
    __syncthreads();   // drains vmcnt: first tile staged

    for (int t = tstart; t < tend; ++t) {
        const int cur = t & 1;
        if (t + 1 < tend) {
            const int nxt = (t + 1) & 1;
            const size_t rbase = (size_t)(t + 1) * TM;
            #pragma unroll
            for (int j = 0; j < 4; ++j) {
                int r = wv * 4 + j;
                gl_lds16(hb + (rbase + r) * D_ + lane * 8, &Bs[nxt][0][r * BROW]);
                gl_lds16(lb + (rbase + r) * D_ + lane * 8, &Bs[nxt][1][r * BROW]);
            }
        }

        // epilogue operands for this tile (issued early)
        int   m    = t * TM + l16;
        float invm = inv_norm[base + m];
        float sqm  = sqv[base + m];
        float relv[4];
        #pragma unroll
        for (int reg = 0; reg < 4; ++reg)
            relv[reg] = rel[(size_t)(nrow + quad * 4 + reg) * N_ + m];

        // 6 independent chains over this wave's K-half
        f32x4 aA0 = {0.f,0.f,0.f,0.f}, aB0 = {0.f,0.f,0.f,0.f}, aC0 = {0.f,0.f,0.f,0.f};
        f32x4 aA1 = {0.f,0.f,0.f,0.f}, aB1 = {0.f,0.f,0.f,0.f}, aC1 = {0.f,0.f,0.f,0.f};
        #pragma unroll
        for (int k = 0; k < 8; ++k) {
            int boff = l16 * BROW + (hf * 8 + k) * 32 + quad * 8;
            short8 bh = *(const short8*)&Bs[cur][0][boff];
            short8 bl = *(const short8*)&Bs[cur][1][boff];
            aA0 = __builtin_amdgcn_mfma_f32_16x16x32_bf16(al0[k], bh, aA0, 0, 0, 0);
            aA1 = __builtin_amdgcn_mfma_f32_16x16x32_bf16(al1[k], bh, aA1, 0, 0, 0);
            aB0 = __builtin_amdgcn_mfma_f32_16x16x32_bf16(ah0[k], bl, aB0, 0, 0, 0);
            aB1 = __builtin_amdgcn_mfma_f32_16x16x32_bf16(ah1[k], bl, aB1, 0, 0, 0);
            aC0 = __builtin_amdgcn_mfma_f32_16x16x32_bf16(ah0[k], bh, aC0, 0, 0, 0);
            aC1 = __builtin_amdgcn_mfma_f32_16x16x32_bf16(ah1[k], bh, aC1, 0, 0, 0);
        }
        f32x4 s0 = aA0 + aB0 + aC0;   // partial dot, rows [rt0, rt0+16)
        f32x4 s1 = aA1 + aB1 + aC1;   // partial dot, rows [rt1, rt1+16)

        // exchange the partial this wave does NOT finalize
        PS[cur][pr][hf][lane] = hf ? s0 : s1;
        __syncthreads();   // PS visible + staged t+1 drained + Bs[cur] free

        f32x4 own  = hf ? s1 : s0;
        f32x4 part = PS[cur][pr][hf ^ 1][lane];
        f32x4 tot  = own + part;

        if (wval) {
            int mr = m / RES_, mc = m % RES_;
            float dv[4];
            #pragma unroll
            for (int reg = 0; reg < 4; ++reg) {
                int n = nrow + quad * 4 + reg;
                float d = sqn[reg] + sqm - 2.f * invn[reg] * invm * tot[reg] + relv[reg];
                int dr = rr[reg] - mr; if (dr < 0) dr = -dr;
                int dc = rc[reg] - mc; if (dc < 0) dc = -dc;
                if (dr <= 1 && dc <= 1) d += INF_;
                dv[reg] = d;
                dist[(base + n) * (size_t)N_ + m] = d;
            }
            if (t >= 4 * i + 4) {
                // mirror: dist[m][nrow+quad*4 .. +3] -- one float4 per lane
                float4 q = make_float4(dv[0], dv[1], dv[2], dv[3]);
                *(float4*)(dist + (base + m) * (size_t)N_ + nrow + quad * 4) = q;
            }
        }
    }
}

// ---------------------------------------------------------------------------
// Kernel C: one wave per row, XCD-matched to gemm's writer (batch b written
// by XCD b>>2 -> this block reads it there for L2 hits). Cached per-lane
// top-2 + lazy repair (proven round 10), lexicographic (value, index).
// ---------------------------------------------------------------------------
__global__ __launch_bounds__(256) void topk_direct(
    const float* __restrict__ dist, int* __restrict__ out)
{
    const int g    = blockIdx.x;            // 6272 blocks
    const int xcd  = g & 7;
    const int li   = g >> 3;                // 0..783
    const int r4   = li * 4 + (threadIdx.x >> 6);   // 0..3135 within-XCD row
    const int lane = threadIdx.x & 63;
    const int bl   = r4 / N_;               // 0..3
    const int n    = r4 - bl * N_;
    const int b    = xcd * 4 + bl;
    const int row  = b * N_ + n;
    const size_t base = (size_t)b * N_;

    const float* dr = dist + (size_t)row * N_;
    // slots 0..11: float4 chunks, mm = (s>>2)*256 + lane*4 + (s&3); slot 12: tail
    float vals[13];
    #pragma unroll
    for (int j = 0; j < 3; j++) {
        float4 q = *(const float4*)(dr + j * 256 + lane * 4);
        vals[j * 4 + 0] = q.x; vals[j * 4 + 1] = q.y;
        vals[j * 4 + 2] = q.z; vals[j * 4 + 3] = q.w;
    }
    vals[12] = (lane < 16) ? dr[768 + lane] : BIGF;

    // ---- per-lane top-2 (strict <, ascending-mm scan order => stable) ----
    float s1 = BIGF, s2 = BIGF;
    int   i1 = 0x7fffffff, i2 = 0x7fffffff;
    #pragma unroll
    for (int s = 0; s < 13; ++s) {
        int   m = (s < 12) ? ((s >> 2) * 256 + lane * 4 + (s & 3)) : (768 + lane);
        float v = vals[s];
        bool lt1 = v < s1;
        bool lt2 = v < s2;
        float ns2 = lt1 ? s1 : (lt2 ? v : s2);
        int   ni2 = lt1 ? i1 : (lt2 ? m : i2);
        s1 = lt1 ? v : s1;  i1 = lt1 ? m : i1;
        s2 = ns2;           i2 = ni2;
    }

    bool dirty = false;
    size_t outbase = (size_t)row * K_ * 3;
    for (int k = 0; k < K_; k++) {
        float cd = s1; int ci = i1;
        #pragma unroll
        for (int off = 32; off >= 1; off >>= 1) {
            float od = __shfl_xor(cd, off, 64);
            int   oi = __shfl_xor(ci, off, 64);
            if (od < cd || (od == cd && oi < ci)) { cd = od; ci = oi; }
        }
        if (lane == 0) {
            out[outbase + (size_t)k * 3 + 0] = (int)base + ci;
            out[outbase + (size_t)k * 3 + 1] = row;
            out[outbase + (size_t)k * 3 + 2] = 0;
        }
        if (ci == i1) {   // unique winner lane (mm sets disjoint across lanes)
            #pragma unroll
            for (int s = 0; s < 13; ++s) {
                int m = (s < 12) ? ((s >> 2) * 256 + lane * 4 + (s & 3)) : (768 + lane);
                if (m == ci) vals[s] = BIGF;
            }
            if (!dirty) {
                s1 = s2; i1 = i2; dirty = true;   // cheap path
            } else {
                float a1 = BIGF, a2 = BIGF;
                int   b1 = 0x7fffffff, b2 = 0x7fffffff;
                #pragma unroll
                for (int s = 0; s < 13; ++s) {
                    int   m = (s < 12) ? ((s >> 2) * 256 + lane * 4 + (s & 3)) : (768 + lane);
                    float v = vals[s];
                    bool lt1 = v < a1;
                    bool lt2 = v < a2;
                    float ns2 = lt1 ? a1 : (lt2 ? v : a2);
                    int   ni2 = lt1 ? b1 : (lt2 ? m : b2);
                    a1 = lt1 ? v : a1;  b1 = lt1 ? m : b1;
                    a2 = ns2;           b2 = ni2;
                }
                s1 = a1; i1 = b1; s2 = a2; i2 = b2; dirty = false;
            }
        }
    }
}

// ===========================================================================
// Fallback (round-4 proven path) — used only if ws can't hold dist scratch.
// ===========================================================================
__global__ __launch_bounds__(256, 2) void dist16_topk(
    const unsigned short* __restrict__ xhi, const unsigned short* __restrict__ xlo,
    const float* __restrict__ rel, const float* __restrict__ inv_norm,
    const float* __restrict__ sqv, int* __restrict__ out)
{
    __shared__ float distS[TM][LDSW];

    const int tid  = threadIdx.x;
    const int wv   = tid >> 6;
    const int lane = tid & 63;
    const int quad = lane >> 4;
    const int l16  = lane & 15;

    int gb   = blockIdx.x;
    int xcd  = gb & 7;
    int loc  = gb >> 3;
    int b    = xcd * 4 + loc / TILES;
    int tile = loc % TILES;
    const int    n0   = tile * TM;
    const size_t base = (size_t)b * N_;

    const unsigned short* hb = xhi + base * D_;
    const unsigned short* lb = xlo + base * D_;

    const size_t arow = (size_t)(n0 + l16) * D_;
    short8 ah[16], al[16];
    #pragma unroll
    for (int t = 0; t < 16; ++t) {
        int koff = t * 32 + quad * 8;
        ah[t] = *(const short8*)(hb + arow + koff);
        al[t] = *(const short8*)(lb + arow + koff);
    }

    float invn[4], sqn[4];
    int   rr[4], rc[4];
    #pragma unroll
    for (int reg = 0; reg < 4; ++reg) {
        int n = n0 + quad * 4 + reg;
        invn[reg] = inv_norm[base + n];
        sqn[reg]  = sqv[base + n];
        rr[reg]   = n / RES_;
        rc[reg]   = n % RES_;
    }

    for (int j0 = 0; j0 < 13; j0 += 2) {
        int  t0 = wv + 4 * j0;
        int  t1 = t0 + 4;
        bool v1 = (t1 < TILES);
        if (t0 >= TILES) break;

        size_t brow0 = (size_t)(t0 * TM + l16) * D_;
        size_t brow1 = v1 ? (size_t)(t1 * TM + l16) * D_ : brow0;

        f32x4 a0a = {0.f,0.f,0.f,0.f}, a0b = {0.f,0.f,0.f,0.f}, a0c = {0.f,0.f,0.f,0.f};
        f32x4 a1a = {0.f,0.f,0.f,0.f}, a1b = {0.f,0.f,0.f,0.f}, a1c = {0.f,0.f,0.f,0.f};

        int k0 = quad * 8;
        short8 c0h = *(const short8*)(hb + brow0 + k0);
        short8 c0l = *(const short8*)(lb + brow0 + k0);
        short8 c1h = *(const short8*)(hb + brow1 + k0);
        short8 c1l = *(const short8*)(lb + brow1 + k0);

        #pragma unroll
        for (int t = 0; t < 16; ++t) {
            short8 n0h, n0l, n1h, n1l;
            if (t < 15) {
                int kn = (t + 1) * 32 + quad * 8;
                n0h = *(const short8*)(hb + brow0 + kn);
                n0l = *(const short8*)(lb + brow0 + kn);
                n1h = *(const short8*)(hb + brow1 + kn);
                n1l = *(const short8*)(lb + brow1 + kn);
            }
            a0a = __builtin_amdgcn_mfma_f32_16x16x32_bf16(al[t], c0h, a0a, 0, 0, 0);
            a1a = __builtin_amdgcn_mfma_f32_16x16x32_bf16(al[t], c1h, a1a, 0, 0, 0);
            a0b = __builtin_amdgcn_mfma_f32_16x16x32_bf16(ah[t], c0l, a0b, 0, 0, 0);
            a1b = __builtin_amdgcn_mfma_f32_16x16x32_bf16(ah[t], c1l, a1b, 0, 0, 0);
            a0c = __builtin_amdgcn_mfma_f32_16x16x32_bf16(ah[t], c0h, a0c, 0, 0, 0);
            a1c = __builtin_amdgcn_mfma_f32_16x16x32_bf16(ah[t], c1h, a1c, 0, 0, 0);
            if (t < 15) { c0h = n0h; c0l = n0l; c1h = n1h; c1l = n1l; }
        }

        #pragma unroll
        for (int p = 0; p < 2; ++p) {
            if (p == 1 && !v1) break;
            int tt = (p == 0) ? t0 : t1;
            f32x4 av;
            if (p == 0) { av = a0a; av += a0b; av += a0c; }
            else        { av = a1a; av += a1b; av += a1c; }
            int m = tt * TM + l16;
            float invm = inv_norm[base + m];
            float sqm  = sqv[base + m];
            int mr = m / RES_, mc = m % RES_;
            #pragma unroll
            for (int reg = 0; reg < 4; ++reg) {
                int n = n0 + quad * 4 + reg;
                float d = sqn[reg] + sqm - 2.f * invn[reg] * invm * av[reg]
                        + rel[(size_t)n * N_ + m];
                int dr = rr[reg] - mr; if (dr < 0) dr = -dr;
                int dc = rc[reg] - mc; if (dc < 0) dc = -dc;
                if (dr <= 1 && dc <= 1) d += INF_;
                distS[quad * 4 + reg][m] = d;
            }
        }
    }
    __syncthreads();

    for (int r = 0; r < 4; ++r) {
        int nl = wv * 4 + r;
        int ng = n0 + nl;
        float vals[13];
        #pragma unroll
        for (int j = 0; j < 13; j++) {
            int mm = lane + 64 * j;
            vals[j] = (mm < N_) ? distS[nl][mm] : BIGF;
        }
        size_t outbase = (size_t)(base + ng) * K_ * 3;
        for (int k = 0; k < K_; k++) {
            float bd = vals[0]; int bi = lane;
            #pragma unroll
            for (int j = 1; j < 13; j++) {
                int mm = lane + 64 * j;
                if (vals[j] < bd || (vals[j] == bd && mm < bi)) { bd = vals[j]; bi = mm; }
            }
            float cd = bd; int ci = bi;
            #pragma unroll
            for (int off = 32; off >= 1; off >>= 1) {
                float od = __shfl_xor(cd, off, 64);
                int   oi = __shfl_xor(ci, off, 64);
                if (od < cd || (od == cd && oi < ci)) { cd = od; ci = oi; }
            }
            #pragma unroll
            for (int j = 0; j < 13; j++) {
                if (ci == lane + 64 * j) vals[j] = BIGF;
            }
            if (lane == 0) {
                out[outbase + (size_t)k * 3 + 0] = (int)base + ci;
                out[outbase + (size_t)k * 3 + 1] = (int)(base + ng);
                out[outbase + (size_t)k * 3 + 2] = 0;
            }
        }
    }
}

extern "C" void kernel_launch(void* const* d_in, const int* in_sizes, int n_in,
                              void* d_out, int out_size, void* d_ws, size_t ws_size,
                              hipStream_t stream) {
    const float* nf  = (const float*)d_in[0];   // [32, 784, 512] f32
    const float* rel = (const float*)d_in[1];   // [1, 784, 784] f32 (already -rel)
    float* inv_norm  = (float*)d_ws;            // [25088]
    float* sq        = inv_norm + B_ * N_;      // [25088]
    int*   out       = (int*)d_out;

    unsigned short* xhi = (unsigned short*)(sq + B_ * N_);
    unsigned short* xlo = xhi + (size_t)B_ * N_ * D_;
    float* dist = (float*)(xlo + (size_t)B_ * N_ * D_);   // [32*784*784]

    size_t need_full = (size_t)2 * B_ * N_ * sizeof(float)
                     + (size_t)2 * B_ * N_ * D_ * sizeof(unsigned short)
                     + (size_t)B_ * N_ * N_ * sizeof(float);

    norm_convert_kernel<<<(B_ * N_) / 4, 256, 0, stream>>>(nf, inv_norm, sq, xhi, xlo);
    if (ws_size >= need_full) {
        gemm64<<<8 * 4 * NCH, 256, 0, stream>>>(xhi, xlo, rel, inv_norm, sq, dist);
        topk_direct<<<(B_ * N_) / 4, 256, 0, stream>>>(dist, out);
    } else {
        dist16_topk<<<8 * 4 * TILES, 256, 0, stream>>>(xhi, xlo, rel, inv_norm, sq, out);
    }
}